// Round 19
// baseline (212.607 us; speedup 1.0000x reference)
//
#include <hip/hip_runtime.h>

#define HWS 65536   // 256*256
#define SPZ 66048   // (256+2)*256 halo strip positions

typedef __attribute__((ext_vector_type(8))) short bf16x8;
typedef __attribute__((ext_vector_type(4))) float f32x4;
typedef unsigned int u32;
typedef unsigned short u16;

__device__ __forceinline__ u16 f2bf(float x) {
    u32 u = __float_as_uint(x);
    return (u16)((u + 0x7fffu + ((u >> 16) & 1u)) >> 16);
}
__device__ __forceinline__ float bf2f(u32 h) { return __uint_as_float(h << 16); }
// HW packed bf16 convert (RNE, identical rounding to f2bf): lo=a, hi=b
__device__ __forceinline__ u32 cvtpk(float a, float b) {
    u32 r;
    asm("v_cvt_pk_bf16_f32 %0, %1, %2" : "=v"(r) : "v"(a), "v"(b));
    return r;
}

// ---------------- prep: weight cvt + zero accumulators (one launch) ----------------
__global__ void k_prep(const float* __restrict__ wr, const float* __restrict__ wi,
                       u16* __restrict__ wbf, float* __restrict__ zbuf, int nz) {
    int i = blockIdx.x * 256 + threadIdx.x;
    if (i < 12288) {
        wbf[i]         = f2bf(wr[i]);
        wbf[12288 + i] = f2bf(wi[i]);
        wbf[24576 + i] = f2bf(-wi[i]);
    }
    if (i < nz) zbuf[i] = 0.f;
}

// ---------------- Kernel X: transpose+convert x -> xTr/xTi bf16 [HWS][64] ----------------
__global__ __launch_bounds__(256) void k_xt(const float* __restrict__ x,
                                            u16* __restrict__ xTr,
                                            u16* __restrict__ xTi,
                                            size_t xs, size_t ts) {
    const int b = blockIdx.z;
    x += (size_t)b * xs; xTr += (size_t)b * ts; xTi += (size_t)b * ts;
    __shared__ u16 Tr[64][74], Ti[64][74];
    int p0 = blockIdx.x << 6;
    int t = threadIdx.x;
    const float2* x2 = (const float2*)x;
    for (int i = t; i < 2048; i += 256) {        // (ci-pair, c)
        int cp = i >> 6, c = i & 63;
        int ci = cp << 1;
        float2 v0 = x2[(size_t)ci * HWS + p0 + c];
        float2 v1 = x2[(size_t)(ci + 1) * HWS + p0 + c];
        *(u32*)&Tr[c][ci] = cvtpk(v0.x, v1.x);
        *(u32*)&Ti[c][ci] = cvtpk(v0.y, v1.y);
    }
    __syncthreads();
    for (int i = t; i < 2048; i += 256) {        // (row, ci-pair)
        int rr = i >> 5, cp = i & 31;
        *(u32*)&xTr[(size_t)(p0 + rr) * 64 + 2 * cp] = *(u32*)&Tr[rr][2 * cp];
        *(u32*)&xTi[(size_t)(p0 + rr) * 64 + 2 * cp] = *(u32*)&Ti[rr][2 * cp];
    }
}

// ---------------- Kernel A: qkv 1x1 complex conv, global->MFMA, LDS epilogue ----------------
// 1D grid, XCD-swizzled: all 6 cog-blocks of a row-pair land on the same XCD.
__global__ __launch_bounds__(256) void k_qkv(const u16* __restrict__ xTr,
                                             const u16* __restrict__ xTi,
                                             const u16* __restrict__ wbf,
                                             u32* __restrict__ qs,
                                             size_t ts, size_t qsst, int NPR) {
    __shared__ u32 Tep[32 * 257];
    const int bid = blockIdx.x;
    const int xcd = bid & 7, j = bid >> 3;
    const int cog = j % 6;               // 0..5, 32 co each
    const int pr  = xcd + 8 * (j / 6);   // row-pair index
    if (pr >= NPR) return;
    const int z  = pr / 258;
    const int rt = pr % 258;             // 0..257
    xTr += (size_t)z * ts; xTi += (size_t)z * ts; qs += (size_t)z * qsst;
    const int w = rt - 1;                // image row (may be OOB -> zeros)
    const int t = threadIdx.x, lane = t & 63, wv = t >> 6;
    const int l15 = lane & 15, l4 = lane >> 4;
    const bool valid = (unsigned)w < 256u;

    bf16x8 Ar[2][2], Ai[2][2], An[2][2];
#pragma unroll
    for (int cf = 0; cf < 2; ++cf)
#pragma unroll
        for (int ks = 0; ks < 2; ++ks) {
            size_t off = (size_t)(cog * 32 + 16 * cf + l15) * 64 + 32 * ks + 8 * l4;
            Ar[cf][ks] = *(const bf16x8*)&wbf[off];
            Ai[cf][ks] = *(const bf16x8*)&wbf[12288 + off];
            An[cf][ks] = *(const bf16x8*)&wbf[24576 + off];
        }

    const f32x4 zz = {0.f, 0.f, 0.f, 0.f};
#pragma unroll
    for (int pf = 0; pf < 4; ++pf) {
        f32x4 cr[2] = {zz, zz}, cim[2] = {zz, zz};
        if (valid) {
            bf16x8 br[2], bi[2];
#pragma unroll
            for (int ks = 0; ks < 2; ++ks) {
                size_t boff = (size_t)(w * 256 + wv * 64 + pf * 16 + l15) * 64
                              + 32 * ks + 8 * l4;
                br[ks] = *(const bf16x8*)&xTr[boff];
                bi[ks] = *(const bf16x8*)&xTi[boff];
            }
#pragma unroll
            for (int ks = 0; ks < 2; ++ks)
#pragma unroll
                for (int cf = 0; cf < 2; ++cf) {
                    cr[cf]  = __builtin_amdgcn_mfma_f32_16x16x32_bf16(Ar[cf][ks], br[ks], cr[cf], 0, 0, 0);
                    cr[cf]  = __builtin_amdgcn_mfma_f32_16x16x32_bf16(An[cf][ks], bi[ks], cr[cf], 0, 0, 0);
                    cim[cf] = __builtin_amdgcn_mfma_f32_16x16x32_bf16(Ai[cf][ks], br[ks], cim[cf], 0, 0, 0);
                    cim[cf] = __builtin_amdgcn_mfma_f32_16x16x32_bf16(Ar[cf][ks], bi[ks], cim[cf], 0, 0, 0);
                }
        }
        int tok = wv * 64 + pf * 16 + l15;           // local token 0..255
#pragma unroll
        for (int cf = 0; cf < 2; ++cf)
#pragma unroll
            for (int r = 0; r < 4; ++r) {
                int col = 16 * cf + 4 * l4 + r;      // local co 0..31
                Tep[col * 257 + tok] = valid ? cvtpk(cr[cf][r], cim[cf][r]) : 0u;
            }
    }

    __syncthreads();
    const int co_l = t & 31, seg = (t >> 5) << 5;    // 8 segments of 32 tokens
    u32 vb[32];
#pragma unroll
    for (int jj = 0; jj < 32; ++jj) vb[jj] = Tep[co_l * 257 + seg + jj];
    uint4* dst = (uint4*)&qs[(size_t)(cog * 32 + co_l) * SPZ + rt * 256 + seg];
#pragma unroll
    for (int jj = 0; jj < 8; ++jj)
        dst[jj] = make_uint4(vb[4 * jj], vb[4 * jj + 1], vb[4 * jj + 2], vb[4 * jj + 3]);
}

// ---------------- Kernel B: depthwise 3x3 complex conv, 4 pixels/thread ----------------
// wave == one image row; uint4 loads + shfl halo. ch uniform per block.
__global__ __launch_bounds__(256) void k_dw(const u32* __restrict__ qs,
                                            const float* __restrict__ wr,
                                            const float* __restrict__ wi,
                                            u16* __restrict__ dwp,
                                            u32* __restrict__ vpack,
                                            size_t qsst, size_t dst, size_t vst) {
    const int b = blockIdx.z;
    qs += (size_t)b * qsst; dwp += (size_t)b * dst; vpack += (size_t)b * vst;
    const int ch = blockIdx.x >> 6;                         // uniform -> s_loads
    const int p4 = (((blockIdx.x & 63) << 8) + threadIdx.x) << 2;
    const int r = p4 >> 8, h = p4 & 255;                    // h = 4*laneInRow
    const u32* src = qs + (size_t)ch * SPZ + r * 256;

    float wrl[9], wil[9];
#pragma unroll
    for (int tt = 0; tt < 9; ++tt) { wrl[tt] = wr[ch * 9 + tt]; wil[tt] = wi[ch * 9 + tt]; }

    u32 uv[3][6];
#pragma unroll
    for (int du = 0; du < 3; ++du) {
        uint4 W = *(const uint4*)&src[du * 256 + h];        // coalesced 16B/lane
        u32 left  = (u32)__shfl_up((int)W.w, 1);            // word at h-1
        u32 right = (u32)__shfl_down((int)W.x, 1);          // word at h+4
        if (h == 0)   left = 0u;
        if (h == 252) right = 0u;
        uv[du][0] = left;  uv[du][1] = W.x; uv[du][2] = W.y;
        uv[du][3] = W.z;   uv[du][4] = W.w; uv[du][5] = right;
    }
    float vr[3][6], vi[3][6];
#pragma unroll
    for (int du = 0; du < 3; ++du)
#pragma unroll
        for (int j = 0; j < 6; ++j) {
            vr[du][j] = bf2f(uv[du][j] & 0xffffu);
            vi[du][j] = bf2f(uv[du][j] >> 16);
        }

    float ar[4] = {0.f, 0.f, 0.f, 0.f}, ai[4] = {0.f, 0.f, 0.f, 0.f};
#pragma unroll
    for (int du = 0; du < 3; ++du)
#pragma unroll
        for (int ct = 0; ct < 3; ++ct) {
            float w0 = wrl[du * 3 + ct], w1 = wil[du * 3 + ct];
#pragma unroll
            for (int px = 0; px < 4; ++px) {
                float xr = vr[du][px + ct], xi = vi[du][px + ct];
                ar[px] = fmaf(w0, xr, ar[px]); ar[px] = fmaf(-w1, xi, ar[px]);
                ai[px] = fmaf(w1, xr, ai[px]); ai[px] = fmaf(w0, xi, ai[px]);
            }
        }

    if (ch < 128) {
        int pl = (ch < 64) ? 0 : 2;
        int c2 = ch & 63;
        uint2 rw = make_uint2(cvtpk(ar[0], ar[1]), cvtpk(ar[2], ar[3]));
        uint2 iw = make_uint2(cvtpk(ai[0], ai[1]), cvtpk(ai[2], ai[3]));
        *(uint2*)&dwp[(size_t)(pl * 64 + c2) * HWS + p4] = rw;
        *(uint2*)&dwp[(size_t)((pl + 1) * 64 + c2) * HWS + p4] = iw;
    } else {
        int e = ch - 128;
        uint4 vv = make_uint4(cvtpk(ar[0], ai[0]), cvtpk(ar[1], ai[1]),
                              cvtpk(ar[2], ai[2]), cvtpk(ar[3], ai[3]));
        *(uint4*)&vpack[(size_t)e * HWS + p4] = vv;
    }
}

// ---------------- Kernel C: q k^T + fused sumsq via MFMA (no LDS) ----------------
// grid (64 chunks, 2 d, nb)
__global__ __launch_bounds__(256) void k_qk(const u16* __restrict__ dwp,
                                            float* __restrict__ rnsum,
                                            float* __restrict__ attn,
                                            int b0, size_t dst) {
    const int z = blockIdx.z;
    const int b = b0 + z;
    dwp += (size_t)z * dst;
    const int chunk = blockIdx.x;        // 0..63
    const int d = blockIdx.y;
    const int Kc = HWS >> 6;
    const int kc0 = chunk * Kc;
    const u16* qp = dwp + (size_t)d * 64 * HWS;
    const u16* kp = dwp + (size_t)(2 + d) * 64 * HWS;

    const int t = threadIdx.x, lane = t & 63, wid = t >> 6;
    const int wy = wid >> 1, wx = wid & 1;
    const int l15 = lane & 15, l4 = lane >> 4;

    f32x4 zz = {0.f, 0.f, 0.f, 0.f};
    f32x4 acc[2][2] = {{zz, zz}, {zz, zz}};
    float sq[2] = {0.f, 0.f}, sk[2] = {0.f, 0.f};

    const int iters = Kc >> 5;
    for (int ks = 0; ks < iters; ++ks) {
        int k0 = kc0 + ks * 32 + 8 * l4;
        bf16x8 aq[2], bk[2];
#pragma unroll
        for (int cf = 0; cf < 2; ++cf)
            aq[cf] = *(const bf16x8*)&qp[(size_t)(32 * wy + 16 * cf + l15) * HWS + k0];
#pragma unroll
        for (int ef = 0; ef < 2; ++ef)
            bk[ef] = *(const bf16x8*)&kp[(size_t)(32 * wx + 16 * ef + l15) * HWS + k0];

        if (wx == 0)
#pragma unroll
            for (int cf = 0; cf < 2; ++cf)
#pragma unroll
                for (int j = 0; j < 8; ++j) {
                    float f = bf2f((u16)aq[cf][j]);
                    sq[cf] = fmaf(f, f, sq[cf]);
                }
        if (wy == 0)
#pragma unroll
            for (int ef = 0; ef < 2; ++ef)
#pragma unroll
                for (int j = 0; j < 8; ++j) {
                    float f = bf2f((u16)bk[ef][j]);
                    sk[ef] = fmaf(f, f, sk[ef]);
                }

#pragma unroll
        for (int cf = 0; cf < 2; ++cf)
#pragma unroll
            for (int ef = 0; ef < 2; ++ef)
                acc[cf][ef] = __builtin_amdgcn_mfma_f32_16x16x32_bf16(aq[cf], bk[ef], acc[cf][ef], 0, 0, 0);
    }

#pragma unroll
    for (int cf = 0; cf < 2; ++cf)
#pragma unroll
        for (int ef = 0; ef < 2; ++ef)
#pragma unroll
            for (int r = 0; r < 4; ++r) {
                int cq = 32 * wy + 16 * cf + 4 * l4 + r;
                int ce = 32 * wx + 16 * ef + l15;
                atomicAdd(&attn[((b * 2 + d) * 64 + cq) * 64 + ce], acc[cf][ef][r]);
            }

    if (wx == 0)
#pragma unroll
        for (int cf = 0; cf < 2; ++cf) {
            float v = sq[cf];
            v += __shfl_xor(v, 16);
            v += __shfl_xor(v, 32);
            if (lane < 16)
                atomicAdd(&rnsum[((size_t)b * 128 + 32 * wy + 16 * cf + lane) * 2 + d], v);
        }
    if (wy == 0)
#pragma unroll
        for (int ef = 0; ef < 2; ++ef) {
            float v = sk[ef];
            v += __shfl_xor(v, 16);
            v += __shfl_xor(v, 32);
            if (lane < 16)
                atomicAdd(&rnsum[((size_t)b * 128 + 64 + 32 * wx + 16 * ef + lane) * 2 + d], v);
        }
}

// ---------------- Kernel D1: scale + row softmax -> P (grid (2 d, nb), 64 thr) ----------------
__global__ __launch_bounds__(64) void k_prob(const float* __restrict__ attn,
                                             const float* __restrict__ rnsum,
                                             float* __restrict__ P, int b0) {
    int d = blockIdx.x;
    int b = b0 + blockIdx.y;
    int t = threadIdx.x;
    __shared__ float rks[64];
    float sk = rnsum[((size_t)b * 128 + 64 + t) * 2 + d];
    rks[t] = 1.0f / fmaxf(sqrtf(sk), 1e-12f);
    float sq = rnsum[((size_t)b * 128 + t) * 2 + d];
    float rq = 1.0f / fmaxf(sqrtf(sq), 1e-12f);
    __syncthreads();

    const float* arow = attn + ((size_t)(b * 2 + d) * 64 + t) * 64;
    float v[64];
    float m = -1e30f;
#pragma unroll
    for (int e = 0; e < 64; ++e) { v[e] = arow[e] * rq * rks[e]; m = fmaxf(m, v[e]); }
    float ssum = 0.f;
#pragma unroll
    for (int e = 0; e < 64; ++e) { v[e] = __expf(v[e] - m); ssum += v[e]; }
    float r = 1.0f / ssum;
    float* prow = P + ((size_t)(b * 2 + d) * 64 + t) * 64;
#pragma unroll
    for (int e = 0; e < 64; ++e) prow[e] = v[e] * r;
}

// ---------------- Kernel D2: build A_big from P and proj weights (grid (16, nb)) ----------------
__global__ __launch_bounds__(256) void k_M(const float* __restrict__ P,
                                           const float* __restrict__ pwr,
                                           const float* __restrict__ pwi,
                                           u16* __restrict__ Abig, int b0) {
    int b = b0 + blockIdx.y;
    int pair = blockIdx.x * 256 + threadIdx.x;   // 0..4095
    __shared__ float P0[64][64], P1[64][64];
    __shared__ float Wr[64][64], Wi2[64][64];
    for (int i = threadIdx.x; i < 4096; i += 256) {
        P0[i >> 6][i & 63] = P[(size_t)(b * 2 + 0) * 4096 + i];
        P1[i >> 6][i & 63] = P[(size_t)(b * 2 + 1) * 4096 + i];
        Wr[i >> 6][i & 63] = pwr[i];
        Wi2[i >> 6][i & 63] = pwi[i];
    }
    __syncthreads();
    int co = pair >> 6, e = pair & 63;
    float m1 = 0.f, m2 = 0.f, m3 = 0.f, m4 = 0.f;
#pragma unroll 8
    for (int c = 0; c < 64; ++c) {
        float pr = Wr[co][c], pi = Wi2[co][c];
        float a0 = P0[c][e], a1 = P1[c][e];
        m1 = fmaf(pr, a0, m1);
        m2 = fmaf(pi, a1, m2);
        m3 = fmaf(pr, a1, m3);
        m4 = fmaf(pi, a0, m4);
    }
    u16* AB = Abig + (size_t)b * 16384;
    AB[(2 * co) * 128 + 2 * e]         = f2bf(m1);
    AB[(2 * co) * 128 + 2 * e + 1]     = f2bf(-m2);
    AB[(2 * co + 1) * 128 + 2 * e]     = f2bf(m4);
    AB[(2 * co + 1) * 128 + 2 * e + 1] = f2bf(m3);
}

// ---------------- Kernel E (fallback): transpose vpack [64][HWS] u32 -> vT [HWS][64] u32 ----------------
__global__ __launch_bounds__(256) void k_vt(const u32* __restrict__ in,
                                            u32* __restrict__ outp) {
    __shared__ u32 tile[64][65];
    int p0 = blockIdx.x << 6;
    int t = threadIdx.x;
    for (int i = t; i < 4096; i += 256) {
        int e = i >> 6, c = i & 63;
        tile[e][c] = in[(size_t)e * HWS + p0 + c];
    }
    __syncthreads();
    for (int i = t; i < 4096; i += 256) {
        int r = i >> 6, e = i & 63;
        outp[(size_t)(p0 + r) * 64 + e] = tile[e][r];
    }
}

// ---------------- Kernel F (fallback): out = A_big * vT via MFMA (no LDS) ----------------
__global__ __launch_bounds__(256) void k_out(const u16* __restrict__ Abig,
                                             const u16* __restrict__ vT,
                                             float* __restrict__ outb) {
    const int p0 = blockIdx.x << 6;
    const int t = threadIdx.x, lane = t & 63, w = t >> 6;
    const int l15 = lane & 15, l4 = lane >> 4;

    bf16x8 Af[2][4];
#pragma unroll
    for (int cf = 0; cf < 2; ++cf)
#pragma unroll
        for (int ks = 0; ks < 4; ++ks)
            Af[cf][ks] = *(const bf16x8*)&Abig[(size_t)(32 * w + 16 * cf + l15) * 128 + 32 * ks + 8 * l4];

    f32x4 zz = {0.f, 0.f, 0.f, 0.f};
    f32x4 acc[2][4];
#pragma unroll
    for (int cf = 0; cf < 2; ++cf)
#pragma unroll
        for (int nf = 0; nf < 4; ++nf) acc[cf][nf] = zz;

#pragma unroll
    for (int ks = 0; ks < 4; ++ks) {
        bf16x8 Bf[4];
#pragma unroll
        for (int nf = 0; nf < 4; ++nf)
            Bf[nf] = *(const bf16x8*)&vT[(size_t)(p0 + 16 * nf + l15) * 128 + 32 * ks + 8 * l4];
#pragma unroll
        for (int cf = 0; cf < 2; ++cf)
#pragma unroll
            for (int nf = 0; nf < 4; ++nf)
                acc[cf][nf] = __builtin_amdgcn_mfma_f32_16x16x32_bf16(Af[cf][ks], Bf[nf], acc[cf][nf], 0, 0, 0);
    }

    float2* o2 = (float2*)outb;
#pragma unroll
    for (int cf = 0; cf < 2; ++cf)
#pragma unroll
        for (int nf = 0; nf < 4; ++nf) {
            int co = 16 * w + 8 * cf + 2 * l4;
            int p = p0 + 16 * nf + l15;
            o2[(size_t)co * HWS + p]       = make_float2(acc[cf][nf][0], acc[cf][nf][1]);
            o2[(size_t)(co + 1) * HWS + p] = make_float2(acc[cf][nf][2], acc[cf][nf][3]);
        }
}

// ---------------- Kernel F2: out = A_big * v via LDS-staged vpack ----------------
__global__ __launch_bounds__(256) void k_out2(const u16* __restrict__ Abig,
                                              const u32* __restrict__ vpk,
                                              float* __restrict__ outb,
                                              int b0, size_t vst, size_t ost) {
    const int z = blockIdx.z;
    const int b = b0 + z;
    vpk += (size_t)z * vst; outb += (size_t)z * ost;
    __shared__ u32 Tep[64][65];
    const int p0 = blockIdx.x << 6;
    const int t = threadIdx.x, lane = t & 63, w = t >> 6;
    const int l15 = lane & 15, l4 = lane >> 4;
    const u16* AB = Abig + (size_t)b * 16384;

    bf16x8 Af[2][4];
#pragma unroll
    for (int cf = 0; cf < 2; ++cf)
#pragma unroll
        for (int ks = 0; ks < 4; ++ks)
            Af[cf][ks] = *(const bf16x8*)&AB[(size_t)(32 * w + 16 * cf + l15) * 128 + 32 * ks + 8 * l4];

    for (int i = t; i < 4096; i += 256) {
        int e = i >> 6, tok = i & 63;
        Tep[e][tok] = vpk[(size_t)e * HWS + p0 + tok];
    }
    __syncthreads();

    f32x4 zz = {0.f, 0.f, 0.f, 0.f};
    f32x4 acc[2][4];
#pragma unroll
    for (int cf = 0; cf < 2; ++cf)
#pragma unroll
        for (int nf = 0; nf < 4; ++nf) acc[cf][nf] = zz;

#pragma unroll
    for (int ks = 0; ks < 4; ++ks) {
        bf16x8 Bf[4];
#pragma unroll
        for (int nf = 0; nf < 4; ++nf) {
            int tok = 16 * nf + l15;
            int e0 = 16 * ks + 4 * l4;
            union { u32 u[4]; bf16x8 v; } bb;
#pragma unroll
            for (int j = 0; j < 4; ++j) bb.u[j] = Tep[e0 + j][tok];
            Bf[nf] = bb.v;
        }
#pragma unroll
        for (int cf = 0; cf < 2; ++cf)
#pragma unroll
            for (int nf = 0; nf < 4; ++nf)
                acc[cf][nf] = __builtin_amdgcn_mfma_f32_16x16x32_bf16(Af[cf][ks], Bf[nf], acc[cf][nf], 0, 0, 0);
    }

    float2* o2 = (float2*)outb;
#pragma unroll
    for (int cf = 0; cf < 2; ++cf)
#pragma unroll
        for (int nf = 0; nf < 4; ++nf) {
            int co = 16 * w + 8 * cf + 2 * l4;
            int p = p0 + 16 * nf + l15;
            o2[(size_t)co * HWS + p]       = make_float2(acc[cf][nf][0], acc[cf][nf][1]);
            o2[(size_t)(co + 1) * HWS + p] = make_float2(acc[cf][nf][2], acc[cf][nf][3]);
        }
}

extern "C" void kernel_launch(void* const* d_in, const int* in_sizes, int n_in,
                              void* d_out, int out_size, void* d_ws, size_t ws_size,
                              hipStream_t stream) {
    const float* x      = (const float*)d_in[0];
    const float* qkv_wr = (const float*)d_in[1];
    const float* qkv_wi = (const float*)d_in[2];
    const float* dw_wr  = (const float*)d_in[3];
    const float* dw_wi  = (const float*)d_in[4];
    const float* p_wr   = (const float*)d_in[5];
    const float* p_wi   = (const float*)d_in[6];
    float* out = (float*)d_out;
    const size_t OSTR = (size_t)64 * HWS * 2;   // floats per batch of output

    const bool z2  = ws_size >= 236000000ull;   // fully per-b-strided buffers
    const bool f14 = !z2 && ws_size >= 118200000ull;

    char* base = (char*)d_ws;

    if (z2) {
        // per-b strided layout (~235.9 MB)
        u32*   qs   = (u32*)base;                          // 2 x 50,724,864 B
        u16*   dwp  = (u16*)(base + 101449728);            // 2 x 33,554,432 B
        u16*   xTr  = (u16*)(base + 168558592);            // 2 x (8.39+8.39) MB
        u16*   xTi  = xTr + (size_t)HWS * 64;
        u32*   vpk  = (u32*)(base + 202113024);            // 2 x 16,777,216 B
        u16*   wbf  = (u16*)(base + 235667456);
        float* rnsum = (float*)(base + 235741184);
        float* attn  = rnsum + 512;
        float* Pbuf  = attn + 16384;
        u16*   Abig  = (u16*)(Pbuf + 16384);

        const size_t XT_ST = 8388608;     // u16 per b (both planes)
        const size_t QS_ST = 12681216;    // u32 per b
        const size_t DW_ST = 16777216;    // u16 per b
        const size_t VP_ST = 4194304;     // u32 per b

        k_prep<<<66, 256, 0, stream>>>(qkv_wr, qkv_wi, wbf, rnsum, 512 + 16384);
        k_xt<<<dim3(1024, 1, 2), 256, 0, stream>>>(x, xTr, xTi, OSTR, XT_ST);
        // NPR = 516 row-pairs; grid = 8*6*ceil(516/8) = 3120
        k_qkv<<<3120, 256, 0, stream>>>(xTr, xTi, wbf, qs, XT_ST, QS_ST, 516);
        k_dw<<<dim3(12288, 1, 2), 256, 0, stream>>>(qs, dw_wr, dw_wi, dwp, vpk,
                                                    QS_ST, DW_ST, VP_ST);
        k_qk<<<dim3(64, 2, 2), 256, 0, stream>>>(dwp, rnsum, attn, 0, DW_ST);
        k_prob<<<dim3(2, 2), 64, 0, stream>>>(attn, rnsum, Pbuf, 0);
        k_M<<<dim3(16, 2), 256, 0, stream>>>(Pbuf, p_wr, p_wi, Abig, 0);
        k_out2<<<dim3(1024, 1, 2), 256, 0, stream>>>(Abig, vpk, out, 0, VP_ST, OSTR);
        return;
    }

    // shared-buffer layouts (round-14 / round-13 proven paths)
    u32*   qs   = (u32*)base;                               // 50,724,864 B
    u16*   dwp  = (u16*)(base + 50724864);                  // 33,554,432 B
    char*  xreg = base + 50724864 + 33554432;               // 16,777,216 B
    u16*   xTr  = (u16*)xreg;
    u16*   xTi  = xTr + (size_t)HWS * 64;
    u32*   vT   = (u32*)xreg;                               // fallback-13: vT aliases xT
    u32*   vpkW = (u32*)(base + 101056512);                 // f14 only
    size_t tail = f14 ? 117833728ull : 101056512ull;
    u16*   wbf  = (u16*)(base + tail);
    float* rnsum = (float*)(base + tail + 73728);
    float* attn  = rnsum + 512;
    float* Pbuf  = attn + 16384;
    u16*   Abig  = (u16*)(Pbuf + 16384);

    k_prep<<<66, 256, 0, stream>>>(qkv_wr, qkv_wi, wbf, rnsum, 512 + 16384);

    for (int b = 0; b < 2; ++b) {
        const float* xb = x + (size_t)b * OSTR;
        u32* vpack = f14 ? vpkW : (u32*)(out + (size_t)b * OSTR);
        k_xt<<<dim3(1024, 1, 1), 256, 0, stream>>>(xb, xTr, xTi, 0, 0);
        // NPR = 258; grid = 8*6*ceil(258/8) = 1584
        k_qkv<<<1584, 256, 0, stream>>>(xTr, xTi, wbf, qs, 0, 0, 258);
        k_dw<<<dim3(12288, 1, 1), 256, 0, stream>>>(qs, dw_wr, dw_wi, dwp, vpack, 0, 0, 0);
        k_qk<<<dim3(64, 2, 1), 256, 0, stream>>>(dwp, rnsum, attn, b, 0);
        k_prob<<<dim3(2, 1), 64, 0, stream>>>(attn, rnsum, Pbuf, b);
        k_M<<<dim3(16, 1), 256, 0, stream>>>(Pbuf, p_wr, p_wi, Abig, b);
        if (f14)
            k_out2<<<dim3(1024, 1, 1), 256, 0, stream>>>(Abig, vpkW,
                                                         out + (size_t)b * OSTR, b, 0, 0);
    }
    if (!f14) {
        for (int b = 0; b < 2; ++b) {
            u32* vpack = (u32*)(out + (size_t)b * OSTR);
            k_vt<<<1024, 256, 0, stream>>>(vpack, vT);
            k_out<<<1024, 256, 0, stream>>>(Abig + (size_t)b * 16384, (const u16*)vT,
                                            out + (size_t)b * OSTR);
        }
    }
}

// Round 20
// 179.625 us; speedup vs baseline: 1.1836x; 1.1836x over previous
//
#include <hip/hip_runtime.h>

#define HWS 65536   // 256*256
#define SPZ 66048   // (256+2)*256 halo strip positions

typedef __attribute__((ext_vector_type(8))) short bf16x8;
typedef __attribute__((ext_vector_type(4))) float f32x4;
typedef unsigned int u32;
typedef unsigned short u16;

__device__ __forceinline__ u16 f2bf(float x) {
    u32 u = __float_as_uint(x);
    return (u16)((u + 0x7fffu + ((u >> 16) & 1u)) >> 16);
}
__device__ __forceinline__ float bf2f(u32 h) { return __uint_as_float(h << 16); }
// HW packed bf16 convert (RNE, identical rounding to f2bf): lo=a, hi=b
__device__ __forceinline__ u32 cvtpk(float a, float b) {
    u32 r;
    asm("v_cvt_pk_bf16_f32 %0, %1, %2" : "=v"(r) : "v"(a), "v"(b));
    return r;
}

// ---------------- prep: weight cvt + zero accumulators (one launch) ----------------
__global__ void k_prep(const float* __restrict__ wr, const float* __restrict__ wi,
                       u16* __restrict__ wbf, float* __restrict__ zbuf, int nz) {
    int i = blockIdx.x * 256 + threadIdx.x;
    if (i < 12288) {
        wbf[i]         = f2bf(wr[i]);
        wbf[12288 + i] = f2bf(wi[i]);
        wbf[24576 + i] = f2bf(-wi[i]);
    }
    if (i < nz) zbuf[i] = 0.f;
}

// ---------------- Kernel X: transpose+convert x -> xTr/xTi bf16 [HWS][64] ----------------
__global__ __launch_bounds__(256) void k_xt(const float* __restrict__ x,
                                            u16* __restrict__ xTr,
                                            u16* __restrict__ xTi,
                                            size_t xs, size_t ts) {
    const int b = blockIdx.z;
    x += (size_t)b * xs; xTr += (size_t)b * ts; xTi += (size_t)b * ts;
    __shared__ u16 Tr[64][74], Ti[64][74];
    int p0 = blockIdx.x << 6;
    int t = threadIdx.x;
    const float2* x2 = (const float2*)x;
    for (int i = t; i < 2048; i += 256) {        // (ci-pair, c)
        int cp = i >> 6, c = i & 63;
        int ci = cp << 1;
        float2 v0 = x2[(size_t)ci * HWS + p0 + c];
        float2 v1 = x2[(size_t)(ci + 1) * HWS + p0 + c];
        *(u32*)&Tr[c][ci] = cvtpk(v0.x, v1.x);
        *(u32*)&Ti[c][ci] = cvtpk(v0.y, v1.y);
    }
    __syncthreads();
    for (int i = t; i < 2048; i += 256) {        // (row, ci-pair)
        int rr = i >> 5, cp = i & 31;
        *(u32*)&xTr[(size_t)(p0 + rr) * 64 + 2 * cp] = *(u32*)&Tr[rr][2 * cp];
        *(u32*)&xTi[(size_t)(p0 + rr) * 64 + 2 * cp] = *(u32*)&Ti[rr][2 * cp];
    }
}

// ---------------- Kernel A: qkv 1x1 complex conv, global->MFMA, LDS epilogue ----------------
// 1D grid, XCD-swizzled. Epilogue: Tep pitch 260 (2-way-free writes), wave-row
// uint4 reads (stride-16B, conflict-free) -> 1KB contiguous row stores.
__global__ __launch_bounds__(256) void k_qkv(const u16* __restrict__ xTr,
                                             const u16* __restrict__ xTi,
                                             const u16* __restrict__ wbf,
                                             u32* __restrict__ qs,
                                             size_t ts, size_t qsst, int NPR) {
    __shared__ u32 Tep[32 * 260];    // 33280 B, rows 16B-aligned
    const int bid = blockIdx.x;
    const int xcd = bid & 7, j = bid >> 3;
    const int cog = j % 6;               // 0..5, 32 co each
    const int pr  = xcd + 8 * (j / 6);   // row-pair index
    if (pr >= NPR) return;
    const int z  = pr / 258;
    const int rt = pr % 258;             // 0..257
    xTr += (size_t)z * ts; xTi += (size_t)z * ts; qs += (size_t)z * qsst;
    const int w = rt - 1;                // image row (may be OOB -> zeros)
    const int t = threadIdx.x, lane = t & 63, wv = t >> 6;
    const int l15 = lane & 15, l4 = lane >> 4;
    const bool valid = (unsigned)w < 256u;

    bf16x8 Ar[2][2], Ai[2][2], An[2][2];
#pragma unroll
    for (int cf = 0; cf < 2; ++cf)
#pragma unroll
        for (int ks = 0; ks < 2; ++ks) {
            size_t off = (size_t)(cog * 32 + 16 * cf + l15) * 64 + 32 * ks + 8 * l4;
            Ar[cf][ks] = *(const bf16x8*)&wbf[off];
            Ai[cf][ks] = *(const bf16x8*)&wbf[12288 + off];
            An[cf][ks] = *(const bf16x8*)&wbf[24576 + off];
        }

    const f32x4 zz = {0.f, 0.f, 0.f, 0.f};
#pragma unroll
    for (int pf = 0; pf < 4; ++pf) {
        f32x4 cr[2] = {zz, zz}, cim[2] = {zz, zz};
        if (valid) {
            bf16x8 br[2], bi[2];
#pragma unroll
            for (int ks = 0; ks < 2; ++ks) {
                size_t boff = (size_t)(w * 256 + wv * 64 + pf * 16 + l15) * 64
                              + 32 * ks + 8 * l4;
                br[ks] = *(const bf16x8*)&xTr[boff];
                bi[ks] = *(const bf16x8*)&xTi[boff];
            }
#pragma unroll
            for (int ks = 0; ks < 2; ++ks)
#pragma unroll
                for (int cf = 0; cf < 2; ++cf) {
                    cr[cf]  = __builtin_amdgcn_mfma_f32_16x16x32_bf16(Ar[cf][ks], br[ks], cr[cf], 0, 0, 0);
                    cr[cf]  = __builtin_amdgcn_mfma_f32_16x16x32_bf16(An[cf][ks], bi[ks], cr[cf], 0, 0, 0);
                    cim[cf] = __builtin_amdgcn_mfma_f32_16x16x32_bf16(Ai[cf][ks], br[ks], cim[cf], 0, 0, 0);
                    cim[cf] = __builtin_amdgcn_mfma_f32_16x16x32_bf16(Ar[cf][ks], bi[ks], cim[cf], 0, 0, 0);
                }
        }
        int tok = wv * 64 + pf * 16 + l15;           // local token 0..255
#pragma unroll
        for (int cf = 0; cf < 2; ++cf)
#pragma unroll
            for (int r = 0; r < 4; ++r) {
                int col = 16 * cf + 4 * l4 + r;      // local co 0..31
                Tep[col * 260 + tok] = valid ? cvtpk(cr[cf][r], cim[cf][r]) : 0u;
            }
    }

    __syncthreads();
    // wave wv handles rows co = wv + 4k: 64 lanes x uint4 = 1KB contiguous store
#pragma unroll
    for (int k = 0; k < 8; ++k) {
        int co = wv + 4 * k;
        uint4 vv = *(const uint4*)&Tep[co * 260 + 4 * lane];
        *(uint4*)&qs[(size_t)(cog * 32 + co) * SPZ + rt * 256 + 4 * lane] = vv;
    }
}

// ---------------- Kernel B: depthwise 3x3 complex conv, 4 pixels/thread ----------------
// wave == one image row; uint4 loads + shfl halo. ch uniform per block.
__global__ __launch_bounds__(256) void k_dw(const u32* __restrict__ qs,
                                            const float* __restrict__ wr,
                                            const float* __restrict__ wi,
                                            u16* __restrict__ dwp,
                                            u32* __restrict__ vpack,
                                            size_t qsst, size_t dst, size_t vst) {
    const int b = blockIdx.z;
    qs += (size_t)b * qsst; dwp += (size_t)b * dst; vpack += (size_t)b * vst;
    const int ch = blockIdx.x >> 6;                         // uniform -> s_loads
    const int p4 = (((blockIdx.x & 63) << 8) + threadIdx.x) << 2;
    const int r = p4 >> 8, h = p4 & 255;                    // h = 4*laneInRow
    const u32* src = qs + (size_t)ch * SPZ + r * 256;

    float wrl[9], wil[9];
#pragma unroll
    for (int tt = 0; tt < 9; ++tt) { wrl[tt] = wr[ch * 9 + tt]; wil[tt] = wi[ch * 9 + tt]; }

    u32 uv[3][6];
#pragma unroll
    for (int du = 0; du < 3; ++du) {
        uint4 W = *(const uint4*)&src[du * 256 + h];        // coalesced 16B/lane
        u32 left  = (u32)__shfl_up((int)W.w, 1);            // word at h-1
        u32 right = (u32)__shfl_down((int)W.x, 1);          // word at h+4
        if (h == 0)   left = 0u;
        if (h == 252) right = 0u;
        uv[du][0] = left;  uv[du][1] = W.x; uv[du][2] = W.y;
        uv[du][3] = W.z;   uv[du][4] = W.w; uv[du][5] = right;
    }
    float vr[3][6], vi[3][6];
#pragma unroll
    for (int du = 0; du < 3; ++du)
#pragma unroll
        for (int j = 0; j < 6; ++j) {
            vr[du][j] = bf2f(uv[du][j] & 0xffffu);
            vi[du][j] = bf2f(uv[du][j] >> 16);
        }

    float ar[4] = {0.f, 0.f, 0.f, 0.f}, ai[4] = {0.f, 0.f, 0.f, 0.f};
#pragma unroll
    for (int du = 0; du < 3; ++du)
#pragma unroll
        for (int ct = 0; ct < 3; ++ct) {
            float w0 = wrl[du * 3 + ct], w1 = wil[du * 3 + ct];
#pragma unroll
            for (int px = 0; px < 4; ++px) {
                float xr = vr[du][px + ct], xi = vi[du][px + ct];
                ar[px] = fmaf(w0, xr, ar[px]); ar[px] = fmaf(-w1, xi, ar[px]);
                ai[px] = fmaf(w1, xr, ai[px]); ai[px] = fmaf(w0, xi, ai[px]);
            }
        }

    if (ch < 128) {
        int pl = (ch < 64) ? 0 : 2;
        int c2 = ch & 63;
        uint2 rw = make_uint2(cvtpk(ar[0], ar[1]), cvtpk(ar[2], ar[3]));
        uint2 iw = make_uint2(cvtpk(ai[0], ai[1]), cvtpk(ai[2], ai[3]));
        *(uint2*)&dwp[(size_t)(pl * 64 + c2) * HWS + p4] = rw;
        *(uint2*)&dwp[(size_t)((pl + 1) * 64 + c2) * HWS + p4] = iw;
    } else {
        int e = ch - 128;
        uint4 vv = make_uint4(cvtpk(ar[0], ai[0]), cvtpk(ar[1], ai[1]),
                              cvtpk(ar[2], ai[2]), cvtpk(ar[3], ai[3]));
        *(uint4*)&vpack[(size_t)e * HWS + p4] = vv;
    }
}

// ---------------- Kernel C: q k^T + fused sumsq via MFMA (no LDS) ----------------
// grid (64 chunks, 2 d, nb)
__global__ __launch_bounds__(256) void k_qk(const u16* __restrict__ dwp,
                                            float* __restrict__ rnsum,
                                            float* __restrict__ attn,
                                            int b0, size_t dst) {
    const int z = blockIdx.z;
    const int b = b0 + z;
    dwp += (size_t)z * dst;
    const int chunk = blockIdx.x;        // 0..63
    const int d = blockIdx.y;
    const int Kc = HWS >> 6;
    const int kc0 = chunk * Kc;
    const u16* qp = dwp + (size_t)d * 64 * HWS;
    const u16* kp = dwp + (size_t)(2 + d) * 64 * HWS;

    const int t = threadIdx.x, lane = t & 63, wid = t >> 6;
    const int wy = wid >> 1, wx = wid & 1;
    const int l15 = lane & 15, l4 = lane >> 4;

    f32x4 zz = {0.f, 0.f, 0.f, 0.f};
    f32x4 acc[2][2] = {{zz, zz}, {zz, zz}};
    float sq[2] = {0.f, 0.f}, sk[2] = {0.f, 0.f};

    const int iters = Kc >> 5;
    for (int ks = 0; ks < iters; ++ks) {
        int k0 = kc0 + ks * 32 + 8 * l4;
        bf16x8 aq[2], bk[2];
#pragma unroll
        for (int cf = 0; cf < 2; ++cf)
            aq[cf] = *(const bf16x8*)&qp[(size_t)(32 * wy + 16 * cf + l15) * HWS + k0];
#pragma unroll
        for (int ef = 0; ef < 2; ++ef)
            bk[ef] = *(const bf16x8*)&kp[(size_t)(32 * wx + 16 * ef + l15) * HWS + k0];

        if (wx == 0)
#pragma unroll
            for (int cf = 0; cf < 2; ++cf)
#pragma unroll
                for (int j = 0; j < 8; ++j) {
                    float f = bf2f((u16)aq[cf][j]);
                    sq[cf] = fmaf(f, f, sq[cf]);
                }
        if (wy == 0)
#pragma unroll
            for (int ef = 0; ef < 2; ++ef)
#pragma unroll
                for (int j = 0; j < 8; ++j) {
                    float f = bf2f((u16)bk[ef][j]);
                    sk[ef] = fmaf(f, f, sk[ef]);
                }

#pragma unroll
        for (int cf = 0; cf < 2; ++cf)
#pragma unroll
            for (int ef = 0; ef < 2; ++ef)
                acc[cf][ef] = __builtin_amdgcn_mfma_f32_16x16x32_bf16(aq[cf], bk[ef], acc[cf][ef], 0, 0, 0);
    }

#pragma unroll
    for (int cf = 0; cf < 2; ++cf)
#pragma unroll
        for (int ef = 0; ef < 2; ++ef)
#pragma unroll
            for (int r = 0; r < 4; ++r) {
                int cq = 32 * wy + 16 * cf + 4 * l4 + r;
                int ce = 32 * wx + 16 * ef + l15;
                atomicAdd(&attn[((b * 2 + d) * 64 + cq) * 64 + ce], acc[cf][ef][r]);
            }

    if (wx == 0)
#pragma unroll
        for (int cf = 0; cf < 2; ++cf) {
            float v = sq[cf];
            v += __shfl_xor(v, 16);
            v += __shfl_xor(v, 32);
            if (lane < 16)
                atomicAdd(&rnsum[((size_t)b * 128 + 32 * wy + 16 * cf + lane) * 2 + d], v);
        }
    if (wy == 0)
#pragma unroll
        for (int ef = 0; ef < 2; ++ef) {
            float v = sk[ef];
            v += __shfl_xor(v, 16);
            v += __shfl_xor(v, 32);
            if (lane < 16)
                atomicAdd(&rnsum[((size_t)b * 128 + 64 + 32 * wx + 16 * ef + lane) * 2 + d], v);
        }
}

// ---------------- Kernel D1: scale + row softmax -> P (grid (2 d, nb), 64 thr) ----------------
__global__ __launch_bounds__(64) void k_prob(const float* __restrict__ attn,
                                             const float* __restrict__ rnsum,
                                             float* __restrict__ P, int b0) {
    int d = blockIdx.x;
    int b = b0 + blockIdx.y;
    int t = threadIdx.x;
    __shared__ float rks[64];
    float sk = rnsum[((size_t)b * 128 + 64 + t) * 2 + d];
    rks[t] = 1.0f / fmaxf(sqrtf(sk), 1e-12f);
    float sq = rnsum[((size_t)b * 128 + t) * 2 + d];
    float rq = 1.0f / fmaxf(sqrtf(sq), 1e-12f);
    __syncthreads();

    const float* arow = attn + ((size_t)(b * 2 + d) * 64 + t) * 64;
    float v[64];
    float m = -1e30f;
#pragma unroll
    for (int e = 0; e < 64; ++e) { v[e] = arow[e] * rq * rks[e]; m = fmaxf(m, v[e]); }
    float ssum = 0.f;
#pragma unroll
    for (int e = 0; e < 64; ++e) { v[e] = __expf(v[e] - m); ssum += v[e]; }
    float r = 1.0f / ssum;
    float* prow = P + ((size_t)(b * 2 + d) * 64 + t) * 64;
#pragma unroll
    for (int e = 0; e < 64; ++e) prow[e] = v[e] * r;
}

// ---------------- Kernel D2: build A_big from P and proj weights (grid (16, nb)) ----------------
__global__ __launch_bounds__(256) void k_M(const float* __restrict__ P,
                                           const float* __restrict__ pwr,
                                           const float* __restrict__ pwi,
                                           u16* __restrict__ Abig, int b0) {
    int b = b0 + blockIdx.y;
    int pair = blockIdx.x * 256 + threadIdx.x;   // 0..4095
    __shared__ float P0[64][64], P1[64][64];
    __shared__ float Wr[64][64], Wi2[64][64];
    for (int i = threadIdx.x; i < 4096; i += 256) {
        P0[i >> 6][i & 63] = P[(size_t)(b * 2 + 0) * 4096 + i];
        P1[i >> 6][i & 63] = P[(size_t)(b * 2 + 1) * 4096 + i];
        Wr[i >> 6][i & 63] = pwr[i];
        Wi2[i >> 6][i & 63] = pwi[i];
    }
    __syncthreads();
    int co = pair >> 6, e = pair & 63;
    float m1 = 0.f, m2 = 0.f, m3 = 0.f, m4 = 0.f;
#pragma unroll 8
    for (int c = 0; c < 64; ++c) {
        float pr = Wr[co][c], pi = Wi2[co][c];
        float a0 = P0[c][e], a1 = P1[c][e];
        m1 = fmaf(pr, a0, m1);
        m2 = fmaf(pi, a1, m2);
        m3 = fmaf(pr, a1, m3);
        m4 = fmaf(pi, a0, m4);
    }
    u16* AB = Abig + (size_t)b * 16384;
    AB[(2 * co) * 128 + 2 * e]         = f2bf(m1);
    AB[(2 * co) * 128 + 2 * e + 1]     = f2bf(-m2);
    AB[(2 * co + 1) * 128 + 2 * e]     = f2bf(m4);
    AB[(2 * co + 1) * 128 + 2 * e + 1] = f2bf(m3);
}

// ---------------- Kernel E (fallback): transpose vpack [64][HWS] u32 -> vT [HWS][64] u32 ----------------
__global__ __launch_bounds__(256) void k_vt(const u32* __restrict__ in,
                                            u32* __restrict__ outp) {
    __shared__ u32 tile[64][65];
    int p0 = blockIdx.x << 6;
    int t = threadIdx.x;
    for (int i = t; i < 4096; i += 256) {
        int e = i >> 6, c = i & 63;
        tile[e][c] = in[(size_t)e * HWS + p0 + c];
    }
    __syncthreads();
    for (int i = t; i < 4096; i += 256) {
        int r = i >> 6, e = i & 63;
        outp[(size_t)(p0 + r) * 64 + e] = tile[e][r];
    }
}

// ---------------- Kernel F (fallback): out = A_big * vT via MFMA (no LDS) ----------------
__global__ __launch_bounds__(256) void k_out(const u16* __restrict__ Abig,
                                             const u16* __restrict__ vT,
                                             float* __restrict__ outb) {
    const int p0 = blockIdx.x << 6;
    const int t = threadIdx.x, lane = t & 63, w = t >> 6;
    const int l15 = lane & 15, l4 = lane >> 4;

    bf16x8 Af[2][4];
#pragma unroll
    for (int cf = 0; cf < 2; ++cf)
#pragma unroll
        for (int ks = 0; ks < 4; ++ks)
            Af[cf][ks] = *(const bf16x8*)&Abig[(size_t)(32 * w + 16 * cf + l15) * 128 + 32 * ks + 8 * l4];

    f32x4 zz = {0.f, 0.f, 0.f, 0.f};
    f32x4 acc[2][4];
#pragma unroll
    for (int cf = 0; cf < 2; ++cf)
#pragma unroll
        for (int nf = 0; nf < 4; ++nf) acc[cf][nf] = zz;

#pragma unroll
    for (int ks = 0; ks < 4; ++ks) {
        bf16x8 Bf[4];
#pragma unroll
        for (int nf = 0; nf < 4; ++nf)
            Bf[nf] = *(const bf16x8*)&vT[(size_t)(p0 + 16 * nf + l15) * 128 + 32 * ks + 8 * l4];
#pragma unroll
        for (int cf = 0; cf < 2; ++cf)
#pragma unroll
            for (int nf = 0; nf < 4; ++nf)
                acc[cf][nf] = __builtin_amdgcn_mfma_f32_16x16x32_bf16(Af[cf][ks], Bf[nf], acc[cf][nf], 0, 0, 0);
    }

    float2* o2 = (float2*)outb;
#pragma unroll
    for (int cf = 0; cf < 2; ++cf)
#pragma unroll
        for (int nf = 0; nf < 4; ++nf) {
            int co = 16 * w + 8 * cf + 2 * l4;
            int p = p0 + 16 * nf + l15;
            o2[(size_t)co * HWS + p]       = make_float2(acc[cf][nf][0], acc[cf][nf][1]);
            o2[(size_t)(co + 1) * HWS + p] = make_float2(acc[cf][nf][2], acc[cf][nf][3]);
        }
}

// ---------------- Kernel F2: out = A_big * v via LDS-staged vpack ----------------
__global__ __launch_bounds__(256) void k_out2(const u16* __restrict__ Abig,
                                              const u32* __restrict__ vpk,
                                              float* __restrict__ outb,
                                              int b0, size_t vst, size_t ost) {
    const int z = blockIdx.z;
    const int b = b0 + z;
    vpk += (size_t)z * vst; outb += (size_t)z * ost;
    __shared__ u32 Tep[64][65];
    const int p0 = blockIdx.x << 6;
    const int t = threadIdx.x, lane = t & 63, w = t >> 6;
    const int l15 = lane & 15, l4 = lane >> 4;
    const u16* AB = Abig + (size_t)b * 16384;

    bf16x8 Af[2][4];
#pragma unroll
    for (int cf = 0; cf < 2; ++cf)
#pragma unroll
        for (int ks = 0; ks < 4; ++ks)
            Af[cf][ks] = *(const bf16x8*)&AB[(size_t)(32 * w + 16 * cf + l15) * 128 + 32 * ks + 8 * l4];

    for (int i = t; i < 4096; i += 256) {
        int e = i >> 6, tok = i & 63;
        Tep[e][tok] = vpk[(size_t)e * HWS + p0 + tok];
    }
    __syncthreads();

    f32x4 zz = {0.f, 0.f, 0.f, 0.f};
    f32x4 acc[2][4];
#pragma unroll
    for (int cf = 0; cf < 2; ++cf)
#pragma unroll
        for (int nf = 0; nf < 4; ++nf) acc[cf][nf] = zz;

#pragma unroll
    for (int ks = 0; ks < 4; ++ks) {
        bf16x8 Bf[4];
#pragma unroll
        for (int nf = 0; nf < 4; ++nf) {
            int tok = 16 * nf + l15;
            int e0 = 16 * ks + 4 * l4;
            union { u32 u[4]; bf16x8 v; } bb;
#pragma unroll
            for (int j = 0; j < 4; ++j) bb.u[j] = Tep[e0 + j][tok];
            Bf[nf] = bb.v;
        }
#pragma unroll
        for (int cf = 0; cf < 2; ++cf)
#pragma unroll
            for (int nf = 0; nf < 4; ++nf)
                acc[cf][nf] = __builtin_amdgcn_mfma_f32_16x16x32_bf16(Af[cf][ks], Bf[nf], acc[cf][nf], 0, 0, 0);
    }

    float2* o2 = (float2*)outb;
#pragma unroll
    for (int cf = 0; cf < 2; ++cf)
#pragma unroll
        for (int nf = 0; nf < 4; ++nf) {
            int co = 16 * w + 8 * cf + 2 * l4;
            int p = p0 + 16 * nf + l15;
            o2[(size_t)co * HWS + p]       = make_float2(acc[cf][nf][0], acc[cf][nf][1]);
            o2[(size_t)(co + 1) * HWS + p] = make_float2(acc[cf][nf][2], acc[cf][nf][3]);
        }
}

extern "C" void kernel_launch(void* const* d_in, const int* in_sizes, int n_in,
                              void* d_out, int out_size, void* d_ws, size_t ws_size,
                              hipStream_t stream) {
    const float* x      = (const float*)d_in[0];
    const float* qkv_wr = (const float*)d_in[1];
    const float* qkv_wi = (const float*)d_in[2];
    const float* dw_wr  = (const float*)d_in[3];
    const float* dw_wi  = (const float*)d_in[4];
    const float* p_wr   = (const float*)d_in[5];
    const float* p_wi   = (const float*)d_in[6];
    float* out = (float*)d_out;
    const size_t OSTR = (size_t)64 * HWS * 2;   // floats per batch of output

    const bool z2  = ws_size >= 236000000ull;   // fully per-b-strided buffers
    const bool f14 = !z2 && ws_size >= 118200000ull;

    char* base = (char*)d_ws;

    if (z2) {
        // per-b strided layout (~235.9 MB)
        u32*   qs   = (u32*)base;                          // 2 x 50,724,864 B
        u16*   dwp  = (u16*)(base + 101449728);            // 2 x 33,554,432 B
        u16*   xTr  = (u16*)(base + 168558592);            // 2 x (8.39+8.39) MB
        u16*   xTi  = xTr + (size_t)HWS * 64;
        u32*   vpk  = (u32*)(base + 202113024);            // 2 x 16,777,216 B
        u16*   wbf  = (u16*)(base + 235667456);
        float* rnsum = (float*)(base + 235741184);
        float* attn  = rnsum + 512;
        float* Pbuf  = attn + 16384;
        u16*   Abig  = (u16*)(Pbuf + 16384);

        const size_t XT_ST = 8388608;     // u16 per b (both planes)
        const size_t QS_ST = 12681216;    // u32 per b
        const size_t DW_ST = 16777216;    // u16 per b
        const size_t VP_ST = 4194304;     // u32 per b

        k_prep<<<66, 256, 0, stream>>>(qkv_wr, qkv_wi, wbf, rnsum, 512 + 16384);
        k_xt<<<dim3(1024, 1, 2), 256, 0, stream>>>(x, xTr, xTi, OSTR, XT_ST);
        // NPR = 516 row-pairs; grid = 8*6*ceil(516/8) = 3120
        k_qkv<<<3120, 256, 0, stream>>>(xTr, xTi, wbf, qs, XT_ST, QS_ST, 516);
        k_dw<<<dim3(12288, 1, 2), 256, 0, stream>>>(qs, dw_wr, dw_wi, dwp, vpk,
                                                    QS_ST, DW_ST, VP_ST);
        k_qk<<<dim3(64, 2, 2), 256, 0, stream>>>(dwp, rnsum, attn, 0, DW_ST);
        k_prob<<<dim3(2, 2), 64, 0, stream>>>(attn, rnsum, Pbuf, 0);
        k_M<<<dim3(16, 2), 256, 0, stream>>>(Pbuf, p_wr, p_wi, Abig, 0);
        k_out2<<<dim3(1024, 1, 2), 256, 0, stream>>>(Abig, vpk, out, 0, VP_ST, OSTR);
        return;
    }

    // shared-buffer layouts (round-14 / round-13 proven paths)
    u32*   qs   = (u32*)base;                               // 50,724,864 B
    u16*   dwp  = (u16*)(base + 50724864);                  // 33,554,432 B
    char*  xreg = base + 50724864 + 33554432;               // 16,777,216 B
    u16*   xTr  = (u16*)xreg;
    u16*   xTi  = xTr + (size_t)HWS * 64;
    u32*   vT   = (u32*)xreg;                               // fallback-13: vT aliases xT
    u32*   vpkW = (u32*)(base + 101056512);                 // f14 only
    size_t tail = f14 ? 117833728ull : 101056512ull;
    u16*   wbf  = (u16*)(base + tail);
    float* rnsum = (float*)(base + tail + 73728);
    float* attn  = rnsum + 512;
    float* Pbuf  = attn + 16384;
    u16*   Abig  = (u16*)(Pbuf + 16384);

    k_prep<<<66, 256, 0, stream>>>(qkv_wr, qkv_wi, wbf, rnsum, 512 + 16384);

    for (int b = 0; b < 2; ++b) {
        const float* xb = x + (size_t)b * OSTR;
        u32* vpack = f14 ? vpkW : (u32*)(out + (size_t)b * OSTR);
        k_xt<<<dim3(1024, 1, 1), 256, 0, stream>>>(xb, xTr, xTi, 0, 0);
        // NPR = 258; grid = 8*6*ceil(258/8) = 1584
        k_qkv<<<1584, 256, 0, stream>>>(xTr, xTi, wbf, qs, 0, 0, 258);
        k_dw<<<dim3(12288, 1, 1), 256, 0, stream>>>(qs, dw_wr, dw_wi, dwp, vpack, 0, 0, 0);
        k_qk<<<dim3(64, 2, 1), 256, 0, stream>>>(dwp, rnsum, attn, b, 0);
        k_prob<<<dim3(2, 1), 64, 0, stream>>>(attn, rnsum, Pbuf, b);
        k_M<<<dim3(16, 1), 256, 0, stream>>>(Pbuf, p_wr, p_wi, Abig, b);
        if (f14)
            k_out2<<<dim3(1024, 1, 1), 256, 0, stream>>>(Abig, vpkW,
                                                         out + (size_t)b * OSTR, b, 0, 0);
    }
    if (!f14) {
        for (int b = 0; b < 2; ++b) {
            u32* vpack = (u32*)(out + (size_t)b * OSTR);
            k_vt<<<1024, 256, 0, stream>>>(vpack, vT);
            k_out<<<1024, 256, 0, stream>>>(Abig + (size_t)b * 16384, (const u16*)vT,
                                            out + (size_t)b * OSTR);
        }
    }
}

// Round 21
// 179.074 us; speedup vs baseline: 1.1873x; 1.0031x over previous
//
#include <hip/hip_runtime.h>

#define HWS 65536   // 256*256
#define SPZ 66048   // (256+2)*256 halo strip positions

typedef __attribute__((ext_vector_type(8))) short bf16x8;
typedef __attribute__((ext_vector_type(4))) float f32x4;
typedef unsigned int u32;
typedef unsigned short u16;

__device__ __forceinline__ u16 f2bf(float x) {
    u32 u = __float_as_uint(x);
    return (u16)((u + 0x7fffu + ((u >> 16) & 1u)) >> 16);
}
__device__ __forceinline__ float bf2f(u32 h) { return __uint_as_float(h << 16); }
// HW packed bf16 convert (RNE, identical rounding to f2bf): lo=a, hi=b
__device__ __forceinline__ u32 cvtpk(float a, float b) {
    u32 r;
    asm("v_cvt_pk_bf16_f32 %0, %1, %2" : "=v"(r) : "v"(a), "v"(b));
    return r;
}

// ---------------- prep: weight cvt + zero accumulators (one launch) ----------------
__global__ void k_prep(const float* __restrict__ wr, const float* __restrict__ wi,
                       u16* __restrict__ wbf, float* __restrict__ zbuf, int nz) {
    int i = blockIdx.x * 256 + threadIdx.x;
    if (i < 12288) {
        wbf[i]         = f2bf(wr[i]);
        wbf[12288 + i] = f2bf(wi[i]);
        wbf[24576 + i] = f2bf(-wi[i]);
    }
    if (i < nz) zbuf[i] = 0.f;
}

// ---------------- Kernel X: transpose+convert x -> xTr/xTi bf16 [HWS][64] ----------------
__global__ __launch_bounds__(256) void k_xt(const float* __restrict__ x,
                                            u16* __restrict__ xTr,
                                            u16* __restrict__ xTi,
                                            size_t xs, size_t ts) {
    const int b = blockIdx.z;
    x += (size_t)b * xs; xTr += (size_t)b * ts; xTi += (size_t)b * ts;
    __shared__ u16 Tr[64][74], Ti[64][74];
    int p0 = blockIdx.x << 6;
    int t = threadIdx.x;
    const float2* x2 = (const float2*)x;
    for (int i = t; i < 2048; i += 256) {        // (ci-pair, c)
        int cp = i >> 6, c = i & 63;
        int ci = cp << 1;
        float2 v0 = x2[(size_t)ci * HWS + p0 + c];
        float2 v1 = x2[(size_t)(ci + 1) * HWS + p0 + c];
        *(u32*)&Tr[c][ci] = cvtpk(v0.x, v1.x);
        *(u32*)&Ti[c][ci] = cvtpk(v0.y, v1.y);
    }
    __syncthreads();
    for (int i = t; i < 2048; i += 256) {        // (row, ci-pair)
        int rr = i >> 5, cp = i & 31;
        *(u32*)&xTr[(size_t)(p0 + rr) * 64 + 2 * cp] = *(u32*)&Tr[rr][2 * cp];
        *(u32*)&xTi[(size_t)(p0 + rr) * 64 + 2 * cp] = *(u32*)&Ti[rr][2 * cp];
    }
}

// ---------------- Kernel A: qkv 1x1 complex conv, global->MFMA, 2-half LDS epilogue ----------------
// 1D grid, XCD-swizzled. Token map: tok = pf*64 + wv*16 + l15 (bijection).
// Each half (pf 0-1 / 2-3) drains a 16.9 KB Tep -> 8 blocks/CU occupancy.
__global__ __launch_bounds__(256) void k_qkv(const u16* __restrict__ xTr,
                                             const u16* __restrict__ xTi,
                                             const u16* __restrict__ wbf,
                                             u32* __restrict__ qs,
                                             size_t ts, size_t qsst, int NPR) {
    __shared__ u32 Tep[32 * 132];    // 16896 B
    const int bid = blockIdx.x;
    const int xcd = bid & 7, j = bid >> 3;
    const int cog = j % 6;               // 0..5, 32 co each
    const int pr  = xcd + 8 * (j / 6);   // row-pair index
    if (pr >= NPR) return;
    const int z  = pr / 258;
    const int rt = pr % 258;             // 0..257
    xTr += (size_t)z * ts; xTi += (size_t)z * ts; qs += (size_t)z * qsst;
    const int w = rt - 1;                // image row (may be OOB -> zeros)
    const int t = threadIdx.x, lane = t & 63, wv = t >> 6;
    const int l15 = lane & 15, l4 = lane >> 4;
    const bool valid = (unsigned)w < 256u;

    bf16x8 Ar[2][2], Ai[2][2], An[2][2];
#pragma unroll
    for (int cf = 0; cf < 2; ++cf)
#pragma unroll
        for (int ks = 0; ks < 2; ++ks) {
            size_t off = (size_t)(cog * 32 + 16 * cf + l15) * 64 + 32 * ks + 8 * l4;
            Ar[cf][ks] = *(const bf16x8*)&wbf[off];
            Ai[cf][ks] = *(const bf16x8*)&wbf[12288 + off];
            An[cf][ks] = *(const bf16x8*)&wbf[24576 + off];
        }

    const f32x4 zz = {0.f, 0.f, 0.f, 0.f};
    const int ln2 = lane & 31, rsel = lane >> 5;

#pragma unroll
    for (int half = 0; half < 2; ++half) {
        __syncthreads();                          // Tep reuse guard
#pragma unroll
        for (int pfh = 0; pfh < 2; ++pfh) {
            const int pf = half * 2 + pfh;
            const int tokh = pfh * 64 + wv * 16 + l15;   // token within half
            f32x4 cr[2] = {zz, zz}, cim[2] = {zz, zz};
            if (valid) {
                int tok = half * 128 + tokh;
                bf16x8 br[2], bi[2];
#pragma unroll
                for (int ks = 0; ks < 2; ++ks) {
                    size_t boff = (size_t)(w * 256 + tok) * 64 + 32 * ks + 8 * l4;
                    br[ks] = *(const bf16x8*)&xTr[boff];
                    bi[ks] = *(const bf16x8*)&xTi[boff];
                }
#pragma unroll
                for (int ks = 0; ks < 2; ++ks)
#pragma unroll
                    for (int cf = 0; cf < 2; ++cf) {
                        cr[cf]  = __builtin_amdgcn_mfma_f32_16x16x32_bf16(Ar[cf][ks], br[ks], cr[cf], 0, 0, 0);
                        cr[cf]  = __builtin_amdgcn_mfma_f32_16x16x32_bf16(An[cf][ks], bi[ks], cr[cf], 0, 0, 0);
                        cim[cf] = __builtin_amdgcn_mfma_f32_16x16x32_bf16(Ai[cf][ks], br[ks], cim[cf], 0, 0, 0);
                        cim[cf] = __builtin_amdgcn_mfma_f32_16x16x32_bf16(Ar[cf][ks], bi[ks], cim[cf], 0, 0, 0);
                    }
            }
#pragma unroll
            for (int cf = 0; cf < 2; ++cf)
#pragma unroll
                for (int r = 0; r < 4; ++r) {
                    int col = 16 * cf + 4 * l4 + r;      // local co 0..31
                    Tep[col * 132 + tokh] = valid ? cvtpk(cr[cf][r], cim[cf][r]) : 0u;
                }
        }
        __syncthreads();
        // drain: each half-wave stores one 512B row-segment (rows co = wv + 4*(2k+rsel))
#pragma unroll
        for (int k = 0; k < 4; ++k) {
            int co = wv + 4 * (2 * k + rsel);
            uint4 vv = *(const uint4*)&Tep[co * 132 + 4 * ln2];
            *(uint4*)&qs[(size_t)(cog * 32 + co) * SPZ + rt * 256 + half * 128 + 4 * ln2] = vv;
        }
    }
}

// ---------------- Kernel B: depthwise 3x3 complex conv, 4 pixels/thread ----------------
// wave == one image row; uint4 loads + shfl halo. ch uniform per block.
__global__ __launch_bounds__(256) void k_dw(const u32* __restrict__ qs,
                                            const float* __restrict__ wr,
                                            const float* __restrict__ wi,
                                            u16* __restrict__ dwp,
                                            u32* __restrict__ vpack,
                                            size_t qsst, size_t dst, size_t vst) {
    const int b = blockIdx.z;
    qs += (size_t)b * qsst; dwp += (size_t)b * dst; vpack += (size_t)b * vst;
    const int ch = blockIdx.x >> 6;                         // uniform -> s_loads
    const int p4 = (((blockIdx.x & 63) << 8) + threadIdx.x) << 2;
    const int r = p4 >> 8, h = p4 & 255;                    // h = 4*laneInRow
    const u32* src = qs + (size_t)ch * SPZ + r * 256;

    float wrl[9], wil[9];
#pragma unroll
    for (int tt = 0; tt < 9; ++tt) { wrl[tt] = wr[ch * 9 + tt]; wil[tt] = wi[ch * 9 + tt]; }

    u32 uv[3][6];
#pragma unroll
    for (int du = 0; du < 3; ++du) {
        uint4 W = *(const uint4*)&src[du * 256 + h];        // coalesced 16B/lane
        u32 left  = (u32)__shfl_up((int)W.w, 1);            // word at h-1
        u32 right = (u32)__shfl_down((int)W.x, 1);          // word at h+4
        if (h == 0)   left = 0u;
        if (h == 252) right = 0u;
        uv[du][0] = left;  uv[du][1] = W.x; uv[du][2] = W.y;
        uv[du][3] = W.z;   uv[du][4] = W.w; uv[du][5] = right;
    }
    float vr[3][6], vi[3][6];
#pragma unroll
    for (int du = 0; du < 3; ++du)
#pragma unroll
        for (int j = 0; j < 6; ++j) {
            vr[du][j] = bf2f(uv[du][j] & 0xffffu);
            vi[du][j] = bf2f(uv[du][j] >> 16);
        }

    float ar[4] = {0.f, 0.f, 0.f, 0.f}, ai[4] = {0.f, 0.f, 0.f, 0.f};
#pragma unroll
    for (int du = 0; du < 3; ++du)
#pragma unroll
        for (int ct = 0; ct < 3; ++ct) {
            float w0 = wrl[du * 3 + ct], w1 = wil[du * 3 + ct];
#pragma unroll
            for (int px = 0; px < 4; ++px) {
                float xr = vr[du][px + ct], xi = vi[du][px + ct];
                ar[px] = fmaf(w0, xr, ar[px]); ar[px] = fmaf(-w1, xi, ar[px]);
                ai[px] = fmaf(w1, xr, ai[px]); ai[px] = fmaf(w0, xi, ai[px]);
            }
        }

    if (ch < 128) {
        int pl = (ch < 64) ? 0 : 2;
        int c2 = ch & 63;
        uint2 rw = make_uint2(cvtpk(ar[0], ar[1]), cvtpk(ar[2], ar[3]));
        uint2 iw = make_uint2(cvtpk(ai[0], ai[1]), cvtpk(ai[2], ai[3]));
        *(uint2*)&dwp[(size_t)(pl * 64 + c2) * HWS + p4] = rw;
        *(uint2*)&dwp[(size_t)((pl + 1) * 64 + c2) * HWS + p4] = iw;
    } else {
        int e = ch - 128;
        uint4 vv = make_uint4(cvtpk(ar[0], ai[0]), cvtpk(ar[1], ai[1]),
                              cvtpk(ar[2], ai[2]), cvtpk(ar[3], ai[3]));
        *(uint4*)&vpack[(size_t)e * HWS + p4] = vv;
    }
}

// ---------------- Kernel C: q k^T + fused sumsq via MFMA (no LDS) ----------------
// grid (64 chunks, 2 d, nb)
__global__ __launch_bounds__(256) void k_qk(const u16* __restrict__ dwp,
                                            float* __restrict__ rnsum,
                                            float* __restrict__ attn,
                                            int b0, size_t dst) {
    const int z = blockIdx.z;
    const int b = b0 + z;
    dwp += (size_t)z * dst;
    const int chunk = blockIdx.x;        // 0..63
    const int d = blockIdx.y;
    const int Kc = HWS >> 6;
    const int kc0 = chunk * Kc;
    const u16* qp = dwp + (size_t)d * 64 * HWS;
    const u16* kp = dwp + (size_t)(2 + d) * 64 * HWS;

    const int t = threadIdx.x, lane = t & 63, wid = t >> 6;
    const int wy = wid >> 1, wx = wid & 1;
    const int l15 = lane & 15, l4 = lane >> 4;

    f32x4 zz = {0.f, 0.f, 0.f, 0.f};
    f32x4 acc[2][2] = {{zz, zz}, {zz, zz}};
    float sq[2] = {0.f, 0.f}, sk[2] = {0.f, 0.f};

    const int iters = Kc >> 5;
    for (int ks = 0; ks < iters; ++ks) {
        int k0 = kc0 + ks * 32 + 8 * l4;
        bf16x8 aq[2], bk[2];
#pragma unroll
        for (int cf = 0; cf < 2; ++cf)
            aq[cf] = *(const bf16x8*)&qp[(size_t)(32 * wy + 16 * cf + l15) * HWS + k0];
#pragma unroll
        for (int ef = 0; ef < 2; ++ef)
            bk[ef] = *(const bf16x8*)&kp[(size_t)(32 * wx + 16 * ef + l15) * HWS + k0];

        if (wx == 0)
#pragma unroll
            for (int cf = 0; cf < 2; ++cf)
#pragma unroll
                for (int j = 0; j < 8; ++j) {
                    float f = bf2f((u16)aq[cf][j]);
                    sq[cf] = fmaf(f, f, sq[cf]);
                }
        if (wy == 0)
#pragma unroll
            for (int ef = 0; ef < 2; ++ef)
#pragma unroll
                for (int j = 0; j < 8; ++j) {
                    float f = bf2f((u16)bk[ef][j]);
                    sk[ef] = fmaf(f, f, sk[ef]);
                }

#pragma unroll
        for (int cf = 0; cf < 2; ++cf)
#pragma unroll
            for (int ef = 0; ef < 2; ++ef)
                acc[cf][ef] = __builtin_amdgcn_mfma_f32_16x16x32_bf16(aq[cf], bk[ef], acc[cf][ef], 0, 0, 0);
    }

#pragma unroll
    for (int cf = 0; cf < 2; ++cf)
#pragma unroll
        for (int ef = 0; ef < 2; ++ef)
#pragma unroll
            for (int r = 0; r < 4; ++r) {
                int cq = 32 * wy + 16 * cf + 4 * l4 + r;
                int ce = 32 * wx + 16 * ef + l15;
                atomicAdd(&attn[((b * 2 + d) * 64 + cq) * 64 + ce], acc[cf][ef][r]);
            }

    if (wx == 0)
#pragma unroll
        for (int cf = 0; cf < 2; ++cf) {
            float v = sq[cf];
            v += __shfl_xor(v, 16);
            v += __shfl_xor(v, 32);
            if (lane < 16)
                atomicAdd(&rnsum[((size_t)b * 128 + 32 * wy + 16 * cf + lane) * 2 + d], v);
        }
    if (wy == 0)
#pragma unroll
        for (int ef = 0; ef < 2; ++ef) {
            float v = sk[ef];
            v += __shfl_xor(v, 16);
            v += __shfl_xor(v, 32);
            if (lane < 16)
                atomicAdd(&rnsum[((size_t)b * 128 + 64 + 32 * wx + 16 * ef + lane) * 2 + d], v);
        }
}

// ---------------- Kernel D1: scale + row softmax -> P (grid (2 d, nb), 64 thr) ----------------
__global__ __launch_bounds__(64) void k_prob(const float* __restrict__ attn,
                                             const float* __restrict__ rnsum,
                                             float* __restrict__ P, int b0) {
    int d = blockIdx.x;
    int b = b0 + blockIdx.y;
    int t = threadIdx.x;
    __shared__ float rks[64];
    float sk = rnsum[((size_t)b * 128 + 64 + t) * 2 + d];
    rks[t] = 1.0f / fmaxf(sqrtf(sk), 1e-12f);
    float sq = rnsum[((size_t)b * 128 + t) * 2 + d];
    float rq = 1.0f / fmaxf(sqrtf(sq), 1e-12f);
    __syncthreads();

    const float* arow = attn + ((size_t)(b * 2 + d) * 64 + t) * 64;
    float v[64];
    float m = -1e30f;
#pragma unroll
    for (int e = 0; e < 64; ++e) { v[e] = arow[e] * rq * rks[e]; m = fmaxf(m, v[e]); }
    float ssum = 0.f;
#pragma unroll
    for (int e = 0; e < 64; ++e) { v[e] = __expf(v[e] - m); ssum += v[e]; }
    float r = 1.0f / ssum;
    float* prow = P + ((size_t)(b * 2 + d) * 64 + t) * 64;
#pragma unroll
    for (int e = 0; e < 64; ++e) prow[e] = v[e] * r;
}

// ---------------- Kernel D2: build A_big from P and proj weights (grid (16, nb)) ----------------
__global__ __launch_bounds__(256) void k_M(const float* __restrict__ P,
                                           const float* __restrict__ pwr,
                                           const float* __restrict__ pwi,
                                           u16* __restrict__ Abig, int b0) {
    int b = b0 + blockIdx.y;
    int pair = blockIdx.x * 256 + threadIdx.x;   // 0..4095
    __shared__ float P0[64][64], P1[64][64];
    __shared__ float Wr[64][64], Wi2[64][64];
    for (int i = threadIdx.x; i < 4096; i += 256) {
        P0[i >> 6][i & 63] = P[(size_t)(b * 2 + 0) * 4096 + i];
        P1[i >> 6][i & 63] = P[(size_t)(b * 2 + 1) * 4096 + i];
        Wr[i >> 6][i & 63] = pwr[i];
        Wi2[i >> 6][i & 63] = pwi[i];
    }
    __syncthreads();
    int co = pair >> 6, e = pair & 63;
    float m1 = 0.f, m2 = 0.f, m3 = 0.f, m4 = 0.f;
#pragma unroll 8
    for (int c = 0; c < 64; ++c) {
        float pr = Wr[co][c], pi = Wi2[co][c];
        float a0 = P0[c][e], a1 = P1[c][e];
        m1 = fmaf(pr, a0, m1);
        m2 = fmaf(pi, a1, m2);
        m3 = fmaf(pr, a1, m3);
        m4 = fmaf(pi, a0, m4);
    }
    u16* AB = Abig + (size_t)b * 16384;
    AB[(2 * co) * 128 + 2 * e]         = f2bf(m1);
    AB[(2 * co) * 128 + 2 * e + 1]     = f2bf(-m2);
    AB[(2 * co + 1) * 128 + 2 * e]     = f2bf(m4);
    AB[(2 * co + 1) * 128 + 2 * e + 1] = f2bf(m3);
}

// ---------------- Kernel E (fallback): transpose vpack [64][HWS] u32 -> vT [HWS][64] u32 ----------------
__global__ __launch_bounds__(256) void k_vt(const u32* __restrict__ in,
                                            u32* __restrict__ outp) {
    __shared__ u32 tile[64][65];
    int p0 = blockIdx.x << 6;
    int t = threadIdx.x;
    for (int i = t; i < 4096; i += 256) {
        int e = i >> 6, c = i & 63;
        tile[e][c] = in[(size_t)e * HWS + p0 + c];
    }
    __syncthreads();
    for (int i = t; i < 4096; i += 256) {
        int r = i >> 6, e = i & 63;
        outp[(size_t)(p0 + r) * 64 + e] = tile[e][r];
    }
}

// ---------------- Kernel F (fallback): out = A_big * vT via MFMA (no LDS) ----------------
__global__ __launch_bounds__(256) void k_out(const u16* __restrict__ Abig,
                                             const u16* __restrict__ vT,
                                             float* __restrict__ outb) {
    const int p0 = blockIdx.x << 6;
    const int t = threadIdx.x, lane = t & 63, w = t >> 6;
    const int l15 = lane & 15, l4 = lane >> 4;

    bf16x8 Af[2][4];
#pragma unroll
    for (int cf = 0; cf < 2; ++cf)
#pragma unroll
        for (int ks = 0; ks < 4; ++ks)
            Af[cf][ks] = *(const bf16x8*)&Abig[(size_t)(32 * w + 16 * cf + l15) * 128 + 32 * ks + 8 * l4];

    f32x4 zz = {0.f, 0.f, 0.f, 0.f};
    f32x4 acc[2][4];
#pragma unroll
    for (int cf = 0; cf < 2; ++cf)
#pragma unroll
        for (int nf = 0; nf < 4; ++nf) acc[cf][nf] = zz;

#pragma unroll
    for (int ks = 0; ks < 4; ++ks) {
        bf16x8 Bf[4];
#pragma unroll
        for (int nf = 0; nf < 4; ++nf)
            Bf[nf] = *(const bf16x8*)&vT[(size_t)(p0 + 16 * nf + l15) * 128 + 32 * ks + 8 * l4];
#pragma unroll
        for (int cf = 0; cf < 2; ++cf)
#pragma unroll
            for (int nf = 0; nf < 4; ++nf)
                acc[cf][nf] = __builtin_amdgcn_mfma_f32_16x16x32_bf16(Af[cf][ks], Bf[nf], acc[cf][nf], 0, 0, 0);
    }

    float2* o2 = (float2*)outb;
#pragma unroll
    for (int cf = 0; cf < 2; ++cf)
#pragma unroll
        for (int nf = 0; nf < 4; ++nf) {
            int co = 16 * w + 8 * cf + 2 * l4;
            int p = p0 + 16 * nf + l15;
            o2[(size_t)co * HWS + p]       = make_float2(acc[cf][nf][0], acc[cf][nf][1]);
            o2[(size_t)(co + 1) * HWS + p] = make_float2(acc[cf][nf][2], acc[cf][nf][3]);
        }
}

// ---------------- Kernel F2: out = A_big * v via LDS-staged vpack ----------------
__global__ __launch_bounds__(256) void k_out2(const u16* __restrict__ Abig,
                                              const u32* __restrict__ vpk,
                                              float* __restrict__ outb,
                                              int b0, size_t vst, size_t ost) {
    const int z = blockIdx.z;
    const int b = b0 + z;
    vpk += (size_t)z * vst; outb += (size_t)z * ost;
    __shared__ u32 Tep[64][65];
    const int p0 = blockIdx.x << 6;
    const int t = threadIdx.x, lane = t & 63, w = t >> 6;
    const int l15 = lane & 15, l4 = lane >> 4;
    const u16* AB = Abig + (size_t)b * 16384;

    bf16x8 Af[2][4];
#pragma unroll
    for (int cf = 0; cf < 2; ++cf)
#pragma unroll
        for (int ks = 0; ks < 4; ++ks)
            Af[cf][ks] = *(const bf16x8*)&AB[(size_t)(32 * w + 16 * cf + l15) * 128 + 32 * ks + 8 * l4];

    for (int i = t; i < 4096; i += 256) {
        int e = i >> 6, tok = i & 63;
        Tep[e][tok] = vpk[(size_t)e * HWS + p0 + tok];
    }
    __syncthreads();

    f32x4 zz = {0.f, 0.f, 0.f, 0.f};
    f32x4 acc[2][4];
#pragma unroll
    for (int cf = 0; cf < 2; ++cf)
#pragma unroll
        for (int nf = 0; nf < 4; ++nf) acc[cf][nf] = zz;

#pragma unroll
    for (int ks = 0; ks < 4; ++ks) {
        bf16x8 Bf[4];
#pragma unroll
        for (int nf = 0; nf < 4; ++nf) {
            int tok = 16 * nf + l15;
            int e0 = 16 * ks + 4 * l4;
            union { u32 u[4]; bf16x8 v; } bb;
#pragma unroll
            for (int j = 0; j < 4; ++j) bb.u[j] = Tep[e0 + j][tok];
            Bf[nf] = bb.v;
        }
#pragma unroll
        for (int cf = 0; cf < 2; ++cf)
#pragma unroll
            for (int nf = 0; nf < 4; ++nf)
                acc[cf][nf] = __builtin_amdgcn_mfma_f32_16x16x32_bf16(Af[cf][ks], Bf[nf], acc[cf][nf], 0, 0, 0);
    }

    float2* o2 = (float2*)outb;
#pragma unroll
    for (int cf = 0; cf < 2; ++cf)
#pragma unroll
        for (int nf = 0; nf < 4; ++nf) {
            int co = 16 * w + 8 * cf + 2 * l4;
            int p = p0 + 16 * nf + l15;
            o2[(size_t)co * HWS + p]       = make_float2(acc[cf][nf][0], acc[cf][nf][1]);
            o2[(size_t)(co + 1) * HWS + p] = make_float2(acc[cf][nf][2], acc[cf][nf][3]);
        }
}

extern "C" void kernel_launch(void* const* d_in, const int* in_sizes, int n_in,
                              void* d_out, int out_size, void* d_ws, size_t ws_size,
                              hipStream_t stream) {
    const float* x      = (const float*)d_in[0];
    const float* qkv_wr = (const float*)d_in[1];
    const float* qkv_wi = (const float*)d_in[2];
    const float* dw_wr  = (const float*)d_in[3];
    const float* dw_wi  = (const float*)d_in[4];
    const float* p_wr   = (const float*)d_in[5];
    const float* p_wi   = (const float*)d_in[6];
    float* out = (float*)d_out;
    const size_t OSTR = (size_t)64 * HWS * 2;   // floats per batch of output

    const bool z2  = ws_size >= 236000000ull;   // fully per-b-strided buffers
    const bool f14 = !z2 && ws_size >= 118200000ull;

    char* base = (char*)d_ws;

    if (z2) {
        // per-b strided layout (~235.9 MB)
        u32*   qs   = (u32*)base;                          // 2 x 50,724,864 B
        u16*   dwp  = (u16*)(base + 101449728);            // 2 x 33,554,432 B
        u16*   xTr  = (u16*)(base + 168558592);            // 2 x (8.39+8.39) MB
        u16*   xTi  = xTr + (size_t)HWS * 64;
        u32*   vpk  = (u32*)(base + 202113024);            // 2 x 16,777,216 B
        u16*   wbf  = (u16*)(base + 235667456);
        float* rnsum = (float*)(base + 235741184);
        float* attn  = rnsum + 512;
        float* Pbuf  = attn + 16384;
        u16*   Abig  = (u16*)(Pbuf + 16384);

        const size_t XT_ST = 8388608;     // u16 per b (both planes)
        const size_t QS_ST = 12681216;    // u32 per b
        const size_t DW_ST = 16777216;    // u16 per b
        const size_t VP_ST = 4194304;     // u32 per b

        k_prep<<<66, 256, 0, stream>>>(qkv_wr, qkv_wi, wbf, rnsum, 512 + 16384);
        k_xt<<<dim3(1024, 1, 2), 256, 0, stream>>>(x, xTr, xTi, OSTR, XT_ST);
        // NPR = 516 row-pairs; grid = 8*6*ceil(516/8) = 3120
        k_qkv<<<3120, 256, 0, stream>>>(xTr, xTi, wbf, qs, XT_ST, QS_ST, 516);
        k_dw<<<dim3(12288, 1, 2), 256, 0, stream>>>(qs, dw_wr, dw_wi, dwp, vpk,
                                                    QS_ST, DW_ST, VP_ST);
        k_qk<<<dim3(64, 2, 2), 256, 0, stream>>>(dwp, rnsum, attn, 0, DW_ST);
        k_prob<<<dim3(2, 2), 64, 0, stream>>>(attn, rnsum, Pbuf, 0);
        k_M<<<dim3(16, 2), 256, 0, stream>>>(Pbuf, p_wr, p_wi, Abig, 0);
        k_out2<<<dim3(1024, 1, 2), 256, 0, stream>>>(Abig, vpk, out, 0, VP_ST, OSTR);
        return;
    }

    // shared-buffer layouts (round-14 / round-13 proven paths)
    u32*   qs   = (u32*)base;                               // 50,724,864 B
    u16*   dwp  = (u16*)(base + 50724864);                  // 33,554,432 B
    char*  xreg = base + 50724864 + 33554432;               // 16,777,216 B
    u16*   xTr  = (u16*)xreg;
    u16*   xTi  = xTr + (size_t)HWS * 64;
    u32*   vT   = (u32*)xreg;                               // fallback-13: vT aliases xT
    u32*   vpkW = (u32*)(base + 101056512);                 // f14 only
    size_t tail = f14 ? 117833728ull : 101056512ull;
    u16*   wbf  = (u16*)(base + tail);
    float* rnsum = (float*)(base + tail + 73728);
    float* attn  = rnsum + 512;
    float* Pbuf  = attn + 16384;
    u16*   Abig  = (u16*)(Pbuf + 16384);

    k_prep<<<66, 256, 0, stream>>>(qkv_wr, qkv_wi, wbf, rnsum, 512 + 16384);

    for (int b = 0; b < 2; ++b) {
        const float* xb = x + (size_t)b * OSTR;
        u32* vpack = f14 ? vpkW : (u32*)(out + (size_t)b * OSTR);
        k_xt<<<dim3(1024, 1, 1), 256, 0, stream>>>(xb, xTr, xTi, 0, 0);
        // NPR = 258; grid = 8*6*ceil(258/8) = 1584
        k_qkv<<<1584, 256, 0, stream>>>(xTr, xTi, wbf, qs, 0, 0, 258);
        k_dw<<<dim3(12288, 1, 1), 256, 0, stream>>>(qs, dw_wr, dw_wi, dwp, vpack, 0, 0, 0);
        k_qk<<<dim3(64, 2, 1), 256, 0, stream>>>(dwp, rnsum, attn, b, 0);
        k_prob<<<dim3(2, 1), 64, 0, stream>>>(attn, rnsum, Pbuf, b);
        k_M<<<dim3(16, 1), 256, 0, stream>>>(Pbuf, p_wr, p_wi, Abig, b);
        if (f14)
            k_out2<<<dim3(1024, 1, 1), 256, 0, stream>>>(Abig, vpkW,
                                                         out + (size_t)b * OSTR, b, 0, 0);
    }
    if (!f14) {
        for (int b = 0; b < 2; ++b) {
            u32* vpack = (u32*)(out + (size_t)b * OSTR);
            k_vt<<<1024, 256, 0, stream>>>(vpack, vT);
            k_out<<<1024, 256, 0, stream>>>(Abig + (size_t)b * 16384, (const u16*)vT,
                                            out + (size_t)b * OSTR);
        }
    }
}

// Round 22
// 170.025 us; speedup vs baseline: 1.2504x; 1.0532x over previous
//
#include <hip/hip_runtime.h>

#define HWS 65536   // 256*256
#define SPZ 66048   // (256+2)*256 halo strip positions

typedef __attribute__((ext_vector_type(8))) short bf16x8;
typedef __attribute__((ext_vector_type(4))) float f32x4;
typedef unsigned int u32;
typedef unsigned short u16;

__device__ __forceinline__ u16 f2bf(float x) {
    u32 u = __float_as_uint(x);
    return (u16)((u + 0x7fffu + ((u >> 16) & 1u)) >> 16);
}
__device__ __forceinline__ float bf2f(u32 h) { return __uint_as_float(h << 16); }
// HW packed bf16 convert (RNE, identical rounding to f2bf): lo=a, hi=b
__device__ __forceinline__ u32 cvtpk(float a, float b) {
    u32 r;
    asm("v_cvt_pk_bf16_f32 %0, %1, %2" : "=v"(r) : "v"(a), "v"(b));
    return r;
}

// ---------------- prep: weight cvt + zero accumulators (one launch) ----------------
__global__ void k_prep(const float* __restrict__ wr, const float* __restrict__ wi,
                       u16* __restrict__ wbf, float* __restrict__ zbuf, int nz) {
    int i = blockIdx.x * 256 + threadIdx.x;
    if (i < 12288) {
        wbf[i]         = f2bf(wr[i]);
        wbf[12288 + i] = f2bf(wi[i]);
        wbf[24576 + i] = f2bf(-wi[i]);
    }
    if (i < nz) zbuf[i] = 0.f;
}

// ---------------- Kernel X: transpose+convert x -> xT planes in MFMA-fragment order ----------
// Layout: per 16-token block (2KB/plane): byte = (l4*16+l15)*16 + ks*1024
// i.e. u16 off = tok16*8-chunk order: chunk = l15 + l4*16 + ks*64, within-chunk 8 u16.
__global__ __launch_bounds__(256) void k_xt(const float* __restrict__ x,
                                            u16* __restrict__ xTr,
                                            u16* __restrict__ xTi,
                                            size_t xs, size_t ts) {
    const int b = blockIdx.z;
    x += (size_t)b * xs; xTr += (size_t)b * ts; xTi += (size_t)b * ts;
    __shared__ u16 Tr[64][74], Ti[64][74];
    int p0 = blockIdx.x << 6;
    int t = threadIdx.x;
    const float2* x2 = (const float2*)x;
    for (int i = t; i < 2048; i += 256) {        // (ci-pair, c)
        int cp = i >> 6, c = i & 63;
        int ci = cp << 1;
        float2 v0 = x2[(size_t)ci * HWS + p0 + c];
        float2 v1 = x2[(size_t)(ci + 1) * HWS + p0 + c];
        *(u32*)&Tr[c][ci] = cvtpk(v0.x, v1.x);
        *(u32*)&Ti[c][ci] = cvtpk(v0.y, v1.y);
    }
    __syncthreads();
    u32* dr = (u32*)xTr;
    u32* di = (u32*)xTi;
    for (int i = t; i < 2048; i += 256) {        // fragment-order store
        int tb = i >> 9, rem = i & 511;          // 4 tok-blocks x 512 u32
        int chunk = rem >> 2, w4 = rem & 3;      // chunk = l15 + l4*16 + ks*64
        int tl  = chunk & 15;
        int l4c = (chunk >> 4) & 3;
        int ksc = chunk >> 6;
        int token = tb * 16 + tl;
        int cio = ksc * 32 + l4c * 8 + w4 * 2;
        size_t dst = (size_t)(p0 + tb * 16) * 32 + rem;
        dr[dst] = *(u32*)&Tr[token][cio];
        di[dst] = *(u32*)&Ti[token][cio];
    }
}

// ---------------- Kernel A: qkv 1x1 complex conv, fragment-linear B loads ----------------
// 1D grid, XCD-swizzled. B-loads: contiguous 1KB wave-loads from pre-swizzled xT.
__global__ __launch_bounds__(256) void k_qkv(const u16* __restrict__ xTr,
                                             const u16* __restrict__ xTi,
                                             const u16* __restrict__ wbf,
                                             u32* __restrict__ qs,
                                             size_t ts, size_t qsst, int NPR) {
    __shared__ u32 Tep[32 * 132];    // 16896 B
    const int bid = blockIdx.x;
    const int xcd = bid & 7, j = bid >> 3;
    const int cog = j % 6;               // 0..5, 32 co each
    const int pr  = xcd + 8 * (j / 6);   // row-pair index
    if (pr >= NPR) return;
    const int z  = pr / 258;
    const int rt = pr % 258;             // 0..257
    xTr += (size_t)z * ts; xTi += (size_t)z * ts; qs += (size_t)z * qsst;
    const int w = rt - 1;                // image row (may be OOB -> zeros)
    const int t = threadIdx.x, lane = t & 63, wv = t >> 6;
    const int l15 = lane & 15, l4 = lane >> 4;
    const bool valid = (unsigned)w < 256u;

    bf16x8 Ar[2][2], Ai[2][2], An[2][2];
#pragma unroll
    for (int cf = 0; cf < 2; ++cf)
#pragma unroll
        for (int ks = 0; ks < 2; ++ks) {
            size_t off = (size_t)(cog * 32 + 16 * cf + l15) * 64 + 32 * ks + 8 * l4;
            Ar[cf][ks] = *(const bf16x8*)&wbf[off];
            Ai[cf][ks] = *(const bf16x8*)&wbf[12288 + off];
            An[cf][ks] = *(const bf16x8*)&wbf[24576 + off];
        }

    const f32x4 zz = {0.f, 0.f, 0.f, 0.f};
    const int ln2 = lane & 31, rsel = lane >> 5;

#pragma unroll
    for (int half = 0; half < 2; ++half) {
        __syncthreads();                          // Tep reuse guard
#pragma unroll
        for (int pfh = 0; pfh < 2; ++pfh) {
            const int tokh = pfh * 64 + wv * 16 + l15;   // token within half
            f32x4 cr[2] = {zz, zz}, cim[2] = {zz, zz};
            if (valid) {
                // fragment-linear: base of this 16-token block + lane*16B (+ks*1KB)
                size_t base = ((size_t)w * 256 + half * 128 + pfh * 64 + wv * 16) * 64
                              + lane * 8;
                bf16x8 br[2], bi[2];
                br[0] = *(const bf16x8*)&xTr[base];
                br[1] = *(const bf16x8*)&xTr[base + 512];
                bi[0] = *(const bf16x8*)&xTi[base];
                bi[1] = *(const bf16x8*)&xTi[base + 512];
#pragma unroll
                for (int ks = 0; ks < 2; ++ks)
#pragma unroll
                    for (int cf = 0; cf < 2; ++cf) {
                        cr[cf]  = __builtin_amdgcn_mfma_f32_16x16x32_bf16(Ar[cf][ks], br[ks], cr[cf], 0, 0, 0);
                        cr[cf]  = __builtin_amdgcn_mfma_f32_16x16x32_bf16(An[cf][ks], bi[ks], cr[cf], 0, 0, 0);
                        cim[cf] = __builtin_amdgcn_mfma_f32_16x16x32_bf16(Ai[cf][ks], br[ks], cim[cf], 0, 0, 0);
                        cim[cf] = __builtin_amdgcn_mfma_f32_16x16x32_bf16(Ar[cf][ks], bi[ks], cim[cf], 0, 0, 0);
                    }
            }
#pragma unroll
            for (int cf = 0; cf < 2; ++cf)
#pragma unroll
                for (int r = 0; r < 4; ++r) {
                    int col = 16 * cf + 4 * l4 + r;      // local co 0..31
                    Tep[col * 132 + tokh] = valid ? cvtpk(cr[cf][r], cim[cf][r]) : 0u;
                }
        }
        __syncthreads();
        // drain: each half-wave stores one 512B row-segment
#pragma unroll
        for (int k = 0; k < 4; ++k) {
            int co = wv + 4 * (2 * k + rsel);
            uint4 vv = *(const uint4*)&Tep[co * 132 + 4 * ln2];
            *(uint4*)&qs[(size_t)(cog * 32 + co) * SPZ + rt * 256 + half * 128 + 4 * ln2] = vv;
        }
    }
}

// ---------------- Kernel B: depthwise 3x3 complex conv, 4 pixels/thread ----------------
__global__ __launch_bounds__(256) void k_dw(const u32* __restrict__ qs,
                                            const float* __restrict__ wr,
                                            const float* __restrict__ wi,
                                            u16* __restrict__ dwp,
                                            u32* __restrict__ vpack,
                                            size_t qsst, size_t dst, size_t vst) {
    const int b = blockIdx.z;
    qs += (size_t)b * qsst; dwp += (size_t)b * dst; vpack += (size_t)b * vst;
    const int ch = blockIdx.x >> 6;                         // uniform -> s_loads
    const int p4 = (((blockIdx.x & 63) << 8) + threadIdx.x) << 2;
    const int r = p4 >> 8, h = p4 & 255;                    // h = 4*laneInRow
    const u32* src = qs + (size_t)ch * SPZ + r * 256;

    float wrl[9], wil[9];
#pragma unroll
    for (int tt = 0; tt < 9; ++tt) { wrl[tt] = wr[ch * 9 + tt]; wil[tt] = wi[ch * 9 + tt]; }

    u32 uv[3][6];
#pragma unroll
    for (int du = 0; du < 3; ++du) {
        uint4 W = *(const uint4*)&src[du * 256 + h];        // coalesced 16B/lane
        u32 left  = (u32)__shfl_up((int)W.w, 1);            // word at h-1
        u32 right = (u32)__shfl_down((int)W.x, 1);          // word at h+4
        if (h == 0)   left = 0u;
        if (h == 252) right = 0u;
        uv[du][0] = left;  uv[du][1] = W.x; uv[du][2] = W.y;
        uv[du][3] = W.z;   uv[du][4] = W.w; uv[du][5] = right;
    }
    float vr[3][6], vi[3][6];
#pragma unroll
    for (int du = 0; du < 3; ++du)
#pragma unroll
        for (int j = 0; j < 6; ++j) {
            vr[du][j] = bf2f(uv[du][j] & 0xffffu);
            vi[du][j] = bf2f(uv[du][j] >> 16);
        }

    float ar[4] = {0.f, 0.f, 0.f, 0.f}, ai[4] = {0.f, 0.f, 0.f, 0.f};
#pragma unroll
    for (int du = 0; du < 3; ++du)
#pragma unroll
        for (int ct = 0; ct < 3; ++ct) {
            float w0 = wrl[du * 3 + ct], w1 = wil[du * 3 + ct];
#pragma unroll
            for (int px = 0; px < 4; ++px) {
                float xr = vr[du][px + ct], xi = vi[du][px + ct];
                ar[px] = fmaf(w0, xr, ar[px]); ar[px] = fmaf(-w1, xi, ar[px]);
                ai[px] = fmaf(w1, xr, ai[px]); ai[px] = fmaf(w0, xi, ai[px]);
            }
        }

    if (ch < 128) {
        int pl = (ch < 64) ? 0 : 2;
        int c2 = ch & 63;
        uint2 rw = make_uint2(cvtpk(ar[0], ar[1]), cvtpk(ar[2], ar[3]));
        uint2 iw = make_uint2(cvtpk(ai[0], ai[1]), cvtpk(ai[2], ai[3]));
        *(uint2*)&dwp[(size_t)(pl * 64 + c2) * HWS + p4] = rw;
        *(uint2*)&dwp[(size_t)((pl + 1) * 64 + c2) * HWS + p4] = iw;
    } else {
        int e = ch - 128;
        uint4 vv = make_uint4(cvtpk(ar[0], ai[0]), cvtpk(ar[1], ai[1]),
                              cvtpk(ar[2], ai[2]), cvtpk(ar[3], ai[3]));
        *(uint4*)&vpack[(size_t)e * HWS + p4] = vv;
    }
}

// ---------------- Kernel C: q k^T + fused sumsq via MFMA (no LDS) ----------------
__global__ __launch_bounds__(256) void k_qk(const u16* __restrict__ dwp,
                                            float* __restrict__ rnsum,
                                            float* __restrict__ attn,
                                            int b0, size_t dst) {
    const int z = blockIdx.z;
    const int b = b0 + z;
    dwp += (size_t)z * dst;
    const int chunk = blockIdx.x;        // 0..63
    const int d = blockIdx.y;
    const int Kc = HWS >> 6;
    const int kc0 = chunk * Kc;
    const u16* qp = dwp + (size_t)d * 64 * HWS;
    const u16* kp = dwp + (size_t)(2 + d) * 64 * HWS;

    const int t = threadIdx.x, lane = t & 63, wid = t >> 6;
    const int wy = wid >> 1, wx = wid & 1;
    const int l15 = lane & 15, l4 = lane >> 4;

    f32x4 zz = {0.f, 0.f, 0.f, 0.f};
    f32x4 acc[2][2] = {{zz, zz}, {zz, zz}};
    float sq[2] = {0.f, 0.f}, sk[2] = {0.f, 0.f};

    const int iters = Kc >> 5;
    for (int ks = 0; ks < iters; ++ks) {
        int k0 = kc0 + ks * 32 + 8 * l4;
        bf16x8 aq[2], bk[2];
#pragma unroll
        for (int cf = 0; cf < 2; ++cf)
            aq[cf] = *(const bf16x8*)&qp[(size_t)(32 * wy + 16 * cf + l15) * HWS + k0];
#pragma unroll
        for (int ef = 0; ef < 2; ++ef)
            bk[ef] = *(const bf16x8*)&kp[(size_t)(32 * wx + 16 * ef + l15) * HWS + k0];

        if (wx == 0)
#pragma unroll
            for (int cf = 0; cf < 2; ++cf)
#pragma unroll
                for (int j = 0; j < 8; ++j) {
                    float f = bf2f((u16)aq[cf][j]);
                    sq[cf] = fmaf(f, f, sq[cf]);
                }
        if (wy == 0)
#pragma unroll
            for (int ef = 0; ef < 2; ++ef)
#pragma unroll
                for (int j = 0; j < 8; ++j) {
                    float f = bf2f((u16)bk[ef][j]);
                    sk[ef] = fmaf(f, f, sk[ef]);
                }

#pragma unroll
        for (int cf = 0; cf < 2; ++cf)
#pragma unroll
            for (int ef = 0; ef < 2; ++ef)
                acc[cf][ef] = __builtin_amdgcn_mfma_f32_16x16x32_bf16(aq[cf], bk[ef], acc[cf][ef], 0, 0, 0);
    }

#pragma unroll
    for (int cf = 0; cf < 2; ++cf)
#pragma unroll
        for (int ef = 0; ef < 2; ++ef)
#pragma unroll
            for (int r = 0; r < 4; ++r) {
                int cq = 32 * wy + 16 * cf + 4 * l4 + r;
                int ce = 32 * wx + 16 * ef + l15;
                atomicAdd(&attn[((b * 2 + d) * 64 + cq) * 64 + ce], acc[cf][ef][r]);
            }

    if (wx == 0)
#pragma unroll
        for (int cf = 0; cf < 2; ++cf) {
            float v = sq[cf];
            v += __shfl_xor(v, 16);
            v += __shfl_xor(v, 32);
            if (lane < 16)
                atomicAdd(&rnsum[((size_t)b * 128 + 32 * wy + 16 * cf + lane) * 2 + d], v);
        }
    if (wy == 0)
#pragma unroll
        for (int ef = 0; ef < 2; ++ef) {
            float v = sk[ef];
            v += __shfl_xor(v, 16);
            v += __shfl_xor(v, 32);
            if (lane < 16)
                atomicAdd(&rnsum[((size_t)b * 128 + 64 + 32 * wx + 16 * ef + lane) * 2 + d], v);
        }
}

// ---------------- Kernel D1: scale + row softmax -> P (grid (2 d, nb), 64 thr) ----------------
__global__ __launch_bounds__(64) void k_prob(const float* __restrict__ attn,
                                             const float* __restrict__ rnsum,
                                             float* __restrict__ P, int b0) {
    int d = blockIdx.x;
    int b = b0 + blockIdx.y;
    int t = threadIdx.x;
    __shared__ float rks[64];
    float sk = rnsum[((size_t)b * 128 + 64 + t) * 2 + d];
    rks[t] = 1.0f / fmaxf(sqrtf(sk), 1e-12f);
    float sq = rnsum[((size_t)b * 128 + t) * 2 + d];
    float rq = 1.0f / fmaxf(sqrtf(sq), 1e-12f);
    __syncthreads();

    const float* arow = attn + ((size_t)(b * 2 + d) * 64 + t) * 64;
    float v[64];
    float m = -1e30f;
#pragma unroll
    for (int e = 0; e < 64; ++e) { v[e] = arow[e] * rq * rks[e]; m = fmaxf(m, v[e]); }
    float ssum = 0.f;
#pragma unroll
    for (int e = 0; e < 64; ++e) { v[e] = __expf(v[e] - m); ssum += v[e]; }
    float r = 1.0f / ssum;
    float* prow = P + ((size_t)(b * 2 + d) * 64 + t) * 64;
#pragma unroll
    for (int e = 0; e < 64; ++e) prow[e] = v[e] * r;
}

// ---------------- Kernel D2: build A_big from P and proj weights (grid (16, nb)) ----------------
__global__ __launch_bounds__(256) void k_M(const float* __restrict__ P,
                                           const float* __restrict__ pwr,
                                           const float* __restrict__ pwi,
                                           u16* __restrict__ Abig, int b0) {
    int b = b0 + blockIdx.y;
    int pair = blockIdx.x * 256 + threadIdx.x;   // 0..4095
    __shared__ float P0[64][64], P1[64][64];
    __shared__ float Wr[64][64], Wi2[64][64];
    for (int i = threadIdx.x; i < 4096; i += 256) {
        P0[i >> 6][i & 63] = P[(size_t)(b * 2 + 0) * 4096 + i];
        P1[i >> 6][i & 63] = P[(size_t)(b * 2 + 1) * 4096 + i];
        Wr[i >> 6][i & 63] = pwr[i];
        Wi2[i >> 6][i & 63] = pwi[i];
    }
    __syncthreads();
    int co = pair >> 6, e = pair & 63;
    float m1 = 0.f, m2 = 0.f, m3 = 0.f, m4 = 0.f;
#pragma unroll 8
    for (int c = 0; c < 64; ++c) {
        float pr = Wr[co][c], pi = Wi2[co][c];
        float a0 = P0[c][e], a1 = P1[c][e];
        m1 = fmaf(pr, a0, m1);
        m2 = fmaf(pi, a1, m2);
        m3 = fmaf(pr, a1, m3);
        m4 = fmaf(pi, a0, m4);
    }
    u16* AB = Abig + (size_t)b * 16384;
    AB[(2 * co) * 128 + 2 * e]         = f2bf(m1);
    AB[(2 * co) * 128 + 2 * e + 1]     = f2bf(-m2);
    AB[(2 * co + 1) * 128 + 2 * e]     = f2bf(m4);
    AB[(2 * co + 1) * 128 + 2 * e + 1] = f2bf(m3);
}

// ---------------- Kernel E (fallback): transpose vpack [64][HWS] u32 -> vT [HWS][64] u32 ----------------
__global__ __launch_bounds__(256) void k_vt(const u32* __restrict__ in,
                                            u32* __restrict__ outp) {
    __shared__ u32 tile[64][65];
    int p0 = blockIdx.x << 6;
    int t = threadIdx.x;
    for (int i = t; i < 4096; i += 256) {
        int e = i >> 6, c = i & 63;
        tile[e][c] = in[(size_t)e * HWS + p0 + c];
    }
    __syncthreads();
    for (int i = t; i < 4096; i += 256) {
        int r = i >> 6, e = i & 63;
        outp[(size_t)(p0 + r) * 64 + e] = tile[e][r];
    }
}

// ---------------- Kernel F (fallback): out = A_big * vT via MFMA (no LDS) ----------------
__global__ __launch_bounds__(256) void k_out(const u16* __restrict__ Abig,
                                             const u16* __restrict__ vT,
                                             float* __restrict__ outb) {
    const int p0 = blockIdx.x << 6;
    const int t = threadIdx.x, lane = t & 63, w = t >> 6;
    const int l15 = lane & 15, l4 = lane >> 4;

    bf16x8 Af[2][4];
#pragma unroll
    for (int cf = 0; cf < 2; ++cf)
#pragma unroll
        for (int ks = 0; ks < 4; ++ks)
            Af[cf][ks] = *(const bf16x8*)&Abig[(size_t)(32 * w + 16 * cf + l15) * 128 + 32 * ks + 8 * l4];

    f32x4 zz = {0.f, 0.f, 0.f, 0.f};
    f32x4 acc[2][4];
#pragma unroll
    for (int cf = 0; cf < 2; ++cf)
#pragma unroll
        for (int nf = 0; nf < 4; ++nf) acc[cf][nf] = zz;

#pragma unroll
    for (int ks = 0; ks < 4; ++ks) {
        bf16x8 Bf[4];
#pragma unroll
        for (int nf = 0; nf < 4; ++nf)
            Bf[nf] = *(const bf16x8*)&vT[(size_t)(p0 + 16 * nf + l15) * 128 + 32 * ks + 8 * l4];
#pragma unroll
        for (int cf = 0; cf < 2; ++cf)
#pragma unroll
            for (int nf = 0; nf < 4; ++nf)
                acc[cf][nf] = __builtin_amdgcn_mfma_f32_16x16x32_bf16(Af[cf][ks], Bf[nf], acc[cf][nf], 0, 0, 0);
    }

    float2* o2 = (float2*)outb;
#pragma unroll
    for (int cf = 0; cf < 2; ++cf)
#pragma unroll
        for (int nf = 0; nf < 4; ++nf) {
            int co = 16 * w + 8 * cf + 2 * l4;
            int p = p0 + 16 * nf + l15;
            o2[(size_t)co * HWS + p]       = make_float2(acc[cf][nf][0], acc[cf][nf][1]);
            o2[(size_t)(co + 1) * HWS + p] = make_float2(acc[cf][nf][2], acc[cf][nf][3]);
        }
}

// ---------------- Kernel F2: out = A_big * v via LDS-staged vpack ----------------
__global__ __launch_bounds__(256) void k_out2(const u16* __restrict__ Abig,
                                              const u32* __restrict__ vpk,
                                              float* __restrict__ outb,
                                              int b0, size_t vst, size_t ost) {
    const int z = blockIdx.z;
    const int b = b0 + z;
    vpk += (size_t)z * vst; outb += (size_t)z * ost;
    __shared__ u32 Tep[64][65];
    const int p0 = blockIdx.x << 6;
    const int t = threadIdx.x, lane = t & 63, w = t >> 6;
    const int l15 = lane & 15, l4 = lane >> 4;
    const u16* AB = Abig + (size_t)b * 16384;

    bf16x8 Af[2][4];
#pragma unroll
    for (int cf = 0; cf < 2; ++cf)
#pragma unroll
        for (int ks = 0; ks < 4; ++ks)
            Af[cf][ks] = *(const bf16x8*)&AB[(size_t)(32 * w + 16 * cf + l15) * 128 + 32 * ks + 8 * l4];

    for (int i = t; i < 4096; i += 256) {
        int e = i >> 6, tok = i & 63;
        Tep[e][tok] = vpk[(size_t)e * HWS + p0 + tok];
    }
    __syncthreads();

    f32x4 zz = {0.f, 0.f, 0.f, 0.f};
    f32x4 acc[2][4];
#pragma unroll
    for (int cf = 0; cf < 2; ++cf)
#pragma unroll
        for (int nf = 0; nf < 4; ++nf) acc[cf][nf] = zz;

#pragma unroll
    for (int ks = 0; ks < 4; ++ks) {
        bf16x8 Bf[4];
#pragma unroll
        for (int nf = 0; nf < 4; ++nf) {
            int tok = 16 * nf + l15;
            int e0 = 16 * ks + 4 * l4;
            union { u32 u[4]; bf16x8 v; } bb;
#pragma unroll
            for (int j = 0; j < 4; ++j) bb.u[j] = Tep[e0 + j][tok];
            Bf[nf] = bb.v;
        }
#pragma unroll
        for (int cf = 0; cf < 2; ++cf)
#pragma unroll
            for (int nf = 0; nf < 4; ++nf)
                acc[cf][nf] = __builtin_amdgcn_mfma_f32_16x16x32_bf16(Af[cf][ks], Bf[nf], acc[cf][nf], 0, 0, 0);
    }

    float2* o2 = (float2*)outb;
#pragma unroll
    for (int cf = 0; cf < 2; ++cf)
#pragma unroll
        for (int nf = 0; nf < 4; ++nf) {
            int co = 16 * w + 8 * cf + 2 * l4;
            int p = p0 + 16 * nf + l15;
            o2[(size_t)co * HWS + p]       = make_float2(acc[cf][nf][0], acc[cf][nf][1]);
            o2[(size_t)(co + 1) * HWS + p] = make_float2(acc[cf][nf][2], acc[cf][nf][3]);
        }
}

extern "C" void kernel_launch(void* const* d_in, const int* in_sizes, int n_in,
                              void* d_out, int out_size, void* d_ws, size_t ws_size,
                              hipStream_t stream) {
    const float* x      = (const float*)d_in[0];
    const float* qkv_wr = (const float*)d_in[1];
    const float* qkv_wi = (const float*)d_in[2];
    const float* dw_wr  = (const float*)d_in[3];
    const float* dw_wi  = (const float*)d_in[4];
    const float* p_wr   = (const float*)d_in[5];
    const float* p_wi   = (const float*)d_in[6];
    float* out = (float*)d_out;
    const size_t OSTR = (size_t)64 * HWS * 2;   // floats per batch of output

    const bool z2  = ws_size >= 236000000ull;   // fully per-b-strided buffers
    const bool f14 = !z2 && ws_size >= 118200000ull;

    char* base = (char*)d_ws;

    if (z2) {
        // per-b strided layout (~235.9 MB)
        u32*   qs   = (u32*)base;                          // 2 x 50,724,864 B
        u16*   dwp  = (u16*)(base + 101449728);            // 2 x 33,554,432 B
        u16*   xTr  = (u16*)(base + 168558592);            // 2 x (8.39+8.39) MB
        u16*   xTi  = xTr + (size_t)HWS * 64;
        u32*   vpk  = (u32*)(base + 202113024);            // 2 x 16,777,216 B
        u16*   wbf  = (u16*)(base + 235667456);
        float* rnsum = (float*)(base + 235741184);
        float* attn  = rnsum + 512;
        float* Pbuf  = attn + 16384;
        u16*   Abig  = (u16*)(Pbuf + 16384);

        const size_t XT_ST = 8388608;     // u16 per b (both planes)
        const size_t QS_ST = 12681216;    // u32 per b
        const size_t DW_ST = 16777216;    // u16 per b
        const size_t VP_ST = 4194304;     // u32 per b

        k_prep<<<66, 256, 0, stream>>>(qkv_wr, qkv_wi, wbf, rnsum, 512 + 16384);
        k_xt<<<dim3(1024, 1, 2), 256, 0, stream>>>(x, xTr, xTi, OSTR, XT_ST);
        // NPR = 516 row-pairs; grid = 8*6*ceil(516/8) = 3120
        k_qkv<<<3120, 256, 0, stream>>>(xTr, xTi, wbf, qs, XT_ST, QS_ST, 516);
        k_dw<<<dim3(12288, 1, 2), 256, 0, stream>>>(qs, dw_wr, dw_wi, dwp, vpk,
                                                    QS_ST, DW_ST, VP_ST);
        k_qk<<<dim3(64, 2, 2), 256, 0, stream>>>(dwp, rnsum, attn, 0, DW_ST);
        k_prob<<<dim3(2, 2), 64, 0, stream>>>(attn, rnsum, Pbuf, 0);
        k_M<<<dim3(16, 2), 256, 0, stream>>>(Pbuf, p_wr, p_wi, Abig, 0);
        k_out2<<<dim3(1024, 1, 2), 256, 0, stream>>>(Abig, vpk, out, 0, VP_ST, OSTR);
        return;
    }

    // shared-buffer layouts (round-14 / round-13 proven paths)
    u32*   qs   = (u32*)base;                               // 50,724,864 B
    u16*   dwp  = (u16*)(base + 50724864);                  // 33,554,432 B
    char*  xreg = base + 50724864 + 33554432;               // 16,777,216 B
    u16*   xTr  = (u16*)xreg;
    u16*   xTi  = xTr + (size_t)HWS * 64;
    u32*   vT   = (u32*)xreg;                               // fallback-13: vT aliases xT
    u32*   vpkW = (u32*)(base + 101056512);                 // f14 only
    size_t tail = f14 ? 117833728ull : 101056512ull;
    u16*   wbf  = (u16*)(base + tail);
    float* rnsum = (float*)(base + tail + 73728);
    float* attn  = rnsum + 512;
    float* Pbuf  = attn + 16384;
    u16*   Abig  = (u16*)(Pbuf + 16384);

    k_prep<<<66, 256, 0, stream>>>(qkv_wr, qkv_wi, wbf, rnsum, 512 + 16384);

    for (int b = 0; b < 2; ++b) {
        const float* xb = x + (size_t)b * OSTR;
        u32* vpack = f14 ? vpkW : (u32*)(out + (size_t)b * OSTR);
        k_xt<<<dim3(1024, 1, 1), 256, 0, stream>>>(xb, xTr, xTi, 0, 0);
        // NPR = 258; grid = 8*6*ceil(258/8) = 1584
        k_qkv<<<1584, 256, 0, stream>>>(xTr, xTi, wbf, qs, 0, 0, 258);
        k_dw<<<dim3(12288, 1, 1), 256, 0, stream>>>(qs, dw_wr, dw_wi, dwp, vpack, 0, 0, 0);
        k_qk<<<dim3(64, 2, 1), 256, 0, stream>>>(dwp, rnsum, attn, b, 0);
        k_prob<<<dim3(2, 1), 64, 0, stream>>>(attn, rnsum, Pbuf, b);
        k_M<<<dim3(16, 1), 256, 0, stream>>>(Pbuf, p_wr, p_wi, Abig, b);
        if (f14)
            k_out2<<<dim3(1024, 1, 1), 256, 0, stream>>>(Abig, vpkW,
                                                         out + (size_t)b * OSTR, b, 0, 0);
    }
    if (!f14) {
        for (int b = 0; b < 2; ++b) {
            u32* vpack = (u32*)(out + (size_t)b * OSTR);
            k_vt<<<1024, 256, 0, stream>>>(vpack, vT);
            k_out<<<1024, 256, 0, stream>>>(Abig + (size_t)b * 16384, (const u16*)vT,
                                            out + (size_t)b * OSTR);
        }
    }
}

// Round 23
// 167.782 us; speedup vs baseline: 1.2672x; 1.0134x over previous
//
#include <hip/hip_runtime.h>

#define HWS 65536   // 256*256
#define SPZ 66048   // (256+2)*256 halo strip positions

typedef __attribute__((ext_vector_type(8))) short bf16x8;
typedef __attribute__((ext_vector_type(4))) float f32x4;
typedef unsigned int u32;
typedef unsigned short u16;

__device__ __forceinline__ u16 f2bf(float x) {
    u32 u = __float_as_uint(x);
    return (u16)((u + 0x7fffu + ((u >> 16) & 1u)) >> 16);
}
__device__ __forceinline__ float bf2f(u32 h) { return __uint_as_float(h << 16); }
// HW packed bf16 convert (RNE, identical rounding to f2bf): lo=a, hi=b
__device__ __forceinline__ u32 cvtpk(float a, float b) {
    u32 r;
    asm("v_cvt_pk_bf16_f32 %0, %1, %2" : "=v"(r) : "v"(a), "v"(b));
    return r;
}
// packed bf16 dot2: d = a.lo*b.lo + a.hi*b.hi + c
__device__ __forceinline__ float dot2bf(u32 a, u32 b, float c) {
    float r;
    asm("v_dot2_f32_bf16 %0, %1, %2, %3" : "=v"(r) : "v"(a), "v"(b), "v"(c));
    return r;
}

// ---------------- prep: weight cvt + dw weight pairs + zero accumulators ----------------
// wdot[ch*18 + tap*2 + 0] = (w0, -w1) bf16 pair; +1 = (w1, w0)
__global__ void k_prep(const float* __restrict__ wr, const float* __restrict__ wi,
                       const float* __restrict__ dr, const float* __restrict__ di,
                       u16* __restrict__ wbf, u32* __restrict__ wdot,
                       float* __restrict__ zbuf, int nz) {
    int i = blockIdx.x * 256 + threadIdx.x;
    if (i < 12288) {
        wbf[i]         = f2bf(wr[i]);
        wbf[12288 + i] = f2bf(wi[i]);
        wbf[24576 + i] = f2bf(-wi[i]);
    }
    if (i < 1728) {                        // 192 ch x 9 taps
        float w0 = dr[i], w1 = di[i];
        wdot[i * 2 + 0] = (u32)f2bf(w0) | ((u32)f2bf(-w1) << 16);
        wdot[i * 2 + 1] = (u32)f2bf(w1) | ((u32)f2bf(w0) << 16);
    }
    if (i < nz) zbuf[i] = 0.f;
}

// ---------------- Kernel X: transpose+convert x -> xT planes in MFMA-fragment order ----------
__global__ __launch_bounds__(256) void k_xt(const float* __restrict__ x,
                                            u16* __restrict__ xTr,
                                            u16* __restrict__ xTi,
                                            size_t xs, size_t ts) {
    const int b = blockIdx.z;
    x += (size_t)b * xs; xTr += (size_t)b * ts; xTi += (size_t)b * ts;
    __shared__ u16 Tr[64][74], Ti[64][74];
    int p0 = blockIdx.x << 6;
    int t = threadIdx.x;
    const float2* x2 = (const float2*)x;
    for (int i = t; i < 2048; i += 256) {        // (ci-pair, c)
        int cp = i >> 6, c = i & 63;
        int ci = cp << 1;
        float2 v0 = x2[(size_t)ci * HWS + p0 + c];
        float2 v1 = x2[(size_t)(ci + 1) * HWS + p0 + c];
        *(u32*)&Tr[c][ci] = cvtpk(v0.x, v1.x);
        *(u32*)&Ti[c][ci] = cvtpk(v0.y, v1.y);
    }
    __syncthreads();
    u32* dr = (u32*)xTr;
    u32* di = (u32*)xTi;
    for (int i = t; i < 2048; i += 256) {        // fragment-order store
        int tb = i >> 9, rem = i & 511;          // 4 tok-blocks x 512 u32
        int chunk = rem >> 2, w4 = rem & 3;      // chunk = l15 + l4*16 + ks*64
        int tl  = chunk & 15;
        int l4c = (chunk >> 4) & 3;
        int ksc = chunk >> 6;
        int token = tb * 16 + tl;
        int cio = ksc * 32 + l4c * 8 + w4 * 2;
        size_t dst = (size_t)(p0 + tb * 16) * 32 + rem;
        dr[dst] = *(u32*)&Tr[token][cio];
        di[dst] = *(u32*)&Ti[token][cio];
    }
}

// ---------------- Kernel A: qkv 1x1 complex conv, fragment-linear B loads ----------------
__global__ __launch_bounds__(256) void k_qkv(const u16* __restrict__ xTr,
                                             const u16* __restrict__ xTi,
                                             const u16* __restrict__ wbf,
                                             u32* __restrict__ qs,
                                             size_t ts, size_t qsst, int NPR) {
    __shared__ u32 Tep[32 * 132];    // 16896 B
    const int bid = blockIdx.x;
    const int xcd = bid & 7, j = bid >> 3;
    const int cog = j % 6;               // 0..5, 32 co each
    const int pr  = xcd + 8 * (j / 6);   // row-pair index
    if (pr >= NPR) return;
    const int z  = pr / 258;
    const int rt = pr % 258;             // 0..257
    xTr += (size_t)z * ts; xTi += (size_t)z * ts; qs += (size_t)z * qsst;
    const int w = rt - 1;                // image row (may be OOB -> zeros)
    const int t = threadIdx.x, lane = t & 63, wv = t >> 6;
    const int l15 = lane & 15, l4 = lane >> 4;
    const bool valid = (unsigned)w < 256u;

    bf16x8 Ar[2][2], Ai[2][2], An[2][2];
#pragma unroll
    for (int cf = 0; cf < 2; ++cf)
#pragma unroll
        for (int ks = 0; ks < 2; ++ks) {
            size_t off = (size_t)(cog * 32 + 16 * cf + l15) * 64 + 32 * ks + 8 * l4;
            Ar[cf][ks] = *(const bf16x8*)&wbf[off];
            Ai[cf][ks] = *(const bf16x8*)&wbf[12288 + off];
            An[cf][ks] = *(const bf16x8*)&wbf[24576 + off];
        }

    const f32x4 zz = {0.f, 0.f, 0.f, 0.f};
    const int ln2 = lane & 31, rsel = lane >> 5;

#pragma unroll
    for (int half = 0; half < 2; ++half) {
        __syncthreads();                          // Tep reuse guard
#pragma unroll
        for (int pfh = 0; pfh < 2; ++pfh) {
            const int tokh = pfh * 64 + wv * 16 + l15;   // token within half
            f32x4 cr[2] = {zz, zz}, cim[2] = {zz, zz};
            if (valid) {
                size_t base = ((size_t)w * 256 + half * 128 + pfh * 64 + wv * 16) * 64
                              + lane * 8;
                bf16x8 br[2], bi[2];
                br[0] = *(const bf16x8*)&xTr[base];
                br[1] = *(const bf16x8*)&xTr[base + 512];
                bi[0] = *(const bf16x8*)&xTi[base];
                bi[1] = *(const bf16x8*)&xTi[base + 512];
#pragma unroll
                for (int ks = 0; ks < 2; ++ks)
#pragma unroll
                    for (int cf = 0; cf < 2; ++cf) {
                        cr[cf]  = __builtin_amdgcn_mfma_f32_16x16x32_bf16(Ar[cf][ks], br[ks], cr[cf], 0, 0, 0);
                        cr[cf]  = __builtin_amdgcn_mfma_f32_16x16x32_bf16(An[cf][ks], bi[ks], cr[cf], 0, 0, 0);
                        cim[cf] = __builtin_amdgcn_mfma_f32_16x16x32_bf16(Ai[cf][ks], br[ks], cim[cf], 0, 0, 0);
                        cim[cf] = __builtin_amdgcn_mfma_f32_16x16x32_bf16(Ar[cf][ks], bi[ks], cim[cf], 0, 0, 0);
                    }
            }
#pragma unroll
            for (int cf = 0; cf < 2; ++cf)
#pragma unroll
                for (int r = 0; r < 4; ++r) {
                    int col = 16 * cf + 4 * l4 + r;      // local co 0..31
                    Tep[col * 132 + tokh] = valid ? cvtpk(cr[cf][r], cim[cf][r]) : 0u;
                }
        }
        __syncthreads();
#pragma unroll
        for (int k = 0; k < 4; ++k) {
            int co = wv + 4 * (2 * k + rsel);
            uint4 vv = *(const uint4*)&Tep[co * 132 + 4 * ln2];
            *(uint4*)&qs[(size_t)(cog * 32 + co) * SPZ + rt * 256 + half * 128 + 4 * ln2] = vv;
        }
    }
}

// ---------------- Kernel B: depthwise 3x3 complex conv via v_dot2_f32_bf16 ----------------
// wave == one image row; uint4 loads + shfl halo; 72 dot2/thread.
__global__ __launch_bounds__(256) void k_dw(const u32* __restrict__ qs,
                                            const u32* __restrict__ wdot,
                                            u16* __restrict__ dwp,
                                            u32* __restrict__ vpack,
                                            size_t qsst, size_t dst, size_t vst) {
    const int b = blockIdx.z;
    qs += (size_t)b * qsst; dwp += (size_t)b * dst; vpack += (size_t)b * vst;
    const int ch = blockIdx.x >> 6;                         // uniform -> s_loads
    const int p4 = (((blockIdx.x & 63) << 8) + threadIdx.x) << 2;
    const int r = p4 >> 8, h = p4 & 255;                    // h = 4*laneInRow
    const u32* src = qs + (size_t)ch * SPZ + r * 256;

    u32 wA[9], wB[9];
#pragma unroll
    for (int tt = 0; tt < 9; ++tt) {
        wA[tt] = wdot[(ch * 9 + tt) * 2 + 0];
        wB[tt] = wdot[(ch * 9 + tt) * 2 + 1];
    }

    u32 uv[3][6];
#pragma unroll
    for (int du = 0; du < 3; ++du) {
        uint4 W = *(const uint4*)&src[du * 256 + h];        // coalesced 16B/lane
        u32 left  = (u32)__shfl_up((int)W.w, 1);            // word at h-1
        u32 right = (u32)__shfl_down((int)W.x, 1);          // word at h+4
        if (h == 0)   left = 0u;
        if (h == 252) right = 0u;
        uv[du][0] = left;  uv[du][1] = W.x; uv[du][2] = W.y;
        uv[du][3] = W.z;   uv[du][4] = W.w; uv[du][5] = right;
    }

    float ar[4] = {0.f, 0.f, 0.f, 0.f}, ai[4] = {0.f, 0.f, 0.f, 0.f};
#pragma unroll
    for (int du = 0; du < 3; ++du)
#pragma unroll
        for (int ct = 0; ct < 3; ++ct) {
            const int tap = du * 3 + ct;
            const u32 a = wA[tap], bw = wB[tap];
#pragma unroll
            for (int px = 0; px < 4; ++px) {
                ar[px] = dot2bf(a,  uv[du][px + ct], ar[px]);
                ai[px] = dot2bf(bw, uv[du][px + ct], ai[px]);
            }
        }

    if (ch < 128) {
        int pl = (ch < 64) ? 0 : 2;
        int c2 = ch & 63;
        uint2 rw = make_uint2(cvtpk(ar[0], ar[1]), cvtpk(ar[2], ar[3]));
        uint2 iw = make_uint2(cvtpk(ai[0], ai[1]), cvtpk(ai[2], ai[3]));
        *(uint2*)&dwp[(size_t)(pl * 64 + c2) * HWS + p4] = rw;
        *(uint2*)&dwp[(size_t)((pl + 1) * 64 + c2) * HWS + p4] = iw;
    } else {
        int e = ch - 128;
        uint4 vv = make_uint4(cvtpk(ar[0], ai[0]), cvtpk(ar[1], ai[1]),
                              cvtpk(ar[2], ai[2]), cvtpk(ar[3], ai[3]));
        *(uint4*)&vpack[(size_t)e * HWS + p4] = vv;
    }
}

// ---------------- Kernel C: q k^T + fused sumsq via MFMA (no LDS) ----------------
__global__ __launch_bounds__(256) void k_qk(const u16* __restrict__ dwp,
                                            float* __restrict__ rnsum,
                                            float* __restrict__ attn,
                                            int b0, size_t dst) {
    const int z = blockIdx.z;
    const int b = b0 + z;
    dwp += (size_t)z * dst;
    const int chunk = blockIdx.x;        // 0..63
    const int d = blockIdx.y;
    const int Kc = HWS >> 6;
    const int kc0 = chunk * Kc;
    const u16* qp = dwp + (size_t)d * 64 * HWS;
    const u16* kp = dwp + (size_t)(2 + d) * 64 * HWS;

    const int t = threadIdx.x, lane = t & 63, wid = t >> 6;
    const int wy = wid >> 1, wx = wid & 1;
    const int l15 = lane & 15, l4 = lane >> 4;

    f32x4 zz = {0.f, 0.f, 0.f, 0.f};
    f32x4 acc[2][2] = {{zz, zz}, {zz, zz}};
    float sq[2] = {0.f, 0.f}, sk[2] = {0.f, 0.f};

    const int iters = Kc >> 5;
    for (int ks = 0; ks < iters; ++ks) {
        int k0 = kc0 + ks * 32 + 8 * l4;
        bf16x8 aq[2], bk[2];
#pragma unroll
        for (int cf = 0; cf < 2; ++cf)
            aq[cf] = *(const bf16x8*)&qp[(size_t)(32 * wy + 16 * cf + l15) * HWS + k0];
#pragma unroll
        for (int ef = 0; ef < 2; ++ef)
            bk[ef] = *(const bf16x8*)&kp[(size_t)(32 * wx + 16 * ef + l15) * HWS + k0];

        if (wx == 0)
#pragma unroll
            for (int cf = 0; cf < 2; ++cf)
#pragma unroll
                for (int j = 0; j < 8; ++j) {
                    float f = bf2f((u16)aq[cf][j]);
                    sq[cf] = fmaf(f, f, sq[cf]);
                }
        if (wy == 0)
#pragma unroll
            for (int ef = 0; ef < 2; ++ef)
#pragma unroll
                for (int j = 0; j < 8; ++j) {
                    float f = bf2f((u16)bk[ef][j]);
                    sk[ef] = fmaf(f, f, sk[ef]);
                }

#pragma unroll
        for (int cf = 0; cf < 2; ++cf)
#pragma unroll
            for (int ef = 0; ef < 2; ++ef)
                acc[cf][ef] = __builtin_amdgcn_mfma_f32_16x16x32_bf16(aq[cf], bk[ef], acc[cf][ef], 0, 0, 0);
    }

#pragma unroll
    for (int cf = 0; cf < 2; ++cf)
#pragma unroll
        for (int ef = 0; ef < 2; ++ef)
#pragma unroll
            for (int r = 0; r < 4; ++r) {
                int cq = 32 * wy + 16 * cf + 4 * l4 + r;
                int ce = 32 * wx + 16 * ef + l15;
                atomicAdd(&attn[((b * 2 + d) * 64 + cq) * 64 + ce], acc[cf][ef][r]);
            }

    if (wx == 0)
#pragma unroll
        for (int cf = 0; cf < 2; ++cf) {
            float v = sq[cf];
            v += __shfl_xor(v, 16);
            v += __shfl_xor(v, 32);
            if (lane < 16)
                atomicAdd(&rnsum[((size_t)b * 128 + 32 * wy + 16 * cf + lane) * 2 + d], v);
        }
    if (wy == 0)
#pragma unroll
        for (int ef = 0; ef < 2; ++ef) {
            float v = sk[ef];
            v += __shfl_xor(v, 16);
            v += __shfl_xor(v, 32);
            if (lane < 16)
                atomicAdd(&rnsum[((size_t)b * 128 + 64 + 32 * wx + 16 * ef + lane) * 2 + d], v);
        }
}

// ---------------- Kernel D1: scale + row softmax -> P (grid (2 d, nb), 64 thr) ----------------
__global__ __launch_bounds__(64) void k_prob(const float* __restrict__ attn,
                                             const float* __restrict__ rnsum,
                                             float* __restrict__ P, int b0) {
    int d = blockIdx.x;
    int b = b0 + blockIdx.y;
    int t = threadIdx.x;
    __shared__ float rks[64];
    float sk = rnsum[((size_t)b * 128 + 64 + t) * 2 + d];
    rks[t] = 1.0f / fmaxf(sqrtf(sk), 1e-12f);
    float sq = rnsum[((size_t)b * 128 + t) * 2 + d];
    float rq = 1.0f / fmaxf(sqrtf(sq), 1e-12f);
    __syncthreads();

    const float* arow = attn + ((size_t)(b * 2 + d) * 64 + t) * 64;
    float v[64];
    float m = -1e30f;
#pragma unroll
    for (int e = 0; e < 64; ++e) { v[e] = arow[e] * rq * rks[e]; m = fmaxf(m, v[e]); }
    float ssum = 0.f;
#pragma unroll
    for (int e = 0; e < 64; ++e) { v[e] = __expf(v[e] - m); ssum += v[e]; }
    float r = 1.0f / ssum;
    float* prow = P + ((size_t)(b * 2 + d) * 64 + t) * 64;
#pragma unroll
    for (int e = 0; e < 64; ++e) prow[e] = v[e] * r;
}

// ---------------- Kernel D2: build A_big from P and proj weights (grid (16, nb)) ----------------
__global__ __launch_bounds__(256) void k_M(const float* __restrict__ P,
                                           const float* __restrict__ pwr,
                                           const float* __restrict__ pwi,
                                           u16* __restrict__ Abig, int b0) {
    int b = b0 + blockIdx.y;
    int pair = blockIdx.x * 256 + threadIdx.x;   // 0..4095
    __shared__ float P0[64][64], P1[64][64];
    __shared__ float Wr[64][64], Wi2[64][64];
    for (int i = threadIdx.x; i < 4096; i += 256) {
        P0[i >> 6][i & 63] = P[(size_t)(b * 2 + 0) * 4096 + i];
        P1[i >> 6][i & 63] = P[(size_t)(b * 2 + 1) * 4096 + i];
        Wr[i >> 6][i & 63] = pwr[i];
        Wi2[i >> 6][i & 63] = pwi[i];
    }
    __syncthreads();
    int co = pair >> 6, e = pair & 63;
    float m1 = 0.f, m2 = 0.f, m3 = 0.f, m4 = 0.f;
#pragma unroll 8
    for (int c = 0; c < 64; ++c) {
        float pr = Wr[co][c], pi = Wi2[co][c];
        float a0 = P0[c][e], a1 = P1[c][e];
        m1 = fmaf(pr, a0, m1);
        m2 = fmaf(pi, a1, m2);
        m3 = fmaf(pr, a1, m3);
        m4 = fmaf(pi, a0, m4);
    }
    u16* AB = Abig + (size_t)b * 16384;
    AB[(2 * co) * 128 + 2 * e]         = f2bf(m1);
    AB[(2 * co) * 128 + 2 * e + 1]     = f2bf(-m2);
    AB[(2 * co + 1) * 128 + 2 * e]     = f2bf(m4);
    AB[(2 * co + 1) * 128 + 2 * e + 1] = f2bf(m3);
}

// ---------------- Kernel E (fallback): transpose vpack [64][HWS] u32 -> vT [HWS][64] u32 ----------------
__global__ __launch_bounds__(256) void k_vt(const u32* __restrict__ in,
                                            u32* __restrict__ outp) {
    __shared__ u32 tile[64][65];
    int p0 = blockIdx.x << 6;
    int t = threadIdx.x;
    for (int i = t; i < 4096; i += 256) {
        int e = i >> 6, c = i & 63;
        tile[e][c] = in[(size_t)e * HWS + p0 + c];
    }
    __syncthreads();
    for (int i = t; i < 4096; i += 256) {
        int r = i >> 6, e = i & 63;
        outp[(size_t)(p0 + r) * 64 + e] = tile[e][r];
    }
}

// ---------------- Kernel F (fallback): out = A_big * vT via MFMA (no LDS) ----------------
__global__ __launch_bounds__(256) void k_out(const u16* __restrict__ Abig,
                                             const u16* __restrict__ vT,
                                             float* __restrict__ outb) {
    const int p0 = blockIdx.x << 6;
    const int t = threadIdx.x, lane = t & 63, w = t >> 6;
    const int l15 = lane & 15, l4 = lane >> 4;

    bf16x8 Af[2][4];
#pragma unroll
    for (int cf = 0; cf < 2; ++cf)
#pragma unroll
        for (int ks = 0; ks < 4; ++ks)
            Af[cf][ks] = *(const bf16x8*)&Abig[(size_t)(32 * w + 16 * cf + l15) * 128 + 32 * ks + 8 * l4];

    f32x4 zz = {0.f, 0.f, 0.f, 0.f};
    f32x4 acc[2][4];
#pragma unroll
    for (int cf = 0; cf < 2; ++cf)
#pragma unroll
        for (int nf = 0; nf < 4; ++nf) acc[cf][nf] = zz;

#pragma unroll
    for (int ks = 0; ks < 4; ++ks) {
        bf16x8 Bf[4];
#pragma unroll
        for (int nf = 0; nf < 4; ++nf)
            Bf[nf] = *(const bf16x8*)&vT[(size_t)(p0 + 16 * nf + l15) * 128 + 32 * ks + 8 * l4];
#pragma unroll
        for (int cf = 0; cf < 2; ++cf)
#pragma unroll
            for (int nf = 0; nf < 4; ++nf)
                acc[cf][nf] = __builtin_amdgcn_mfma_f32_16x16x32_bf16(Af[cf][ks], Bf[nf], acc[cf][nf], 0, 0, 0);
    }

    float2* o2 = (float2*)outb;
#pragma unroll
    for (int cf = 0; cf < 2; ++cf)
#pragma unroll
        for (int nf = 0; nf < 4; ++nf) {
            int co = 16 * w + 8 * cf + 2 * l4;
            int p = p0 + 16 * nf + l15;
            o2[(size_t)co * HWS + p]       = make_float2(acc[cf][nf][0], acc[cf][nf][1]);
            o2[(size_t)(co + 1) * HWS + p] = make_float2(acc[cf][nf][2], acc[cf][nf][3]);
        }
}

// ---------------- Kernel F2: out = A_big * v via LDS-staged vpack ----------------
__global__ __launch_bounds__(256) void k_out2(const u16* __restrict__ Abig,
                                              const u32* __restrict__ vpk,
                                              float* __restrict__ outb,
                                              int b0, size_t vst, size_t ost) {
    const int z = blockIdx.z;
    const int b = b0 + z;
    vpk += (size_t)z * vst; outb += (size_t)z * ost;
    __shared__ u32 Tep[64][65];
    const int p0 = blockIdx.x << 6;
    const int t = threadIdx.x, lane = t & 63, w = t >> 6;
    const int l15 = lane & 15, l4 = lane >> 4;
    const u16* AB = Abig + (size_t)b * 16384;

    bf16x8 Af[2][4];
#pragma unroll
    for (int cf = 0; cf < 2; ++cf)
#pragma unroll
        for (int ks = 0; ks < 4; ++ks)
            Af[cf][ks] = *(const bf16x8*)&AB[(size_t)(32 * w + 16 * cf + l15) * 128 + 32 * ks + 8 * l4];

    for (int i = t; i < 4096; i += 256) {
        int e = i >> 6, tok = i & 63;
        Tep[e][tok] = vpk[(size_t)e * HWS + p0 + tok];
    }
    __syncthreads();

    f32x4 zz = {0.f, 0.f, 0.f, 0.f};
    f32x4 acc[2][4];
#pragma unroll
    for (int cf = 0; cf < 2; ++cf)
#pragma unroll
        for (int nf = 0; nf < 4; ++nf) acc[cf][nf] = zz;

#pragma unroll
    for (int ks = 0; ks < 4; ++ks) {
        bf16x8 Bf[4];
#pragma unroll
        for (int nf = 0; nf < 4; ++nf) {
            int tok = 16 * nf + l15;
            int e0 = 16 * ks + 4 * l4;
            union { u32 u[4]; bf16x8 v; } bb;
#pragma unroll
            for (int j = 0; j < 4; ++j) bb.u[j] = Tep[e0 + j][tok];
            Bf[nf] = bb.v;
        }
#pragma unroll
        for (int cf = 0; cf < 2; ++cf)
#pragma unroll
            for (int nf = 0; nf < 4; ++nf)
                acc[cf][nf] = __builtin_amdgcn_mfma_f32_16x16x32_bf16(Af[cf][ks], Bf[nf], acc[cf][nf], 0, 0, 0);
    }

    float2* o2 = (float2*)outb;
#pragma unroll
    for (int cf = 0; cf < 2; ++cf)
#pragma unroll
        for (int nf = 0; nf < 4; ++nf) {
            int co = 16 * w + 8 * cf + 2 * l4;
            int p = p0 + 16 * nf + l15;
            o2[(size_t)co * HWS + p]       = make_float2(acc[cf][nf][0], acc[cf][nf][1]);
            o2[(size_t)(co + 1) * HWS + p] = make_float2(acc[cf][nf][2], acc[cf][nf][3]);
        }
}

extern "C" void kernel_launch(void* const* d_in, const int* in_sizes, int n_in,
                              void* d_out, int out_size, void* d_ws, size_t ws_size,
                              hipStream_t stream) {
    const float* x      = (const float*)d_in[0];
    const float* qkv_wr = (const float*)d_in[1];
    const float* qkv_wi = (const float*)d_in[2];
    const float* dw_wr  = (const float*)d_in[3];
    const float* dw_wi  = (const float*)d_in[4];
    const float* p_wr   = (const float*)d_in[5];
    const float* p_wi   = (const float*)d_in[6];
    float* out = (float*)d_out;
    const size_t OSTR = (size_t)64 * HWS * 2;   // floats per batch of output

    const bool z2  = ws_size >= 236000000ull;   // fully per-b-strided buffers
    const bool f14 = !z2 && ws_size >= 118200000ull;

    char* base = (char*)d_ws;

    if (z2) {
        // per-b strided layout (~236 MB)
        u32*   qs   = (u32*)base;                          // 2 x 50,724,864 B
        u16*   dwp  = (u16*)(base + 101449728);            // 2 x 33,554,432 B
        u16*   xTr  = (u16*)(base + 168558592);            // 2 x 8,388,608 B (both planes)
        u16*   xTi  = xTr + (size_t)HWS * 64;
        u32*   vpk  = (u32*)(base + 202113024);            // 2 x 16,777,216 B
        u16*   wbf  = (u16*)(base + 235667456);            // 73,728 B
        u32*   wdot = (u32*)(base + 235741184);            // 13,824 B
        float* rnsum = (float*)(base + 235755008);
        float* attn  = rnsum + 512;
        float* Pbuf  = attn + 16384;
        u16*   Abig  = (u16*)(Pbuf + 16384);

        const size_t XT_ST = 8388608;     // u16 per b (both planes)
        const size_t QS_ST = 12681216;    // u32 per b
        const size_t DW_ST = 16777216;    // u16 per b
        const size_t VP_ST = 4194304;     // u32 per b

        k_prep<<<66, 256, 0, stream>>>(qkv_wr, qkv_wi, dw_wr, dw_wi, wbf, wdot,
                                       rnsum, 512 + 16384);
        k_xt<<<dim3(1024, 1, 2), 256, 0, stream>>>(x, xTr, xTi, OSTR, XT_ST);
        k_qkv<<<3120, 256, 0, stream>>>(xTr, xTi, wbf, qs, XT_ST, QS_ST, 516);
        k_dw<<<dim3(12288, 1, 2), 256, 0, stream>>>(qs, wdot, dwp, vpk,
                                                    QS_ST, DW_ST, VP_ST);
        k_qk<<<dim3(64, 2, 2), 256, 0, stream>>>(dwp, rnsum, attn, 0, DW_ST);
        k_prob<<<dim3(2, 2), 64, 0, stream>>>(attn, rnsum, Pbuf, 0);
        k_M<<<dim3(16, 2), 256, 0, stream>>>(Pbuf, p_wr, p_wi, Abig, 0);
        k_out2<<<dim3(1024, 1, 2), 256, 0, stream>>>(Abig, vpk, out, 0, VP_ST, OSTR);
        return;
    }

    // shared-buffer layouts (round-14 / round-13 proven paths)
    u32*   qs   = (u32*)base;                               // 50,724,864 B
    u16*   dwp  = (u16*)(base + 50724864);                  // 33,554,432 B
    char*  xreg = base + 50724864 + 33554432;               // 16,777,216 B
    u16*   xTr  = (u16*)xreg;
    u16*   xTi  = xTr + (size_t)HWS * 64;
    u32*   vT   = (u32*)xreg;                               // fallback-13: vT aliases xT
    u32*   vpkW = (u32*)(base + 101056512);                 // f14 only
    size_t tail = f14 ? 117833728ull : 101056512ull;
    u16*   wbf  = (u16*)(base + tail);
    u32*   wdot = (u32*)(base + tail + 73728);
    float* rnsum = (float*)(base + tail + 87552);
    float* attn  = rnsum + 512;
    float* Pbuf  = attn + 16384;
    u16*   Abig  = (u16*)(Pbuf + 16384);

    k_prep<<<66, 256, 0, stream>>>(qkv_wr, qkv_wi, dw_wr, dw_wi, wbf, wdot,
                                   rnsum, 512 + 16384);

    for (int b = 0; b < 2; ++b) {
        const float* xb = x + (size_t)b * OSTR;
        u32* vpack = f14 ? vpkW : (u32*)(out + (size_t)b * OSTR);
        k_xt<<<dim3(1024, 1, 1), 256, 0, stream>>>(xb, xTr, xTi, 0, 0);
        k_qkv<<<1584, 256, 0, stream>>>(xTr, xTi, wbf, qs, 0, 0, 258);
        k_dw<<<dim3(12288, 1, 1), 256, 0, stream>>>(qs, wdot, dwp, vpack, 0, 0, 0);
        k_qk<<<dim3(64, 2, 1), 256, 0, stream>>>(dwp, rnsum, attn, b, 0);
        k_prob<<<dim3(2, 1), 64, 0, stream>>>(attn, rnsum, Pbuf, b);
        k_M<<<dim3(16, 1), 256, 0, stream>>>(Pbuf, p_wr, p_wi, Abig, b);
        if (f14)
            k_out2<<<dim3(1024, 1, 1), 256, 0, stream>>>(Abig, vpkW,
                                                         out + (size_t)b * OSTR, b, 0, 0);
    }
    if (!f14) {
        for (int b = 0; b < 2; ++b) {
            u32* vpack = (u32*)(out + (size_t)b * OSTR);
            k_vt<<<1024, 256, 0, stream>>>(vpack, vT);
            k_out<<<1024, 256, 0, stream>>>(Abig + (size_t)b * 16384, (const u16*)vT,
                                            out + (size_t)b * OSTR);
        }
    }
}

// Round 24
// 163.099 us; speedup vs baseline: 1.3035x; 1.0287x over previous
//
#include <hip/hip_runtime.h>

#define HWS 65536   // 256*256
#define SPZ 66048   // (256+2)*256 halo strip positions

typedef __attribute__((ext_vector_type(8))) short bf16x8;
typedef __attribute__((ext_vector_type(4))) float f32x4;
typedef unsigned int u32;
typedef unsigned short u16;

__device__ __forceinline__ u16 f2bf(float x) {
    u32 u = __float_as_uint(x);
    return (u16)((u + 0x7fffu + ((u >> 16) & 1u)) >> 16);
}
__device__ __forceinline__ float bf2f(u32 h) { return __uint_as_float(h << 16); }
// HW packed bf16 convert (RNE, identical rounding to f2bf): lo=a, hi=b
__device__ __forceinline__ u32 cvtpk(float a, float b) {
    u32 r;
    asm("v_cvt_pk_bf16_f32 %0, %1, %2" : "=v"(r) : "v"(a), "v"(b));
    return r;
}
// packed bf16 dot2: d = a.lo*b.lo + a.hi*b.hi + c
__device__ __forceinline__ float dot2bf(u32 a, u32 b, float c) {
    float r;
    asm("v_dot2_f32_bf16 %0, %1, %2, %3" : "=v"(r) : "v"(a), "v"(b), "v"(c));
    return r;
}

// ---------------- prep: weight cvt + dw weight pairs + zero accumulators ----------------
__global__ void k_prep(const float* __restrict__ wr, const float* __restrict__ wi,
                       const float* __restrict__ dr, const float* __restrict__ di,
                       u16* __restrict__ wbf, u32* __restrict__ wdot,
                       float* __restrict__ zbuf, int nz) {
    int i = blockIdx.x * 256 + threadIdx.x;
    if (i < 12288) {
        wbf[i]         = f2bf(wr[i]);
        wbf[12288 + i] = f2bf(wi[i]);
        wbf[24576 + i] = f2bf(-wi[i]);
    }
    if (i < 1728) {                        // 192 ch x 9 taps
        float w0 = dr[i], w1 = di[i];
        wdot[i * 2 + 0] = (u32)f2bf(w0) | ((u32)f2bf(-w1) << 16);
        wdot[i * 2 + 1] = (u32)f2bf(w1) | ((u32)f2bf(w0) << 16);
    }
    if (i < nz) zbuf[i] = 0.f;
}

// ---------------- Kernel X: transpose+convert x -> xT planes in MFMA-fragment order ----------
__global__ __launch_bounds__(256) void k_xt(const float* __restrict__ x,
                                            u16* __restrict__ xTr,
                                            u16* __restrict__ xTi,
                                            size_t xs, size_t ts) {
    const int b = blockIdx.z;
    x += (size_t)b * xs; xTr += (size_t)b * ts; xTi += (size_t)b * ts;
    __shared__ u16 Tr[64][74], Ti[64][74];
    int p0 = blockIdx.x << 6;
    int t = threadIdx.x;
    const float2* x2 = (const float2*)x;
    for (int i = t; i < 2048; i += 256) {        // (ci-pair, c)
        int cp = i >> 6, c = i & 63;
        int ci = cp << 1;
        float2 v0 = x2[(size_t)ci * HWS + p0 + c];
        float2 v1 = x2[(size_t)(ci + 1) * HWS + p0 + c];
        *(u32*)&Tr[c][ci] = cvtpk(v0.x, v1.x);
        *(u32*)&Ti[c][ci] = cvtpk(v0.y, v1.y);
    }
    __syncthreads();
    u32* dr = (u32*)xTr;
    u32* di = (u32*)xTi;
    for (int i = t; i < 2048; i += 256) {        // fragment-order store
        int tb = i >> 9, rem = i & 511;          // 4 tok-blocks x 512 u32
        int chunk = rem >> 2, w4 = rem & 3;      // chunk = l15 + l4*16 + ks*64
        int tl  = chunk & 15;
        int l4c = (chunk >> 4) & 3;
        int ksc = chunk >> 6;
        int token = tb * 16 + tl;
        int cio = ksc * 32 + l4c * 8 + w4 * 2;
        size_t dst = (size_t)(p0 + tb * 16) * 32 + rem;
        dr[dst] = *(u32*)&Tr[token][cio];
        di[dst] = *(u32*)&Ti[token][cio];
    }
}

// ---------------- Kernel A: qkv 1x1 complex conv, 2 rows/block, fragment-linear B ----------------
// NP2 = row-pairs (129 per batch); z = pr2/129, rows rt = (pr2%129)*2 + rr.
__global__ __launch_bounds__(256) void k_qkv(const u16* __restrict__ xTr,
                                             const u16* __restrict__ xTi,
                                             const u16* __restrict__ wbf,
                                             u32* __restrict__ qs,
                                             size_t ts, size_t qsst, int NP2) {
    __shared__ u32 Tep[32 * 132];    // 16896 B
    const int bid = blockIdx.x;
    const int xcd = bid & 7, j = bid >> 3;
    const int cog = j % 6;               // 0..5, 32 co each
    const int pr2 = xcd + 8 * (j / 6);   // row-pair index
    if (pr2 >= NP2) return;
    const int z  = pr2 / 129;
    const int rp = pr2 % 129;
    xTr += (size_t)z * ts; xTi += (size_t)z * ts; qs += (size_t)z * qsst;
    const int t = threadIdx.x, lane = t & 63, wv = t >> 6;
    const int l15 = lane & 15, l4 = lane >> 4;

    bf16x8 Ar[2][2], Ai[2][2], An[2][2];
#pragma unroll
    for (int cf = 0; cf < 2; ++cf)
#pragma unroll
        for (int ks = 0; ks < 2; ++ks) {
            size_t off = (size_t)(cog * 32 + 16 * cf + l15) * 64 + 32 * ks + 8 * l4;
            Ar[cf][ks] = *(const bf16x8*)&wbf[off];
            Ai[cf][ks] = *(const bf16x8*)&wbf[12288 + off];
            An[cf][ks] = *(const bf16x8*)&wbf[24576 + off];
        }

    const f32x4 zz = {0.f, 0.f, 0.f, 0.f};
    const int ln2 = lane & 31, rsel = lane >> 5;

#pragma unroll
    for (int rr = 0; rr < 2; ++rr) {
        const int rt = rp * 2 + rr;          // 0..257
        const int w = rt - 1;                // image row (may be OOB -> zeros)
        const bool valid = (unsigned)w < 256u;

#pragma unroll
        for (int half = 0; half < 2; ++half) {
            __syncthreads();                          // Tep reuse guard
#pragma unroll
            for (int pfh = 0; pfh < 2; ++pfh) {
                const int tokh = pfh * 64 + wv * 16 + l15;   // token within half
                f32x4 cr[2] = {zz, zz}, cim[2] = {zz, zz};
                if (valid) {
                    size_t base = ((size_t)w * 256 + half * 128 + pfh * 64 + wv * 16) * 64
                                  + lane * 8;
                    bf16x8 br[2], bi[2];
                    br[0] = *(const bf16x8*)&xTr[base];
                    br[1] = *(const bf16x8*)&xTr[base + 512];
                    bi[0] = *(const bf16x8*)&xTi[base];
                    bi[1] = *(const bf16x8*)&xTi[base + 512];
#pragma unroll
                    for (int ks = 0; ks < 2; ++ks)
#pragma unroll
                        for (int cf = 0; cf < 2; ++cf) {
                            cr[cf]  = __builtin_amdgcn_mfma_f32_16x16x32_bf16(Ar[cf][ks], br[ks], cr[cf], 0, 0, 0);
                            cr[cf]  = __builtin_amdgcn_mfma_f32_16x16x32_bf16(An[cf][ks], bi[ks], cr[cf], 0, 0, 0);
                            cim[cf] = __builtin_amdgcn_mfma_f32_16x16x32_bf16(Ai[cf][ks], br[ks], cim[cf], 0, 0, 0);
                            cim[cf] = __builtin_amdgcn_mfma_f32_16x16x32_bf16(Ar[cf][ks], bi[ks], cim[cf], 0, 0, 0);
                        }
                }
#pragma unroll
                for (int cf = 0; cf < 2; ++cf)
#pragma unroll
                    for (int r = 0; r < 4; ++r) {
                        int col = 16 * cf + 4 * l4 + r;      // local co 0..31
                        Tep[col * 132 + tokh] = valid ? cvtpk(cr[cf][r], cim[cf][r]) : 0u;
                    }
            }
            __syncthreads();
#pragma unroll
            for (int k = 0; k < 4; ++k) {
                int co = wv + 4 * (2 * k + rsel);
                uint4 vv = *(const uint4*)&Tep[co * 132 + 4 * ln2];
                *(uint4*)&qs[(size_t)(cog * 32 + co) * SPZ + rt * 256 + half * 128 + 4 * ln2] = vv;
            }
        }
    }
}

// ---------------- Kernel B: depthwise 3x3 complex conv via v_dot2_f32_bf16 ----------------
__global__ __launch_bounds__(256) void k_dw(const u32* __restrict__ qs,
                                            const u32* __restrict__ wdot,
                                            u16* __restrict__ dwp,
                                            u32* __restrict__ vpack,
                                            size_t qsst, size_t dst, size_t vst) {
    const int b = blockIdx.z;
    qs += (size_t)b * qsst; dwp += (size_t)b * dst; vpack += (size_t)b * vst;
    const int ch = blockIdx.x >> 6;                         // uniform -> s_loads
    const int p4 = (((blockIdx.x & 63) << 8) + threadIdx.x) << 2;
    const int r = p4 >> 8, h = p4 & 255;                    // h = 4*laneInRow
    const u32* src = qs + (size_t)ch * SPZ + r * 256;

    u32 wA[9], wB[9];
#pragma unroll
    for (int tt = 0; tt < 9; ++tt) {
        wA[tt] = wdot[(ch * 9 + tt) * 2 + 0];
        wB[tt] = wdot[(ch * 9 + tt) * 2 + 1];
    }

    u32 uv[3][6];
#pragma unroll
    for (int du = 0; du < 3; ++du) {
        uint4 W = *(const uint4*)&src[du * 256 + h];        // coalesced 16B/lane
        u32 left  = (u32)__shfl_up((int)W.w, 1);            // word at h-1
        u32 right = (u32)__shfl_down((int)W.x, 1);          // word at h+4
        if (h == 0)   left = 0u;
        if (h == 252) right = 0u;
        uv[du][0] = left;  uv[du][1] = W.x; uv[du][2] = W.y;
        uv[du][3] = W.z;   uv[du][4] = W.w; uv[du][5] = right;
    }

    float ar[4] = {0.f, 0.f, 0.f, 0.f}, ai[4] = {0.f, 0.f, 0.f, 0.f};
#pragma unroll
    for (int du = 0; du < 3; ++du)
#pragma unroll
        for (int ct = 0; ct < 3; ++ct) {
            const int tap = du * 3 + ct;
            const u32 a = wA[tap], bw = wB[tap];
#pragma unroll
            for (int px = 0; px < 4; ++px) {
                ar[px] = dot2bf(a,  uv[du][px + ct], ar[px]);
                ai[px] = dot2bf(bw, uv[du][px + ct], ai[px]);
            }
        }

    if (ch < 128) {
        int pl = (ch < 64) ? 0 : 2;
        int c2 = ch & 63;
        uint2 rw = make_uint2(cvtpk(ar[0], ar[1]), cvtpk(ar[2], ar[3]));
        uint2 iw = make_uint2(cvtpk(ai[0], ai[1]), cvtpk(ai[2], ai[3]));
        *(uint2*)&dwp[(size_t)(pl * 64 + c2) * HWS + p4] = rw;
        *(uint2*)&dwp[(size_t)((pl + 1) * 64 + c2) * HWS + p4] = iw;
    } else {
        int e = ch - 128;
        uint4 vv = make_uint4(cvtpk(ar[0], ai[0]), cvtpk(ar[1], ai[1]),
                              cvtpk(ar[2], ai[2]), cvtpk(ar[3], ai[3]));
        *(uint4*)&vpack[(size_t)e * HWS + p4] = vv;
    }
}

// ---------------- Kernel C: q k^T + fused sumsq via MFMA (no LDS) ----------------
__global__ __launch_bounds__(256) void k_qk(const u16* __restrict__ dwp,
                                            float* __restrict__ rnsum,
                                            float* __restrict__ attn,
                                            int b0, size_t dst) {
    const int z = blockIdx.z;
    const int b = b0 + z;
    dwp += (size_t)z * dst;
    const int chunk = blockIdx.x;        // 0..63
    const int d = blockIdx.y;
    const int Kc = HWS >> 6;
    const int kc0 = chunk * Kc;
    const u16* qp = dwp + (size_t)d * 64 * HWS;
    const u16* kp = dwp + (size_t)(2 + d) * 64 * HWS;

    const int t = threadIdx.x, lane = t & 63, wid = t >> 6;
    const int wy = wid >> 1, wx = wid & 1;
    const int l15 = lane & 15, l4 = lane >> 4;

    f32x4 zz = {0.f, 0.f, 0.f, 0.f};
    f32x4 acc[2][2] = {{zz, zz}, {zz, zz}};
    float sq[2] = {0.f, 0.f}, sk[2] = {0.f, 0.f};

    const int iters = Kc >> 5;
    for (int ks = 0; ks < iters; ++ks) {
        int k0 = kc0 + ks * 32 + 8 * l4;
        bf16x8 aq[2], bk[2];
#pragma unroll
        for (int cf = 0; cf < 2; ++cf)
            aq[cf] = *(const bf16x8*)&qp[(size_t)(32 * wy + 16 * cf + l15) * HWS + k0];
#pragma unroll
        for (int ef = 0; ef < 2; ++ef)
            bk[ef] = *(const bf16x8*)&kp[(size_t)(32 * wx + 16 * ef + l15) * HWS + k0];

        if (wx == 0)
#pragma unroll
            for (int cf = 0; cf < 2; ++cf)
#pragma unroll
                for (int j = 0; j < 8; ++j) {
                    float f = bf2f((u16)aq[cf][j]);
                    sq[cf] = fmaf(f, f, sq[cf]);
                }
        if (wy == 0)
#pragma unroll
            for (int ef = 0; ef < 2; ++ef)
#pragma unroll
                for (int j = 0; j < 8; ++j) {
                    float f = bf2f((u16)bk[ef][j]);
                    sk[ef] = fmaf(f, f, sk[ef]);
                }

#pragma unroll
        for (int cf = 0; cf < 2; ++cf)
#pragma unroll
            for (int ef = 0; ef < 2; ++ef)
                acc[cf][ef] = __builtin_amdgcn_mfma_f32_16x16x32_bf16(aq[cf], bk[ef], acc[cf][ef], 0, 0, 0);
    }

#pragma unroll
    for (int cf = 0; cf < 2; ++cf)
#pragma unroll
        for (int ef = 0; ef < 2; ++ef)
#pragma unroll
            for (int r = 0; r < 4; ++r) {
                int cq = 32 * wy + 16 * cf + 4 * l4 + r;
                int ce = 32 * wx + 16 * ef + l15;
                atomicAdd(&attn[((b * 2 + d) * 64 + cq) * 64 + ce], acc[cf][ef][r]);
            }

    if (wx == 0)
#pragma unroll
        for (int cf = 0; cf < 2; ++cf) {
            float v = sq[cf];
            v += __shfl_xor(v, 16);
            v += __shfl_xor(v, 32);
            if (lane < 16)
                atomicAdd(&rnsum[((size_t)b * 128 + 32 * wy + 16 * cf + lane) * 2 + d], v);
        }
    if (wy == 0)
#pragma unroll
        for (int ef = 0; ef < 2; ++ef) {
            float v = sk[ef];
            v += __shfl_xor(v, 16);
            v += __shfl_xor(v, 32);
            if (lane < 16)
                atomicAdd(&rnsum[((size_t)b * 128 + 64 + 32 * wx + 16 * ef + lane) * 2 + d], v);
        }
}

// ---------------- Kernel D1: scale + row softmax -> P (grid (2 d, nb), 64 thr) ----------------
__global__ __launch_bounds__(64) void k_prob(const float* __restrict__ attn,
                                             const float* __restrict__ rnsum,
                                             float* __restrict__ P, int b0) {
    int d = blockIdx.x;
    int b = b0 + blockIdx.y;
    int t = threadIdx.x;
    __shared__ float rks[64];
    float sk = rnsum[((size_t)b * 128 + 64 + t) * 2 + d];
    rks[t] = 1.0f / fmaxf(sqrtf(sk), 1e-12f);
    float sq = rnsum[((size_t)b * 128 + t) * 2 + d];
    float rq = 1.0f / fmaxf(sqrtf(sq), 1e-12f);
    __syncthreads();

    const float* arow = attn + ((size_t)(b * 2 + d) * 64 + t) * 64;
    float v[64];
    float m = -1e30f;
#pragma unroll
    for (int e = 0; e < 64; ++e) { v[e] = arow[e] * rq * rks[e]; m = fmaxf(m, v[e]); }
    float ssum = 0.f;
#pragma unroll
    for (int e = 0; e < 64; ++e) { v[e] = __expf(v[e] - m); ssum += v[e]; }
    float r = 1.0f / ssum;
    float* prow = P + ((size_t)(b * 2 + d) * 64 + t) * 64;
#pragma unroll
    for (int e = 0; e < 64; ++e) prow[e] = v[e] * r;
}

// ---------------- Kernel D2: build A_big from P and proj weights (grid (16, nb)) ----------------
__global__ __launch_bounds__(256) void k_M(const float* __restrict__ P,
                                           const float* __restrict__ pwr,
                                           const float* __restrict__ pwi,
                                           u16* __restrict__ Abig, int b0) {
    int b = b0 + blockIdx.y;
    int pair = blockIdx.x * 256 + threadIdx.x;   // 0..4095
    __shared__ float P0[64][64], P1[64][64];
    __shared__ float Wr[64][64], Wi2[64][64];
    for (int i = threadIdx.x; i < 4096; i += 256) {
        P0[i >> 6][i & 63] = P[(size_t)(b * 2 + 0) * 4096 + i];
        P1[i >> 6][i & 63] = P[(size_t)(b * 2 + 1) * 4096 + i];
        Wr[i >> 6][i & 63] = pwr[i];
        Wi2[i >> 6][i & 63] = pwi[i];
    }
    __syncthreads();
    int co = pair >> 6, e = pair & 63;
    float m1 = 0.f, m2 = 0.f, m3 = 0.f, m4 = 0.f;
#pragma unroll 8
    for (int c = 0; c < 64; ++c) {
        float pr = Wr[co][c], pi = Wi2[co][c];
        float a0 = P0[c][e], a1 = P1[c][e];
        m1 = fmaf(pr, a0, m1);
        m2 = fmaf(pi, a1, m2);
        m3 = fmaf(pr, a1, m3);
        m4 = fmaf(pi, a0, m4);
    }
    u16* AB = Abig + (size_t)b * 16384;
    AB[(2 * co) * 128 + 2 * e]         = f2bf(m1);
    AB[(2 * co) * 128 + 2 * e + 1]     = f2bf(-m2);
    AB[(2 * co + 1) * 128 + 2 * e]     = f2bf(m4);
    AB[(2 * co + 1) * 128 + 2 * e + 1] = f2bf(m3);
}

// ---------------- Kernel E (fallback): transpose vpack [64][HWS] u32 -> vT [HWS][64] u32 ----------------
__global__ __launch_bounds__(256) void k_vt(const u32* __restrict__ in,
                                            u32* __restrict__ outp) {
    __shared__ u32 tile[64][65];
    int p0 = blockIdx.x << 6;
    int t = threadIdx.x;
    for (int i = t; i < 4096; i += 256) {
        int e = i >> 6, c = i & 63;
        tile[e][c] = in[(size_t)e * HWS + p0 + c];
    }
    __syncthreads();
    for (int i = t; i < 4096; i += 256) {
        int r = i >> 6, e = i & 63;
        outp[(size_t)(p0 + r) * 64 + e] = tile[e][r];
    }
}

// ---------------- Kernel F (fallback): out = A_big * vT via MFMA (no LDS) ----------------
__global__ __launch_bounds__(256) void k_out(const u16* __restrict__ Abig,
                                             const u16* __restrict__ vT,
                                             float* __restrict__ outb) {
    const int p0 = blockIdx.x << 6;
    const int t = threadIdx.x, lane = t & 63, w = t >> 6;
    const int l15 = lane & 15, l4 = lane >> 4;

    bf16x8 Af[2][4];
#pragma unroll
    for (int cf = 0; cf < 2; ++cf)
#pragma unroll
        for (int ks = 0; ks < 4; ++ks)
            Af[cf][ks] = *(const bf16x8*)&Abig[(size_t)(32 * w + 16 * cf + l15) * 128 + 32 * ks + 8 * l4];

    f32x4 zz = {0.f, 0.f, 0.f, 0.f};
    f32x4 acc[2][4];
#pragma unroll
    for (int cf = 0; cf < 2; ++cf)
#pragma unroll
        for (int nf = 0; nf < 4; ++nf) acc[cf][nf] = zz;

#pragma unroll
    for (int ks = 0; ks < 4; ++ks) {
        bf16x8 Bf[4];
#pragma unroll
        for (int nf = 0; nf < 4; ++nf)
            Bf[nf] = *(const bf16x8*)&vT[(size_t)(p0 + 16 * nf + l15) * 128 + 32 * ks + 8 * l4];
#pragma unroll
        for (int cf = 0; cf < 2; ++cf)
#pragma unroll
            for (int nf = 0; nf < 4; ++nf)
                acc[cf][nf] = __builtin_amdgcn_mfma_f32_16x16x32_bf16(Af[cf][ks], Bf[nf], acc[cf][nf], 0, 0, 0);
    }

    float2* o2 = (float2*)outb;
#pragma unroll
    for (int cf = 0; cf < 2; ++cf)
#pragma unroll
        for (int nf = 0; nf < 4; ++nf) {
            int co = 16 * w + 8 * cf + 2 * l4;
            int p = p0 + 16 * nf + l15;
            o2[(size_t)co * HWS + p]       = make_float2(acc[cf][nf][0], acc[cf][nf][1]);
            o2[(size_t)(co + 1) * HWS + p] = make_float2(acc[cf][nf][2], acc[cf][nf][3]);
        }
}

// ---------------- Kernel F2: out = A_big * v via LDS-staged vpack ----------------
__global__ __launch_bounds__(256) void k_out2(const u16* __restrict__ Abig,
                                              const u32* __restrict__ vpk,
                                              float* __restrict__ outb,
                                              int b0, size_t vst, size_t ost) {
    const int z = blockIdx.z;
    const int b = b0 + z;
    vpk += (size_t)z * vst; outb += (size_t)z * ost;
    __shared__ u32 Tep[64][65];
    const int p0 = blockIdx.x << 6;
    const int t = threadIdx.x, lane = t & 63, w = t >> 6;
    const int l15 = lane & 15, l4 = lane >> 4;
    const u16* AB = Abig + (size_t)b * 16384;

    bf16x8 Af[2][4];
#pragma unroll
    for (int cf = 0; cf < 2; ++cf)
#pragma unroll
        for (int ks = 0; ks < 4; ++ks)
            Af[cf][ks] = *(const bf16x8*)&AB[(size_t)(32 * w + 16 * cf + l15) * 128 + 32 * ks + 8 * l4];

    for (int i = t; i < 4096; i += 256) {
        int e = i >> 6, tok = i & 63;
        Tep[e][tok] = vpk[(size_t)e * HWS + p0 + tok];
    }
    __syncthreads();

    f32x4 zz = {0.f, 0.f, 0.f, 0.f};
    f32x4 acc[2][4];
#pragma unroll
    for (int cf = 0; cf < 2; ++cf)
#pragma unroll
        for (int nf = 0; nf < 4; ++nf) acc[cf][nf] = zz;

#pragma unroll
    for (int ks = 0; ks < 4; ++ks) {
        bf16x8 Bf[4];
#pragma unroll
        for (int nf = 0; nf < 4; ++nf) {
            int tok = 16 * nf + l15;
            int e0 = 16 * ks + 4 * l4;
            union { u32 u[4]; bf16x8 v; } bb;
#pragma unroll
            for (int j = 0; j < 4; ++j) bb.u[j] = Tep[e0 + j][tok];
            Bf[nf] = bb.v;
        }
#pragma unroll
        for (int cf = 0; cf < 2; ++cf)
#pragma unroll
            for (int nf = 0; nf < 4; ++nf)
                acc[cf][nf] = __builtin_amdgcn_mfma_f32_16x16x32_bf16(Af[cf][ks], Bf[nf], acc[cf][nf], 0, 0, 0);
    }

    float2* o2 = (float2*)outb;
#pragma unroll
    for (int cf = 0; cf < 2; ++cf)
#pragma unroll
        for (int nf = 0; nf < 4; ++nf) {
            int co = 16 * w + 8 * cf + 2 * l4;
            int p = p0 + 16 * nf + l15;
            o2[(size_t)co * HWS + p]       = make_float2(acc[cf][nf][0], acc[cf][nf][1]);
            o2[(size_t)(co + 1) * HWS + p] = make_float2(acc[cf][nf][2], acc[cf][nf][3]);
        }
}

extern "C" void kernel_launch(void* const* d_in, const int* in_sizes, int n_in,
                              void* d_out, int out_size, void* d_ws, size_t ws_size,
                              hipStream_t stream) {
    const float* x      = (const float*)d_in[0];
    const float* qkv_wr = (const float*)d_in[1];
    const float* qkv_wi = (const float*)d_in[2];
    const float* dw_wr  = (const float*)d_in[3];
    const float* dw_wi  = (const float*)d_in[4];
    const float* p_wr   = (const float*)d_in[5];
    const float* p_wi   = (const float*)d_in[6];
    float* out = (float*)d_out;
    const size_t OSTR = (size_t)64 * HWS * 2;   // floats per batch of output

    const bool z2  = ws_size >= 236000000ull;   // fully per-b-strided buffers
    const bool f14 = !z2 && ws_size >= 118200000ull;

    char* base = (char*)d_ws;

    if (z2) {
        // per-b strided layout (~236 MB)
        u32*   qs   = (u32*)base;                          // 2 x 50,724,864 B
        u16*   dwp  = (u16*)(base + 101449728);            // 2 x 33,554,432 B
        u16*   xTr  = (u16*)(base + 168558592);            // 2 x 8,388,608 B (both planes)
        u16*   xTi  = xTr + (size_t)HWS * 64;
        u32*   vpk  = (u32*)(base + 202113024);            // 2 x 16,777,216 B
        u16*   wbf  = (u16*)(base + 235667456);            // 73,728 B
        u32*   wdot = (u32*)(base + 235741184);            // 13,824 B
        float* rnsum = (float*)(base + 235755008);
        float* attn  = rnsum + 512;
        float* Pbuf  = attn + 16384;
        u16*   Abig  = (u16*)(Pbuf + 16384);

        const size_t XT_ST = 8388608;     // u16 per b (both planes)
        const size_t QS_ST = 12681216;    // u32 per b
        const size_t DW_ST = 16777216;    // u16 per b
        const size_t VP_ST = 4194304;     // u32 per b

        k_prep<<<66, 256, 0, stream>>>(qkv_wr, qkv_wi, dw_wr, dw_wi, wbf, wdot,
                                       rnsum, 512 + 16384);
        k_xt<<<dim3(1024, 1, 2), 256, 0, stream>>>(x, xTr, xTi, OSTR, XT_ST);
        // NP2 = 258 row-pairs (129/b); grid = 8*6*ceil(258/8) = 1584
        k_qkv<<<1584, 256, 0, stream>>>(xTr, xTi, wbf, qs, XT_ST, QS_ST, 258);
        k_dw<<<dim3(12288, 1, 2), 256, 0, stream>>>(qs, wdot, dwp, vpk,
                                                    QS_ST, DW_ST, VP_ST);
        k_qk<<<dim3(64, 2, 2), 256, 0, stream>>>(dwp, rnsum, attn, 0, DW_ST);
        k_prob<<<dim3(2, 2), 64, 0, stream>>>(attn, rnsum, Pbuf, 0);
        k_M<<<dim3(16, 2), 256, 0, stream>>>(Pbuf, p_wr, p_wi, Abig, 0);
        k_out2<<<dim3(1024, 1, 2), 256, 0, stream>>>(Abig, vpk, out, 0, VP_ST, OSTR);
        return;
    }

    // shared-buffer layouts (round-14 / round-13 proven paths)
    u32*   qs   = (u32*)base;                               // 50,724,864 B
    u16*   dwp  = (u16*)(base + 50724864);                  // 33,554,432 B
    char*  xreg = base + 50724864 + 33554432;               // 16,777,216 B
    u16*   xTr  = (u16*)xreg;
    u16*   xTi  = xTr + (size_t)HWS * 64;
    u32*   vT   = (u32*)xreg;                               // fallback-13: vT aliases xT
    u32*   vpkW = (u32*)(base + 101056512);                 // f14 only
    size_t tail = f14 ? 117833728ull : 101056512ull;
    u16*   wbf  = (u16*)(base + tail);
    u32*   wdot = (u32*)(base + tail + 73728);
    float* rnsum = (float*)(base + tail + 87552);
    float* attn  = rnsum + 512;
    float* Pbuf  = attn + 16384;
    u16*   Abig  = (u16*)(Pbuf + 16384);

    k_prep<<<66, 256, 0, stream>>>(qkv_wr, qkv_wi, dw_wr, dw_wi, wbf, wdot,
                                   rnsum, 512 + 16384);

    for (int b = 0; b < 2; ++b) {
        const float* xb = x + (size_t)b * OSTR;
        u32* vpack = f14 ? vpkW : (u32*)(out + (size_t)b * OSTR);
        k_xt<<<dim3(1024, 1, 1), 256, 0, stream>>>(xb, xTr, xTi, 0, 0);
        // NP2 = 129 pairs; grid = 8*6*ceil(129/8) = 816
        k_qkv<<<816, 256, 0, stream>>>(xTr, xTi, wbf, qs, 0, 0, 129);
        k_dw<<<dim3(12288, 1, 1), 256, 0, stream>>>(qs, wdot, dwp, vpack, 0, 0, 0);
        k_qk<<<dim3(64, 2, 1), 256, 0, stream>>>(dwp, rnsum, attn, b, 0);
        k_prob<<<dim3(2, 1), 64, 0, stream>>>(attn, rnsum, Pbuf, b);
        k_M<<<dim3(16, 1), 256, 0, stream>>>(Pbuf, p_wr, p_wi, Abig, b);
        if (f14)
            k_out2<<<dim3(1024, 1, 1), 256, 0, stream>>>(Abig, vpkW,
                                                         out + (size_t)b * OSTR, b, 0, 0);
    }
    if (!f14) {
        for (int b = 0; b < 2; ++b) {
            u32* vpack = (u32*)(out + (size_t)b * OSTR);
            k_vt<<<1024, 256, 0, stream>>>(vpack, vT);
            k_out<<<1024, 256, 0, stream>>>(Abig + (size_t)b * 16384, (const u16*)vT,
                                            out + (size_t)b * OSTR);
        }
    }
}

// Round 25
// 157.723 us; speedup vs baseline: 1.3480x; 1.0341x over previous
//
#include <hip/hip_runtime.h>

#define HWS 65536   // 256*256
#define SPZ 66048   // (256+2)*256 halo strip positions

typedef __attribute__((ext_vector_type(8))) short bf16x8;
typedef __attribute__((ext_vector_type(4))) float f32x4;
typedef unsigned int u32;
typedef unsigned short u16;

__device__ __forceinline__ u16 f2bf(float x) {
    u32 u = __float_as_uint(x);
    return (u16)((u + 0x7fffu + ((u >> 16) & 1u)) >> 16);
}
__device__ __forceinline__ float bf2f(u32 h) { return __uint_as_float(h << 16); }
// HW packed bf16 convert (RNE, identical rounding to f2bf): lo=a, hi=b
__device__ __forceinline__ u32 cvtpk(float a, float b) {
    u32 r;
    asm("v_cvt_pk_bf16_f32 %0, %1, %2" : "=v"(r) : "v"(a), "v"(b));
    return r;
}
// packed bf16 dot2: d = a.lo*b.lo + a.hi*b.hi + c
__device__ __forceinline__ float dot2bf(u32 a, u32 b, float c) {
    float r;
    asm("v_dot2_f32_bf16 %0, %1, %2, %3" : "=v"(r) : "v"(a), "v"(b), "v"(c));
    return r;
}

// ---------------- prep: weight cvt + dw weight pairs + zero accumulators ----------------
__global__ void k_prep(const float* __restrict__ wr, const float* __restrict__ wi,
                       const float* __restrict__ dr, const float* __restrict__ di,
                       u16* __restrict__ wbf, u32* __restrict__ wdot,
                       float* __restrict__ zbuf, int nz) {
    int i = blockIdx.x * 256 + threadIdx.x;
    if (i < 12288) {
        wbf[i]         = f2bf(wr[i]);
        wbf[12288 + i] = f2bf(wi[i]);
        wbf[24576 + i] = f2bf(-wi[i]);
    }
    if (i < 1728) {                        // 192 ch x 9 taps
        float w0 = dr[i], w1 = di[i];
        wdot[i * 2 + 0] = (u32)f2bf(w0) | ((u32)f2bf(-w1) << 16);
        wdot[i * 2 + 1] = (u32)f2bf(w1) | ((u32)f2bf(w0) << 16);
    }
    if (i < nz) zbuf[i] = 0.f;
}

// ---------------- Kernel X: transpose+convert x -> xT planes in MFMA-fragment order ----------
__global__ __launch_bounds__(256) void k_xt(const float* __restrict__ x,
                                            u16* __restrict__ xTr,
                                            u16* __restrict__ xTi,
                                            size_t xs, size_t ts) {
    const int b = blockIdx.z;
    x += (size_t)b * xs; xTr += (size_t)b * ts; xTi += (size_t)b * ts;
    __shared__ u16 Tr[64][74], Ti[64][74];
    int p0 = blockIdx.x << 6;
    int t = threadIdx.x;
    const float2* x2 = (const float2*)x;
    for (int i = t; i < 2048; i += 256) {        // (ci-pair, c)
        int cp = i >> 6, c = i & 63;
        int ci = cp << 1;
        float2 v0 = x2[(size_t)ci * HWS + p0 + c];
        float2 v1 = x2[(size_t)(ci + 1) * HWS + p0 + c];
        *(u32*)&Tr[c][ci] = cvtpk(v0.x, v1.x);
        *(u32*)&Ti[c][ci] = cvtpk(v0.y, v1.y);
    }
    __syncthreads();
    u32* dr = (u32*)xTr;
    u32* di = (u32*)xTi;
    for (int i = t; i < 2048; i += 256) {        // fragment-order store
        int tb = i >> 9, rem = i & 511;          // 4 tok-blocks x 512 u32
        int chunk = rem >> 2, w4 = rem & 3;      // chunk = l15 + l4*16 + ks*64
        int tl  = chunk & 15;
        int l4c = (chunk >> 4) & 3;
        int ksc = chunk >> 6;
        int token = tb * 16 + tl;
        int cio = ksc * 32 + l4c * 8 + w4 * 2;
        size_t dst = (size_t)(p0 + tb * 16) * 32 + rem;
        dr[dst] = *(u32*)&Tr[token][cio];
        di[dst] = *(u32*)&Ti[token][cio];
    }
}

// ---------------- Kernel A: qkv 1x1 complex conv, 2 rows/block, fragment-linear B ----------------
__global__ __launch_bounds__(256) void k_qkv(const u16* __restrict__ xTr,
                                             const u16* __restrict__ xTi,
                                             const u16* __restrict__ wbf,
                                             u32* __restrict__ qs,
                                             size_t ts, size_t qsst, int NP2) {
    __shared__ u32 Tep[32 * 132];    // 16896 B
    const int bid = blockIdx.x;
    const int xcd = bid & 7, j = bid >> 3;
    const int cog = j % 6;               // 0..5, 32 co each
    const int pr2 = xcd + 8 * (j / 6);   // row-pair index
    if (pr2 >= NP2) return;
    const int z  = pr2 / 129;
    const int rp = pr2 % 129;
    xTr += (size_t)z * ts; xTi += (size_t)z * ts; qs += (size_t)z * qsst;
    const int t = threadIdx.x, lane = t & 63, wv = t >> 6;
    const int l15 = lane & 15, l4 = lane >> 4;

    bf16x8 Ar[2][2], Ai[2][2], An[2][2];
#pragma unroll
    for (int cf = 0; cf < 2; ++cf)
#pragma unroll
        for (int ks = 0; ks < 2; ++ks) {
            size_t off = (size_t)(cog * 32 + 16 * cf + l15) * 64 + 32 * ks + 8 * l4;
            Ar[cf][ks] = *(const bf16x8*)&wbf[off];
            Ai[cf][ks] = *(const bf16x8*)&wbf[12288 + off];
            An[cf][ks] = *(const bf16x8*)&wbf[24576 + off];
        }

    const f32x4 zz = {0.f, 0.f, 0.f, 0.f};
    const int ln2 = lane & 31, rsel = lane >> 5;

#pragma unroll
    for (int rr = 0; rr < 2; ++rr) {
        const int rt = rp * 2 + rr;          // 0..257
        const int w = rt - 1;                // image row (may be OOB -> zeros)
        const bool valid = (unsigned)w < 256u;

#pragma unroll
        for (int half = 0; half < 2; ++half) {
            __syncthreads();                          // Tep reuse guard
#pragma unroll
            for (int pfh = 0; pfh < 2; ++pfh) {
                const int tokh = pfh * 64 + wv * 16 + l15;   // token within half
                f32x4 cr[2] = {zz, zz}, cim[2] = {zz, zz};
                if (valid) {
                    size_t base = ((size_t)w * 256 + half * 128 + pfh * 64 + wv * 16) * 64
                                  + lane * 8;
                    bf16x8 br[2], bi[2];
                    br[0] = *(const bf16x8*)&xTr[base];
                    br[1] = *(const bf16x8*)&xTr[base + 512];
                    bi[0] = *(const bf16x8*)&xTi[base];
                    bi[1] = *(const bf16x8*)&xTi[base + 512];
#pragma unroll
                    for (int ks = 0; ks < 2; ++ks)
#pragma unroll
                        for (int cf = 0; cf < 2; ++cf) {
                            cr[cf]  = __builtin_amdgcn_mfma_f32_16x16x32_bf16(Ar[cf][ks], br[ks], cr[cf], 0, 0, 0);
                            cr[cf]  = __builtin_amdgcn_mfma_f32_16x16x32_bf16(An[cf][ks], bi[ks], cr[cf], 0, 0, 0);
                            cim[cf] = __builtin_amdgcn_mfma_f32_16x16x32_bf16(Ai[cf][ks], br[ks], cim[cf], 0, 0, 0);
                            cim[cf] = __builtin_amdgcn_mfma_f32_16x16x32_bf16(Ar[cf][ks], bi[ks], cim[cf], 0, 0, 0);
                        }
                }
#pragma unroll
                for (int cf = 0; cf < 2; ++cf)
#pragma unroll
                    for (int r = 0; r < 4; ++r) {
                        int col = 16 * cf + 4 * l4 + r;      // local co 0..31
                        Tep[col * 132 + tokh] = valid ? cvtpk(cr[cf][r], cim[cf][r]) : 0u;
                    }
            }
            __syncthreads();
#pragma unroll
            for (int k = 0; k < 4; ++k) {
                int co = wv + 4 * (2 * k + rsel);
                uint4 vv = *(const uint4*)&Tep[co * 132 + 4 * ln2];
                *(uint4*)&qs[(size_t)(cog * 32 + co) * SPZ + rt * 256 + half * 128 + 4 * ln2] = vv;
            }
        }
    }
}

// ---------------- Kernel B: depthwise 3x3 complex conv, 8 pixels/thread, dot2 ----------------
// 32 lanes per row (wave = 2 rows); h-mask keeps halo correct at row edges.
__global__ __launch_bounds__(256) void k_dw(const u32* __restrict__ qs,
                                            const u32* __restrict__ wdot,
                                            u16* __restrict__ dwp,
                                            u32* __restrict__ vpack,
                                            size_t qsst, size_t dst, size_t vst) {
    const int b = blockIdx.z;
    qs += (size_t)b * qsst; dwp += (size_t)b * dst; vpack += (size_t)b * vst;
    const int ch = blockIdx.x >> 5;                         // uniform -> s_loads
    const int p8 = (((blockIdx.x & 31) << 8) + threadIdx.x) << 3;
    const int r = p8 >> 8, h = p8 & 255;                    // h = 8*laneInRow
    const u32* src = qs + (size_t)ch * SPZ + r * 256;

    u32 wA[9], wB[9];
#pragma unroll
    for (int tt = 0; tt < 9; ++tt) {
        wA[tt] = wdot[(ch * 9 + tt) * 2 + 0];
        wB[tt] = wdot[(ch * 9 + tt) * 2 + 1];
    }

    u32 uv[3][10];
#pragma unroll
    for (int du = 0; du < 3; ++du) {
        uint4 W0 = *(const uint4*)&src[du * 256 + h];       // words h..h+3
        uint4 W1 = *(const uint4*)&src[du * 256 + h + 4];   // words h+4..h+7
        u32 left  = (u32)__shfl_up((int)W1.w, 1);           // word at h-1
        u32 right = (u32)__shfl_down((int)W0.x, 1);         // word at h+8
        if (h == 0)   left = 0u;
        if (h == 248) right = 0u;
        uv[du][0] = left;
        uv[du][1] = W0.x; uv[du][2] = W0.y; uv[du][3] = W0.z; uv[du][4] = W0.w;
        uv[du][5] = W1.x; uv[du][6] = W1.y; uv[du][7] = W1.z; uv[du][8] = W1.w;
        uv[du][9] = right;
    }

    float ar[8], ai[8];
#pragma unroll
    for (int px = 0; px < 8; ++px) { ar[px] = 0.f; ai[px] = 0.f; }
#pragma unroll
    for (int du = 0; du < 3; ++du)
#pragma unroll
        for (int ct = 0; ct < 3; ++ct) {
            const int tap = du * 3 + ct;
            const u32 a = wA[tap], bw = wB[tap];
#pragma unroll
            for (int px = 0; px < 8; ++px) {
                ar[px] = dot2bf(a,  uv[du][px + ct], ar[px]);
                ai[px] = dot2bf(bw, uv[du][px + ct], ai[px]);
            }
        }

    if (ch < 128) {
        int pl = (ch < 64) ? 0 : 2;
        int c2 = ch & 63;
        uint4 rw = make_uint4(cvtpk(ar[0], ar[1]), cvtpk(ar[2], ar[3]),
                              cvtpk(ar[4], ar[5]), cvtpk(ar[6], ar[7]));
        uint4 iw = make_uint4(cvtpk(ai[0], ai[1]), cvtpk(ai[2], ai[3]),
                              cvtpk(ai[4], ai[5]), cvtpk(ai[6], ai[7]));
        *(uint4*)&dwp[(size_t)(pl * 64 + c2) * HWS + p8] = rw;
        *(uint4*)&dwp[(size_t)((pl + 1) * 64 + c2) * HWS + p8] = iw;
    } else {
        int e = ch - 128;
        uint4 v0 = make_uint4(cvtpk(ar[0], ai[0]), cvtpk(ar[1], ai[1]),
                              cvtpk(ar[2], ai[2]), cvtpk(ar[3], ai[3]));
        uint4 v1 = make_uint4(cvtpk(ar[4], ai[4]), cvtpk(ar[5], ai[5]),
                              cvtpk(ar[6], ai[6]), cvtpk(ar[7], ai[7]));
        *(uint4*)&vpack[(size_t)e * HWS + p8] = v0;
        *(uint4*)&vpack[(size_t)e * HWS + p8 + 4] = v1;
    }
}

// ---------------- Kernel C: q k^T + fused sumsq via MFMA (no LDS) ----------------
__global__ __launch_bounds__(256) void k_qk(const u16* __restrict__ dwp,
                                            float* __restrict__ rnsum,
                                            float* __restrict__ attn,
                                            int b0, size_t dst) {
    const int z = blockIdx.z;
    const int b = b0 + z;
    dwp += (size_t)z * dst;
    const int chunk = blockIdx.x;        // 0..63
    const int d = blockIdx.y;
    const int Kc = HWS >> 6;
    const int kc0 = chunk * Kc;
    const u16* qp = dwp + (size_t)d * 64 * HWS;
    const u16* kp = dwp + (size_t)(2 + d) * 64 * HWS;

    const int t = threadIdx.x, lane = t & 63, wid = t >> 6;
    const int wy = wid >> 1, wx = wid & 1;
    const int l15 = lane & 15, l4 = lane >> 4;

    f32x4 zz = {0.f, 0.f, 0.f, 0.f};
    f32x4 acc[2][2] = {{zz, zz}, {zz, zz}};
    float sq[2] = {0.f, 0.f}, sk[2] = {0.f, 0.f};

    const int iters = Kc >> 5;
    for (int ks = 0; ks < iters; ++ks) {
        int k0 = kc0 + ks * 32 + 8 * l4;
        bf16x8 aq[2], bk[2];
#pragma unroll
        for (int cf = 0; cf < 2; ++cf)
            aq[cf] = *(const bf16x8*)&qp[(size_t)(32 * wy + 16 * cf + l15) * HWS + k0];
#pragma unroll
        for (int ef = 0; ef < 2; ++ef)
            bk[ef] = *(const bf16x8*)&kp[(size_t)(32 * wx + 16 * ef + l15) * HWS + k0];

        if (wx == 0)
#pragma unroll
            for (int cf = 0; cf < 2; ++cf)
#pragma unroll
                for (int j = 0; j < 8; ++j) {
                    float f = bf2f((u16)aq[cf][j]);
                    sq[cf] = fmaf(f, f, sq[cf]);
                }
        if (wy == 0)
#pragma unroll
            for (int ef = 0; ef < 2; ++ef)
#pragma unroll
                for (int j = 0; j < 8; ++j) {
                    float f = bf2f((u16)bk[ef][j]);
                    sk[ef] = fmaf(f, f, sk[ef]);
                }

#pragma unroll
        for (int cf = 0; cf < 2; ++cf)
#pragma unroll
            for (int ef = 0; ef < 2; ++ef)
                acc[cf][ef] = __builtin_amdgcn_mfma_f32_16x16x32_bf16(aq[cf], bk[ef], acc[cf][ef], 0, 0, 0);
    }

#pragma unroll
    for (int cf = 0; cf < 2; ++cf)
#pragma unroll
        for (int ef = 0; ef < 2; ++ef)
#pragma unroll
            for (int r = 0; r < 4; ++r) {
                int cq = 32 * wy + 16 * cf + 4 * l4 + r;
                int ce = 32 * wx + 16 * ef + l15;
                atomicAdd(&attn[((b * 2 + d) * 64 + cq) * 64 + ce], acc[cf][ef][r]);
            }

    if (wx == 0)
#pragma unroll
        for (int cf = 0; cf < 2; ++cf) {
            float v = sq[cf];
            v += __shfl_xor(v, 16);
            v += __shfl_xor(v, 32);
            if (lane < 16)
                atomicAdd(&rnsum[((size_t)b * 128 + 32 * wy + 16 * cf + lane) * 2 + d], v);
        }
    if (wy == 0)
#pragma unroll
        for (int ef = 0; ef < 2; ++ef) {
            float v = sk[ef];
            v += __shfl_xor(v, 16);
            v += __shfl_xor(v, 32);
            if (lane < 16)
                atomicAdd(&rnsum[((size_t)b * 128 + 64 + 32 * wx + 16 * ef + lane) * 2 + d], v);
        }
}

// ---------------- Kernel D1: scale + row softmax -> P (grid (2 d, nb), 64 thr) ----------------
__global__ __launch_bounds__(64) void k_prob(const float* __restrict__ attn,
                                             const float* __restrict__ rnsum,
                                             float* __restrict__ P, int b0) {
    int d = blockIdx.x;
    int b = b0 + blockIdx.y;
    int t = threadIdx.x;
    __shared__ float rks[64];
    float sk = rnsum[((size_t)b * 128 + 64 + t) * 2 + d];
    rks[t] = 1.0f / fmaxf(sqrtf(sk), 1e-12f);
    float sq = rnsum[((size_t)b * 128 + t) * 2 + d];
    float rq = 1.0f / fmaxf(sqrtf(sq), 1e-12f);
    __syncthreads();

    const float* arow = attn + ((size_t)(b * 2 + d) * 64 + t) * 64;
    float v[64];
    float m = -1e30f;
#pragma unroll
    for (int e = 0; e < 64; ++e) { v[e] = arow[e] * rq * rks[e]; m = fmaxf(m, v[e]); }
    float ssum = 0.f;
#pragma unroll
    for (int e = 0; e < 64; ++e) { v[e] = __expf(v[e] - m); ssum += v[e]; }
    float r = 1.0f / ssum;
    float* prow = P + ((size_t)(b * 2 + d) * 64 + t) * 64;
#pragma unroll
    for (int e = 0; e < 64; ++e) prow[e] = v[e] * r;
}

// ---------------- Kernel D2: build A_big from P and proj weights (grid (16, nb)) ----------------
__global__ __launch_bounds__(256) void k_M(const float* __restrict__ P,
                                           const float* __restrict__ pwr,
                                           const float* __restrict__ pwi,
                                           u16* __restrict__ Abig, int b0) {
    int b = b0 + blockIdx.y;
    int pair = blockIdx.x * 256 + threadIdx.x;   // 0..4095
    __shared__ float P0[64][64], P1[64][64];
    __shared__ float Wr[64][64], Wi2[64][64];
    for (int i = threadIdx.x; i < 4096; i += 256) {
        P0[i >> 6][i & 63] = P[(size_t)(b * 2 + 0) * 4096 + i];
        P1[i >> 6][i & 63] = P[(size_t)(b * 2 + 1) * 4096 + i];
        Wr[i >> 6][i & 63] = pwr[i];
        Wi2[i >> 6][i & 63] = pwi[i];
    }
    __syncthreads();
    int co = pair >> 6, e = pair & 63;
    float m1 = 0.f, m2 = 0.f, m3 = 0.f, m4 = 0.f;
#pragma unroll 8
    for (int c = 0; c < 64; ++c) {
        float pr = Wr[co][c], pi = Wi2[co][c];
        float a0 = P0[c][e], a1 = P1[c][e];
        m1 = fmaf(pr, a0, m1);
        m2 = fmaf(pi, a1, m2);
        m3 = fmaf(pr, a1, m3);
        m4 = fmaf(pi, a0, m4);
    }
    u16* AB = Abig + (size_t)b * 16384;
    AB[(2 * co) * 128 + 2 * e]         = f2bf(m1);
    AB[(2 * co) * 128 + 2 * e + 1]     = f2bf(-m2);
    AB[(2 * co + 1) * 128 + 2 * e]     = f2bf(m4);
    AB[(2 * co + 1) * 128 + 2 * e + 1] = f2bf(m3);
}

// ---------------- Kernel E (fallback): transpose vpack [64][HWS] u32 -> vT [HWS][64] u32 ----------------
__global__ __launch_bounds__(256) void k_vt(const u32* __restrict__ in,
                                            u32* __restrict__ outp) {
    __shared__ u32 tile[64][65];
    int p0 = blockIdx.x << 6;
    int t = threadIdx.x;
    for (int i = t; i < 4096; i += 256) {
        int e = i >> 6, c = i & 63;
        tile[e][c] = in[(size_t)e * HWS + p0 + c];
    }
    __syncthreads();
    for (int i = t; i < 4096; i += 256) {
        int r = i >> 6, e = i & 63;
        outp[(size_t)(p0 + r) * 64 + e] = tile[e][r];
    }
}

// ---------------- Kernel F (fallback): out = A_big * vT via MFMA (no LDS) ----------------
__global__ __launch_bounds__(256) void k_out(const u16* __restrict__ Abig,
                                             const u16* __restrict__ vT,
                                             float* __restrict__ outb) {
    const int p0 = blockIdx.x << 6;
    const int t = threadIdx.x, lane = t & 63, w = t >> 6;
    const int l15 = lane & 15, l4 = lane >> 4;

    bf16x8 Af[2][4];
#pragma unroll
    for (int cf = 0; cf < 2; ++cf)
#pragma unroll
        for (int ks = 0; ks < 4; ++ks)
            Af[cf][ks] = *(const bf16x8*)&Abig[(size_t)(32 * w + 16 * cf + l15) * 128 + 32 * ks + 8 * l4];

    f32x4 zz = {0.f, 0.f, 0.f, 0.f};
    f32x4 acc[2][4];
#pragma unroll
    for (int cf = 0; cf < 2; ++cf)
#pragma unroll
        for (int nf = 0; nf < 4; ++nf) acc[cf][nf] = zz;

#pragma unroll
    for (int ks = 0; ks < 4; ++ks) {
        bf16x8 Bf[4];
#pragma unroll
        for (int nf = 0; nf < 4; ++nf)
            Bf[nf] = *(const bf16x8*)&vT[(size_t)(p0 + 16 * nf + l15) * 128 + 32 * ks + 8 * l4];
#pragma unroll
        for (int cf = 0; cf < 2; ++cf)
#pragma unroll
            for (int nf = 0; nf < 4; ++nf)
                acc[cf][nf] = __builtin_amdgcn_mfma_f32_16x16x32_bf16(Af[cf][ks], Bf[nf], acc[cf][nf], 0, 0, 0);
    }

    float2* o2 = (float2*)outb;
#pragma unroll
    for (int cf = 0; cf < 2; ++cf)
#pragma unroll
        for (int nf = 0; nf < 4; ++nf) {
            int co = 16 * w + 8 * cf + 2 * l4;
            int p = p0 + 16 * nf + l15;
            o2[(size_t)co * HWS + p]       = make_float2(acc[cf][nf][0], acc[cf][nf][1]);
            o2[(size_t)(co + 1) * HWS + p] = make_float2(acc[cf][nf][2], acc[cf][nf][3]);
        }
}

// ---------------- Kernel F2: out = A_big * v via LDS-staged vpack ----------------
__global__ __launch_bounds__(256) void k_out2(const u16* __restrict__ Abig,
                                              const u32* __restrict__ vpk,
                                              float* __restrict__ outb,
                                              int b0, size_t vst, size_t ost) {
    const int z = blockIdx.z;
    const int b = b0 + z;
    vpk += (size_t)z * vst; outb += (size_t)z * ost;
    __shared__ u32 Tep[64][65];
    const int p0 = blockIdx.x << 6;
    const int t = threadIdx.x, lane = t & 63, w = t >> 6;
    const int l15 = lane & 15, l4 = lane >> 4;
    const u16* AB = Abig + (size_t)b * 16384;

    bf16x8 Af[2][4];
#pragma unroll
    for (int cf = 0; cf < 2; ++cf)
#pragma unroll
        for (int ks = 0; ks < 4; ++ks)
            Af[cf][ks] = *(const bf16x8*)&AB[(size_t)(32 * w + 16 * cf + l15) * 128 + 32 * ks + 8 * l4];

    for (int i = t; i < 4096; i += 256) {
        int e = i >> 6, tok = i & 63;
        Tep[e][tok] = vpk[(size_t)e * HWS + p0 + tok];
    }
    __syncthreads();

    f32x4 zz = {0.f, 0.f, 0.f, 0.f};
    f32x4 acc[2][4];
#pragma unroll
    for (int cf = 0; cf < 2; ++cf)
#pragma unroll
        for (int nf = 0; nf < 4; ++nf) acc[cf][nf] = zz;

#pragma unroll
    for (int ks = 0; ks < 4; ++ks) {
        bf16x8 Bf[4];
#pragma unroll
        for (int nf = 0; nf < 4; ++nf) {
            int tok = 16 * nf + l15;
            int e0 = 16 * ks + 4 * l4;
            union { u32 u[4]; bf16x8 v; } bb;
#pragma unroll
            for (int j = 0; j < 4; ++j) bb.u[j] = Tep[e0 + j][tok];
            Bf[nf] = bb.v;
        }
#pragma unroll
        for (int cf = 0; cf < 2; ++cf)
#pragma unroll
            for (int nf = 0; nf < 4; ++nf)
                acc[cf][nf] = __builtin_amdgcn_mfma_f32_16x16x32_bf16(Af[cf][ks], Bf[nf], acc[cf][nf], 0, 0, 0);
    }

    float2* o2 = (float2*)outb;
#pragma unroll
    for (int cf = 0; cf < 2; ++cf)
#pragma unroll
        for (int nf = 0; nf < 4; ++nf) {
            int co = 16 * w + 8 * cf + 2 * l4;
            int p = p0 + 16 * nf + l15;
            o2[(size_t)co * HWS + p]       = make_float2(acc[cf][nf][0], acc[cf][nf][1]);
            o2[(size_t)(co + 1) * HWS + p] = make_float2(acc[cf][nf][2], acc[cf][nf][3]);
        }
}

extern "C" void kernel_launch(void* const* d_in, const int* in_sizes, int n_in,
                              void* d_out, int out_size, void* d_ws, size_t ws_size,
                              hipStream_t stream) {
    const float* x      = (const float*)d_in[0];
    const float* qkv_wr = (const float*)d_in[1];
    const float* qkv_wi = (const float*)d_in[2];
    const float* dw_wr  = (const float*)d_in[3];
    const float* dw_wi  = (const float*)d_in[4];
    const float* p_wr   = (const float*)d_in[5];
    const float* p_wi   = (const float*)d_in[6];
    float* out = (float*)d_out;
    const size_t OSTR = (size_t)64 * HWS * 2;   // floats per batch of output

    const bool z2  = ws_size >= 236000000ull;   // fully per-b-strided buffers
    const bool f14 = !z2 && ws_size >= 118200000ull;

    char* base = (char*)d_ws;

    if (z2) {
        // per-b strided layout (~236 MB)
        u32*   qs   = (u32*)base;                          // 2 x 50,724,864 B
        u16*   dwp  = (u16*)(base + 101449728);            // 2 x 33,554,432 B
        u16*   xTr  = (u16*)(base + 168558592);            // 2 x 8,388,608 B (both planes)
        u16*   xTi  = xTr + (size_t)HWS * 64;
        u32*   vpk  = (u32*)(base + 202113024);            // 2 x 16,777,216 B
        u16*   wbf  = (u16*)(base + 235667456);            // 73,728 B
        u32*   wdot = (u32*)(base + 235741184);            // 13,824 B
        float* rnsum = (float*)(base + 235755008);
        float* attn  = rnsum + 512;
        float* Pbuf  = attn + 16384;
        u16*   Abig  = (u16*)(Pbuf + 16384);

        const size_t XT_ST = 8388608;     // u16 per b (both planes)
        const size_t QS_ST = 12681216;    // u32 per b
        const size_t DW_ST = 16777216;    // u16 per b
        const size_t VP_ST = 4194304;     // u32 per b

        k_prep<<<66, 256, 0, stream>>>(qkv_wr, qkv_wi, dw_wr, dw_wi, wbf, wdot,
                                       rnsum, 512 + 16384);
        k_xt<<<dim3(1024, 1, 2), 256, 0, stream>>>(x, xTr, xTi, OSTR, XT_ST);
        k_qkv<<<1584, 256, 0, stream>>>(xTr, xTi, wbf, qs, XT_ST, QS_ST, 258);
        k_dw<<<dim3(6144, 1, 2), 256, 0, stream>>>(qs, wdot, dwp, vpk,
                                                   QS_ST, DW_ST, VP_ST);
        k_qk<<<dim3(64, 2, 2), 256, 0, stream>>>(dwp, rnsum, attn, 0, DW_ST);
        k_prob<<<dim3(2, 2), 64, 0, stream>>>(attn, rnsum, Pbuf, 0);
        k_M<<<dim3(16, 2), 256, 0, stream>>>(Pbuf, p_wr, p_wi, Abig, 0);
        k_out2<<<dim3(1024, 1, 2), 256, 0, stream>>>(Abig, vpk, out, 0, VP_ST, OSTR);
        return;
    }

    // shared-buffer layouts (round-14 / round-13 proven paths)
    u32*   qs   = (u32*)base;                               // 50,724,864 B
    u16*   dwp  = (u16*)(base + 50724864);                  // 33,554,432 B
    char*  xreg = base + 50724864 + 33554432;               // 16,777,216 B
    u16*   xTr  = (u16*)xreg;
    u16*   xTi  = xTr + (size_t)HWS * 64;
    u32*   vT   = (u32*)xreg;                               // fallback-13: vT aliases xT
    u32*   vpkW = (u32*)(base + 101056512);                 // f14 only
    size_t tail = f14 ? 117833728ull : 101056512ull;
    u16*   wbf  = (u16*)(base + tail);
    u32*   wdot = (u32*)(base + tail + 73728);
    float* rnsum = (float*)(base + tail + 87552);
    float* attn  = rnsum + 512;
    float* Pbuf  = attn + 16384;
    u16*   Abig  = (u16*)(Pbuf + 16384);

    k_prep<<<66, 256, 0, stream>>>(qkv_wr, qkv_wi, dw_wr, dw_wi, wbf, wdot,
                                   rnsum, 512 + 16384);

    for (int b = 0; b < 2; ++b) {
        const float* xb = x + (size_t)b * OSTR;
        u32* vpack = f14 ? vpkW : (u32*)(out + (size_t)b * OSTR);
        k_xt<<<dim3(1024, 1, 1), 256, 0, stream>>>(xb, xTr, xTi, 0, 0);
        k_qkv<<<816, 256, 0, stream>>>(xTr, xTi, wbf, qs, 0, 0, 129);
        k_dw<<<dim3(6144, 1, 1), 256, 0, stream>>>(qs, wdot, dwp, vpack, 0, 0, 0);
        k_qk<<<dim3(64, 2, 1), 256, 0, stream>>>(dwp, rnsum, attn, b, 0);
        k_prob<<<dim3(2, 1), 64, 0, stream>>>(attn, rnsum, Pbuf, b);
        k_M<<<dim3(16, 1), 256, 0, stream>>>(Pbuf, p_wr, p_wi, Abig, b);
        if (f14)
            k_out2<<<dim3(1024, 1, 1), 256, 0, stream>>>(Abig, vpkW,
                                                         out + (size_t)b * OSTR, b, 0, 0);
    }
    if (!f14) {
        for (int b = 0; b < 2; ++b) {
            u32* vpack = (u32*)(out + (size_t)b * OSTR);
            k_vt<<<1024, 256, 0, stream>>>(vpack, vT);
            k_out<<<1024, 256, 0, stream>>>(Abig + (size_t)b * 16384, (const u16*)vT,
                                            out + (size_t)b * OSTR);
        }
    }
}